// Round 17
// baseline (1382.610 us; speedup 1.0000x reference)
//
#include <hip/hip_runtime.h>
#include <hip/hip_bf16.h>
#include <float.h>
#include <math.h>

// Problem constants
#define NB 4
#define ND 512
#define NS 512
#define NH 8
#define NHD 64
#define NM 8192
#define NL 6
#define NFF 2048
#define NMLP 1024
#define NC 117

// knn5 (fallback) params
#define KCC 64
#define NCC (NM / KCC)
#define CAPB 160
#define TRIG 96

// k_ksel params
#define CAPS 352
#define TRIGS 96

#define AS1 __attribute__((address_space(1)))
#define AS3 __attribute__((address_space(3)))

typedef __attribute__((ext_vector_type(8))) short s16x8;
typedef __attribute__((ext_vector_type(4))) float f32x4;

__device__ __forceinline__ float gelu_f(float x) {
    return 0.5f * x * (1.0f + erff(x * 0.70710678118654752440f));
}

__device__ __forceinline__ ushort f2bf_rne(float x) {
    uint u = __float_as_uint(x);
    uint r = u + 0x7FFFu + ((u >> 16) & 1u);
    return (ushort)(r >> 16);
}
__device__ __forceinline__ float bf2f(ushort h) { return __uint_as_float(((uint)h) << 16); }
__device__ __forceinline__ void split1(float x, ushort& h, ushort& l) {
    h = f2bf_rne(x);
    float r = x - bf2f(h);
    l = f2bf_rne(r);
}
__device__ __forceinline__ void split8(const float* v, s16x8& hv, s16x8& lv) {
#pragma unroll
    for (int j = 0; j < 8; ++j) {
        ushort h, l;
        split1(v[j], h, l);
        hv[j] = (short)h;
        lv[j] = (short)l;
    }
}

// sortable key: (value desc, index asc) -> larger key wins; valid keys nonzero
__device__ __forceinline__ unsigned long long packkey(float v, int idx) {
    uint u = __float_as_uint(v);
    u = u ^ (((int)u < 0) ? 0xFFFFFFFFu : 0x80000000u);
    return (((unsigned long long)u) << 13) | (unsigned long long)(8191 - idx);
}
__device__ __forceinline__ float keyval(unsigned long long K) {
    uint vb = (uint)(K >> 13);
    uint orig = (vb & 0x80000000u) ? (vb ^ 0x80000000u) : ~vb;
    return __uint_as_float(orig);
}
__device__ __forceinline__ uint sortable32(float v) {
    uint u = __float_as_uint(v);
    return u ^ (((int)u < 0) ? 0xFFFFFFFFu : 0x80000000u);
}
__device__ __forceinline__ float unsortable32(uint s) {
    uint u = (s & 0x80000000u) ? (s ^ 0x80000000u) : ~s;
    return __uint_as_float(u);
}

// wave-parallel exact top-32 retain (3 slots/lane) — knn5 fallback path
__device__ __forceinline__ void shrink_cheap(float* __restrict__ cval,
                                             ushort* __restrict__ cidx,
                                             int q, int n, int lane,
                                             float* __restrict__ thrOut) {
    if (n < 32) return;
    int j0 = lane, j1 = lane + 64, j2 = lane + 128;
    bool o0 = j0 < n, o1 = j1 < n, o2 = j2 < n;
    float v0 = o0 ? cval[q * CAPB + j0] : 0.f;
    float v1 = o1 ? cval[q * CAPB + j1] : 0.f;
    float v2 = o2 ? cval[q * CAPB + j2] : 0.f;
    ushort i0 = o0 ? cidx[q * CAPB + j0] : 0;
    ushort i1 = o1 ? cidx[q * CAPB + j1] : 0;
    ushort i2 = o2 ? cidx[q * CAPB + j2] : 0;
    unsigned long long k0 = o0 ? packkey(v0, (int)i0) : 0ULL;
    unsigned long long k1 = o1 ? packkey(v1, (int)i1) : 0ULL;
    unsigned long long k2 = o2 ? packkey(v2, (int)i2) : 0ULL;
    unsigned long long lo = 0, hi = (1ULL << 45) - 1;
    while (lo < hi) {
        unsigned long long mid = (lo + hi + 1) >> 1;
        int c = (int)__popcll(__ballot(k0 >= mid)) + (int)__popcll(__ballot(k1 >= mid)) +
                (int)__popcll(__ballot(k2 >= mid));
        if (c >= 32) lo = mid;
        else hi = mid - 1;
    }
    unsigned long long K = lo;
    unsigned long long lm = (1ULL << lane) - 1;
    int base = 0;
    {
        unsigned long long m = __ballot(k0 >= K);
        if (k0 >= K) { int p = base + (int)__popcll(m & lm); cval[q * CAPB + p] = v0; cidx[q * CAPB + p] = i0; }
        base += (int)__popcll(m);
    }
    {
        unsigned long long m = __ballot(k1 >= K);
        if (k1 >= K) { int p = base + (int)__popcll(m & lm); cval[q * CAPB + p] = v1; cidx[q * CAPB + p] = i1; }
        base += (int)__popcll(m);
    }
    {
        unsigned long long m = __ballot(k2 >= K);
        if (k2 >= K) { int p = base + (int)__popcll(m & lm); cval[q * CAPB + p] = v2; cidx[q * CAPB + p] = i2; }
        base += (int)__popcll(m);
    }
    if (thrOut && lane == 0) *thrOut = keyval(K);
}

// Exact top-32 retain over n<=CAPS (6 slots/lane): value-only 32-bit bitwise
// descend + exact tie fallback (45-bit key). Winners -> slots 0..31 (unsorted).
__device__ __forceinline__ float shrink6v(float* __restrict__ bv,
                                          ushort* __restrict__ bi,
                                          int n, int lane) {
    int j0 = lane, j1 = lane + 64, j2 = lane + 128, j3 = lane + 192, j4 = lane + 256, j5 = lane + 320;
    bool o0 = j0 < n, o1 = j1 < n, o2 = j2 < n, o3 = j3 < n, o4 = j4 < n, o5 = j5 < n;
    float v0 = o0 ? bv[j0] : 0.f, v1 = o1 ? bv[j1] : 0.f, v2 = o2 ? bv[j2] : 0.f;
    float v3 = o3 ? bv[j3] : 0.f, v4 = o4 ? bv[j4] : 0.f, v5 = o5 ? bv[j5] : 0.f;
    ushort i0 = o0 ? bi[j0] : 0, i1 = o1 ? bi[j1] : 0, i2 = o2 ? bi[j2] : 0;
    ushort i3 = o3 ? bi[j3] : 0, i4 = o4 ? bi[j4] : 0, i5 = o5 ? bi[j5] : 0;
    uint s0 = o0 ? sortable32(v0) : 0u, s1 = o1 ? sortable32(v1) : 0u;
    uint s2 = o2 ? sortable32(v2) : 0u, s3 = o3 ? sortable32(v3) : 0u;
    uint s4 = o4 ? sortable32(v4) : 0u, s5 = o5 ? sortable32(v5) : 0u;
    uint S = 0;
#pragma unroll 1
    for (int bit = 31; bit >= 0; --bit) {
        uint cand = S | (1u << bit);
        int c = (int)__popcll(__ballot(s0 >= cand)) + (int)__popcll(__ballot(s1 >= cand)) +
                (int)__popcll(__ballot(s2 >= cand)) + (int)__popcll(__ballot(s3 >= cand)) +
                (int)__popcll(__ballot(s4 >= cand)) + (int)__popcll(__ballot(s5 >= cand));
        if (c >= 32) S = cand;
    }
    unsigned long long g0 = __ballot(s0 > S), g1 = __ballot(s1 > S), g2 = __ballot(s2 > S);
    unsigned long long g3 = __ballot(s3 > S), g4 = __ballot(s4 > S), g5 = __ballot(s5 > S);
    unsigned long long e0 = __ballot(o0 && s0 == S), e1 = __ballot(o1 && s1 == S), e2 = __ballot(o2 && s2 == S);
    unsigned long long e3 = __ballot(o3 && s3 == S), e4 = __ballot(o4 && s4 == S), e5 = __ballot(o5 && s5 == S);
    int cgt = (int)__popcll(g0) + (int)__popcll(g1) + (int)__popcll(g2) +
              (int)__popcll(g3) + (int)__popcll(g4) + (int)__popcll(g5);
    int ceq = (int)__popcll(e0) + (int)__popcll(e1) + (int)__popcll(e2) +
              (int)__popcll(e3) + (int)__popcll(e4) + (int)__popcll(e5);
    unsigned long long lm = (1ULL << lane) - 1;
    if (cgt + ceq == 32) {
        int base = 0;
        if (s0 > S) { int p = base + (int)__popcll(g0 & lm); bv[p] = v0; bi[p] = i0; } base += (int)__popcll(g0);
        if (s1 > S) { int p = base + (int)__popcll(g1 & lm); bv[p] = v1; bi[p] = i1; } base += (int)__popcll(g1);
        if (s2 > S) { int p = base + (int)__popcll(g2 & lm); bv[p] = v2; bi[p] = i2; } base += (int)__popcll(g2);
        if (s3 > S) { int p = base + (int)__popcll(g3 & lm); bv[p] = v3; bi[p] = i3; } base += (int)__popcll(g3);
        if (s4 > S) { int p = base + (int)__popcll(g4 & lm); bv[p] = v4; bi[p] = i4; } base += (int)__popcll(g4);
        if (s5 > S) { int p = base + (int)__popcll(g5 & lm); bv[p] = v5; bi[p] = i5; } base += (int)__popcll(g5);
        if (o0 && s0 == S) { int p = base + (int)__popcll(e0 & lm); bv[p] = v0; bi[p] = i0; } base += (int)__popcll(e0);
        if (o1 && s1 == S) { int p = base + (int)__popcll(e1 & lm); bv[p] = v1; bi[p] = i1; } base += (int)__popcll(e1);
        if (o2 && s2 == S) { int p = base + (int)__popcll(e2 & lm); bv[p] = v2; bi[p] = i2; } base += (int)__popcll(e2);
        if (o3 && s3 == S) { int p = base + (int)__popcll(e3 & lm); bv[p] = v3; bi[p] = i3; } base += (int)__popcll(e3);
        if (o4 && s4 == S) { int p = base + (int)__popcll(e4 & lm); bv[p] = v4; bi[p] = i4; } base += (int)__popcll(e4);
        if (o5 && s5 == S) { int p = base + (int)__popcll(e5 & lm); bv[p] = v5; bi[p] = i5; }
        return unsortable32(S);
    }
    unsigned long long k0 = o0 ? packkey(v0, (int)i0) : 0ULL;
    unsigned long long k1 = o1 ? packkey(v1, (int)i1) : 0ULL;
    unsigned long long k2 = o2 ? packkey(v2, (int)i2) : 0ULL;
    unsigned long long k3 = o3 ? packkey(v3, (int)i3) : 0ULL;
    unsigned long long k4 = o4 ? packkey(v4, (int)i4) : 0ULL;
    unsigned long long k5 = o5 ? packkey(v5, (int)i5) : 0ULL;
    unsigned long long K = 0;
#pragma unroll 1
    for (int bit = 44; bit >= 0; --bit) {
        unsigned long long cand = K | (1ULL << bit);
        int c = (int)__popcll(__ballot(k0 >= cand)) + (int)__popcll(__ballot(k1 >= cand)) +
                (int)__popcll(__ballot(k2 >= cand)) + (int)__popcll(__ballot(k3 >= cand)) +
                (int)__popcll(__ballot(k4 >= cand)) + (int)__popcll(__ballot(k5 >= cand));
        if (c >= 32) K = cand;
    }
    int base = 0;
    {
        unsigned long long m = __ballot(k0 >= K);
        if (k0 >= K) { int p = base + (int)__popcll(m & lm); bv[p] = v0; bi[p] = i0; }
        base += (int)__popcll(m);
    }
    {
        unsigned long long m = __ballot(k1 >= K);
        if (k1 >= K) { int p = base + (int)__popcll(m & lm); bv[p] = v1; bi[p] = i1; }
        base += (int)__popcll(m);
    }
    {
        unsigned long long m = __ballot(k2 >= K);
        if (k2 >= K) { int p = base + (int)__popcll(m & lm); bv[p] = v2; bi[p] = i2; }
        base += (int)__popcll(m);
    }
    {
        unsigned long long m = __ballot(k3 >= K);
        if (k3 >= K) { int p = base + (int)__popcll(m & lm); bv[p] = v3; bi[p] = i3; }
        base += (int)__popcll(m);
    }
    {
        unsigned long long m = __ballot(k4 >= K);
        if (k4 >= K) { int p = base + (int)__popcll(m & lm); bv[p] = v4; bi[p] = i4; }
        base += (int)__popcll(m);
    }
    {
        unsigned long long m = __ballot(k5 >= K);
        if (k5 >= K) { int p = base + (int)__popcll(m & lm); bv[p] = v5; bi[p] = i5; }
        base += (int)__popcll(m);
    }
    return keyval(K);
}

// ---- DMA helpers (rule #21: pre-swizzled sources, linear LDS dest) ----
__device__ __forceinline__ void stage_dma64(const ushort* __restrict__ gh,
                                            const ushort* __restrict__ gl,
                                            ushort* kh, ushort* kl,
                                            int wvi, int lane) {
#pragma unroll
    for (int i = 0; i < 2; ++i) {
        int off = (wvi * 2 + i) * 1024;
        __builtin_amdgcn_global_load_lds(
            (const AS1 uint*)((const char*)gh + off + lane * 16),
            (AS3 uint*)((char*)kh + off), 16, 0, 0);
        __builtin_amdgcn_global_load_lds(
            (const AS1 uint*)((const char*)gl + off + lane * 16),
            (AS3 uint*)((char*)kl + off), 16, 0, 0);
    }
}

// 8KB linear chunk
__device__ __forceinline__ void stage_lin(const char* __restrict__ g, char* dst,
                                          int wvi, int lane) {
#pragma unroll
    for (int i = 0; i < 2; ++i) {
        int base = (wvi * 2 + i) * 1024;
        __builtin_amdgcn_global_load_lds((const AS1 uint*)(g + base + lane * 16),
                                         (AS3 uint*)(dst + base), 16, 0, 0);
    }
}

// 8KB chunk of V^T: 64 rows of 1024B, chunk slice 128B per row
__device__ __forceinline__ void stage_vt(const char* __restrict__ gb, int cByte,
                                         char* dst, int wvi, int lane) {
#pragma unroll
    for (int i = 0; i < 2; ++i) {
        int base = (wvi * 2 + i) * 1024;
        int off = base + lane * 16;
        int d = off >> 7, o7 = off & 127;
        __builtin_amdgcn_global_load_lds(
            (const AS1 uint*)(gb + (size_t)d * 1024 + cByte + o7),
            (AS3 uint*)(dst + base), 16, 0, 0);
    }
}

// ---- mask 64^3 -> 8^3 trilinear ----
__global__ void k_m8(const float* __restrict__ mask, float* __restrict__ m8) {
    int b = blockIdx.x, sp = threadIdx.x;
    int a = sp >> 6, bb = (sp >> 3) & 7, cc = sp & 7;
    const float* mb = mask + (size_t)b * 262144;
    int i0 = 8 * a + 3, j0 = 8 * bb + 3, k0 = 8 * cc + 3;
    float s = 0.f;
#pragma unroll
    for (int di = 0; di < 2; ++di)
#pragma unroll
        for (int dj = 0; dj < 2; ++dj)
#pragma unroll
            for (int dk = 0; dk < 2; ++dk)
                s += mb[(i0 + di) * 4096 + (j0 + dj) * 64 + (k0 + dk)];
    m8[b * NS + sp] = s * 0.125f;
}

// ---- tok[b][s][d] = x[b][d][s]*m8[b][s] + pe[d][s] ----
__global__ void k_tok(const float* __restrict__ x, const float* __restrict__ pe,
                      const float* __restrict__ m8, float* __restrict__ tok) {
    __shared__ float t[32][33];
    int b = blockIdx.z;
    int sp0 = blockIdx.x * 32, d0 = blockIdx.y * 32;
    int tx = threadIdx.x, ty = threadIdx.y;
#pragma unroll
    for (int i = 0; i < 4; ++i) {
        int d = d0 + ty + i * 8;
        int sp = sp0 + tx;
        float v = x[((size_t)(b * ND + d)) * NS + sp] * m8[b * NS + sp] + pe[(size_t)d * NS + sp];
        t[ty + i * 8][tx] = v;
    }
    __syncthreads();
#pragma unroll
    for (int i = 0; i < 4; ++i) {
        int sp = sp0 + ty + i * 8;
        int d = d0 + tx;
        tok[((size_t)(b * NS) + sp) * ND + d] = t[tx][ty + i * 8];
    }
}

// ---- mem_k fp32 -> bf16 hi/lo pre-swizzled rows [m][64] ----
__global__ void k_mksplit(const float* __restrict__ mk, ushort* __restrict__ mh,
                          ushort* __restrict__ ml) {
    int t = blockIdx.x * 256 + threadIdx.x;
    int g = t & 7;
    int m = (t >> 3) & 8191;
    int b = t >> 16;
    const float* src = mk + ((size_t)(b * NM + m) * 64 + g * 8);
    float v[8];
#pragma unroll
    for (int j = 0; j < 8; ++j) v[j] = src[j];
    s16x8 hv, lv;
    split8(v, hv, lv);
    size_t rowbyte = (size_t)(b * NM + m) * 128;
    size_t off = rowbyte + (size_t)((g * 16) ^ ((m & 7) << 4));
    *(s16x8*)((char*)mh + off) = hv;
    *(s16x8*)((char*)ml + off) = lv;
}

// ---- mem_k [B,M,64] -> memkT [B,64,M] (mid path) ----
__global__ void k_memkT(const float* __restrict__ mk, float* __restrict__ mt) {
    __shared__ float t[32][33];
    int b = blockIdx.z;
    int m0 = blockIdx.x * 32, d0 = blockIdx.y * 32;
    int tx = threadIdx.x, ty = threadIdx.y;
    const float* src = mk + (size_t)b * NM * NHD;
    float* dst = mt + (size_t)b * NHD * NM;
#pragma unroll
    for (int i = 0; i < 4; ++i)
        t[ty + i * 8][tx] = src[(size_t)(m0 + ty + i * 8) * NHD + d0 + tx];
    __syncthreads();
#pragma unroll
    for (int i = 0; i < 4; ++i)
        dst[(size_t)(d0 + ty + i * 8) * NM + m0 + tx] = t[tx][ty + i * 8];
}

// ---- qmat (mid path), h-major rows ----
__global__ void k_qmat(const float* __restrict__ qkv, float* __restrict__ qmat) {
    int id = blockIdx.x * 256 + threadIdx.x;
    int r = id >> 4, dj = (id & 15) * 4;
    int b = r >> 12, h = (r >> 9) & 7, s = r & 511;
    float4 v = *(const float4*)&qkv[((size_t)(b * NS + s)) * 1536 + h * 64 + dj];
    v.x *= 0.125f; v.y *= 0.125f; v.z *= 0.125f; v.w *= 0.125f;
    *(float4*)&qmat[(size_t)r * 64 + dj] = v;
}

// ---- W [K][N] fp32 -> transposed split bf16 [N][K] hi/lo, swizzled rows ----
__global__ void k_wsplitT(const float* __restrict__ W, ushort* __restrict__ WH,
                          ushort* __restrict__ WL, int K, int N) {
    __shared__ float t[32][65];
    int l = blockIdx.z;
    const float* Wl = W + (size_t)l * K * N;
    ushort* WHl = WH + (size_t)l * N * K;
    ushort* WLl = WL + (size_t)l * N * K;
    int n0 = blockIdx.x * 32, k0 = blockIdx.y * 64;
    int tx = threadIdx.x, ty = threadIdx.y;
#pragma unroll
    for (int i = 0; i < 8; ++i) {
        int k = ty * 8 + i;
        t[tx][k] = Wl[(size_t)(k0 + k) * N + n0 + tx];
    }
    __syncthreads();
    int tid = ty * 32 + tx;
    int r = tid >> 3, gg = tid & 7;
    float v[8];
#pragma unroll
    for (int j = 0; j < 8; ++j) v[j] = t[r][gg * 8 + j];
    s16x8 hv, lv;
    split8(v, hv, lv);
    size_t byte = (size_t)(n0 + r) * (2 * K) + (size_t)(k0 >> 6) * 128 +
                  (size_t)(((gg * 16)) ^ ((r & 7) << 4));
    *(s16x8*)((char*)WHl + byte) = hv;
    *(s16x8*)((char*)WLl + byte) = lv;
}

// ---- activation X [M][K] fp32 -> split bf16 hi/lo swizzled rows ----
__global__ void k_asplit(const float* __restrict__ X, ushort* __restrict__ XH,
                         ushort* __restrict__ XL, int K) {
    int id = blockIdx.x * 256 + threadIdx.x;
    int gtot = K >> 3;
    int m = id / gtot, g = id - m * gtot;
    const float* src = X + (size_t)m * K + g * 8;
    float v[8];
    *(float4*)&v[0] = *(const float4*)(src);
    *(float4*)&v[4] = *(const float4*)(src + 4);
    s16x8 hv, lv;
    split8(v, hv, lv);
    int kc = g >> 3, gg = g & 7;
    size_t byte = (size_t)m * (2 * K) + (size_t)kc * 128 +
                  (size_t)((gg * 16) ^ ((m & 7) << 4));
    *(s16x8*)((char*)XH + byte) = hv;
    *(s16x8*)((char*)XL + byte) = lv;
}

// ---- OLD split-bf16 MFMA GEMM (mid-path only) ----
template <int BM, int BN, int EPI>
__global__ __launch_bounds__(256) void k_gmm(
    const float* __restrict__ A, const float* __restrict__ W,
    const float* __restrict__ bias, const float* __restrict__ resid,
    float* __restrict__ C, int M, int N, int K) {
    constexpr int PAD = 40;
    constexpr int FM = BM / 32, FN = BN / 32;
    __shared__ __align__(16) ushort Ah[BM * PAD];
    __shared__ __align__(16) ushort Al[BM * PAD];
    __shared__ __align__(16) ushort Bh[BN * PAD];
    __shared__ __align__(16) ushort Bl[BN * PAD];
    int tid = threadIdx.x, lane = tid & 63, wvi = tid >> 6;
    int wr = wvi >> 1, wc = wvi & 1;
    int bn = blockIdx.x * BN, bm = blockIdx.y * BM;
    constexpr int FPTA = BM / 8;
    constexpr int TPRA = 32 / FPTA;
    int arow = tid / TPRA;
    int akoff = (tid % TPRA) * FPTA;
    const float* Ap = A + (size_t)(bm + arow) * K + akoff;
    constexpr int FPTB = BN / 8;
    int bkrow = tid >> 3;
    int bnoff = (tid & 7) * FPTB;
    const float* Wp = W + (size_t)bkrow * N + bn + bnoff;
    float abuf[FPTA], bbuf[FPTB];
#pragma unroll
    for (int j = 0; j < FPTA; j += 4) *(float4*)&abuf[j] = *(const float4*)(Ap + j);
#pragma unroll
    for (int j = 0; j < FPTB; j += 4) *(float4*)&bbuf[j] = *(const float4*)(Wp + j);
    f32x4 acc[FM][FN] = {};
    for (int k0 = 0; k0 < K; k0 += 32) {
#pragma unroll
        for (int g = 0; g < FPTA / 8; ++g) {
            s16x8 hv, lv;
            split8(&abuf[g * 8], hv, lv);
            *(s16x8*)&Ah[arow * PAD + akoff + g * 8] = hv;
            *(s16x8*)&Al[arow * PAD + akoff + g * 8] = lv;
        }
#pragma unroll
        for (int j = 0; j < FPTB; ++j) {
            ushort h, l;
            split1(bbuf[j], h, l);
            Bh[(bnoff + j) * PAD + bkrow] = h;
            Bl[(bnoff + j) * PAD + bkrow] = l;
        }
        __syncthreads();
        if (k0 + 32 < K) {
#pragma unroll
            for (int j = 0; j < FPTA; j += 4)
                *(float4*)&abuf[j] = *(const float4*)(Ap + k0 + 32 + j);
#pragma unroll
            for (int j = 0; j < FPTB; j += 4)
                *(float4*)&bbuf[j] = *(const float4*)(Wp + (size_t)(k0 + 32) * N + j);
        }
        s16x8 fah[FM], fal[FM], fbh[FN], fbl[FN];
        int kb = (lane >> 4) * 8;
#pragma unroll
        for (int fm = 0; fm < FM; ++fm) {
            int row = wr * (BM / 2) + fm * 16 + (lane & 15);
            fah[fm] = *(const s16x8*)&Ah[row * PAD + kb];
            fal[fm] = *(const s16x8*)&Al[row * PAD + kb];
        }
#pragma unroll
        for (int fn = 0; fn < FN; ++fn) {
            int row = wc * (BN / 2) + fn * 16 + (lane & 15);
            fbh[fn] = *(const s16x8*)&Bh[row * PAD + kb];
            fbl[fn] = *(const s16x8*)&Bl[row * PAD + kb];
        }
#pragma unroll
        for (int fm = 0; fm < FM; ++fm)
#pragma unroll
            for (int fn = 0; fn < FN; ++fn) {
                acc[fm][fn] = __builtin_amdgcn_mfma_f32_16x16x32_bf16(fah[fm], fbh[fn], acc[fm][fn], 0, 0, 0);
                acc[fm][fn] = __builtin_amdgcn_mfma_f32_16x16x32_bf16(fah[fm], fbl[fn], acc[fm][fn], 0, 0, 0);
                acc[fm][fn] = __builtin_amdgcn_mfma_f32_16x16x32_bf16(fal[fm], fbh[fn], acc[fm][fn], 0, 0, 0);
            }
        __syncthreads();
    }
#pragma unroll
    for (int fm = 0; fm < FM; ++fm) {
#pragma unroll
        for (int fn = 0; fn < FN; ++fn) {
            int n = bn + wc * (BN / 2) + fn * 16 + (lane & 15);
            float bb = 0.f;
            if (EPI != 3) bb = bias[n];
#pragma unroll
            for (int r = 0; r < 4; ++r) {
                int m = bm + wr * (BM / 2) + fm * 16 + (lane >> 4) * 4 + r;
                float o = acc[fm][fn][r] + bb;
                if (EPI == 1) o = gelu_f(o);
                else if (EPI == 2) o += resid[(size_t)m * N + n];
                C[(size_t)m * N + n] = o;
            }
        }
    }
}

// ---- pure-bf16 MFMA GEMM: pre-split swizzled operands, DMA staging ----
// EPI: 0 bias, 1 bias+gelu, 2 bias+resid, 3 plain, 4 bias+gelu->split CH/CL,
//      5 qkv fused split epilogue. bsA/bsB/bsC: per-blockIdx.z element strides.
template <int BM, int BN, int EPI>
__global__ __launch_bounds__(256) void k_gmm2(
    const ushort* __restrict__ AH, const ushort* __restrict__ AL,
    const ushort* __restrict__ BH, const ushort* __restrict__ BL,
    const float* __restrict__ bias, const float* __restrict__ resid,
    float* __restrict__ C, ushort* __restrict__ CH, ushort* __restrict__ CL,
    ushort* __restrict__ C2H, ushort* __restrict__ C2L,
    ushort* __restrict__ C3H, ushort* __restrict__ C3L,
    int M, int N, int K, size_t bsA, size_t bsB, size_t bsC) {
    constexpr int FM = BM / 32, FN = BN / 32;
    __shared__ __align__(16) ushort sAh[BM * 64];
    __shared__ __align__(16) ushort sAl[BM * 64];
    __shared__ __align__(16) ushort sBh[BN * 64];
    __shared__ __align__(16) ushort sBl[BN * 64];
    int bz = blockIdx.z;
    AH += (size_t)bz * bsA; AL += (size_t)bz * bsA;
    BH += (size_t)bz * bsB; BL += (size_t)bz * bsB;
    if (C) C += (size_t)bz * bsC;
    int tid = threadIdx.x, lane = tid & 63, wvi = tid >> 6;
    int wr = wvi >> 1, wc = wvi & 1;
    int bn = blockIdx.x * BN, bm = blockIdx.y * BM;
    int rloc = tid >> 3, bgr = (tid & 7) * 16;
    size_t rowstride = (size_t)(2 * K);
    f32x4 acc[FM][FN] = {};

    for (int k0 = 0; k0 < K; k0 += 64) {
        __syncthreads();
        size_t kcb = (size_t)k0 * 2;
#pragma unroll
        for (int i = 0; i < BM / 32; ++i) {
            int r = i * 32 + rloc;
            size_t g = (size_t)(bm + r) * rowstride + kcb + bgr;
            __builtin_amdgcn_global_load_lds((const AS1 uint*)((const char*)AH + g),
                                             (AS3 uint*)((char*)sAh + r * 128 + bgr), 16, 0, 0);
            __builtin_amdgcn_global_load_lds((const AS1 uint*)((const char*)AL + g),
                                             (AS3 uint*)((char*)sAl + r * 128 + bgr), 16, 0, 0);
        }
#pragma unroll
        for (int i = 0; i < BN / 32; ++i) {
            int r = i * 32 + rloc;
            size_t g = (size_t)(bn + r) * rowstride + kcb + bgr;
            __builtin_amdgcn_global_load_lds((const AS1 uint*)((const char*)BH + g),
                                             (AS3 uint*)((char*)sBh + r * 128 + bgr), 16, 0, 0);
            __builtin_amdgcn_global_load_lds((const AS1 uint*)((const char*)BL + g),
                                             (AS3 uint*)((char*)sBl + r * 128 + bgr), 16, 0, 0);
        }
        __syncthreads();
#pragma unroll
        for (int ks = 0; ks < 2; ++ks) {
            int kbyte = (ks * 32 + (lane >> 4) * 8) * 2;
            s16x8 fah[FM], fal[FM], fbh[FN], fbl[FN];
#pragma unroll
            for (int fm = 0; fm < FM; ++fm) {
                int row = wr * (BM / 2) + fm * 16 + (lane & 15);
                int by = row * 128 + (kbyte ^ ((row & 7) << 4));
                fah[fm] = *(const s16x8*)((const char*)sAh + by);
                fal[fm] = *(const s16x8*)((const char*)sAl + by);
            }
#pragma unroll
            for (int fn = 0; fn < FN; ++fn) {
                int row = wc * (BN / 2) + fn * 16 + (lane & 15);
                int by = row * 128 + (kbyte ^ ((row & 7) << 4));
                fbh[fn] = *(const s16x8*)((const char*)sBh + by);
                fbl[fn] = *(const s16x8*)((const char*)sBl + by);
            }
#pragma unroll
            for (int fm = 0; fm < FM; ++fm)
#pragma unroll
                for (int fn = 0; fn < FN; ++fn) {
                    acc[fm][fn] = __builtin_amdgcn_mfma_f32_16x16x32_bf16(fah[fm], fbh[fn], acc[fm][fn], 0, 0, 0);
                    acc[fm][fn] = __builtin_amdgcn_mfma_f32_16x16x32_bf16(fah[fm], fbl[fn], acc[fm][fn], 0, 0, 0);
                    acc[fm][fn] = __builtin_amdgcn_mfma_f32_16x16x32_bf16(fal[fm], fbh[fn], acc[fm][fn], 0, 0, 0);
                }
        }
    }
#pragma unroll
    for (int fm = 0; fm < FM; ++fm) {
#pragma unroll
        for (int fn = 0; fn < FN; ++fn) {
            int n = bn + wc * (BN / 2) + fn * 16 + (lane & 15);
            float bb = 0.f;
            if (EPI != 3) bb = bias[n];
#pragma unroll
            for (int r = 0; r < 4; ++r) {
                int m = bm + wr * (BM / 2) + fm * 16 + (lane >> 4) * 4 + r;
                float o = acc[fm][fn][r] + bb;
                if (EPI == 4) {
                    o = gelu_f(o);
                    ushort hh, ll;
                    split1(o, hh, ll);
                    size_t byb = (size_t)m * 2 * N + (size_t)(n >> 6) * 128 +
                                 (size_t)(((((n >> 3) & 7) * 16)) ^ ((m & 7) << 4)) + (n & 7) * 2;
                    *(ushort*)((char*)CH + byb) = hh;
                    *(ushort*)((char*)CL + byb) = ll;
                } else if (EPI == 5) {
                    int seg = n >> 9;  // block-uniform
                    int hh_ = (n >> 6) & 7, dd = n & 63;
                    int bq = m >> 9, sq = m & 511;
                    ushort hh, ll;
                    if (seg == 0) {
                        split1(o * 0.125f, hh, ll);
                        size_t rr = (size_t)bq * 4096 + hh_ * 512 + sq;
                        size_t by = rr * 128 + (size_t)((((dd >> 3) * 16)) ^ ((sq & 7) << 4)) + (dd & 7) * 2;
                        *(ushort*)((char*)CH + by) = hh;
                        *(ushort*)((char*)CL + by) = ll;
                    } else if (seg == 1) {
                        split1(o, hh, ll);
                        size_t rr = (size_t)bq * 4096 + hh_ * 512 + sq;
                        size_t by = rr * 128 + (size_t)((((dd >> 3) * 16)) ^ ((sq & 7) << 4)) + (dd & 7) * 2;
                        *(ushort*)((char*)C2H + by) = hh;
                        *(ushort*)((char*)C2L + by) = ll;
                    } else {
                        split1(o, hh, ll);
                        size_t rr = (size_t)(bq * 8 + hh_) * 64 + dd;
                        size_t by = rr * 1024 + (size_t)(sq >> 6) * 128 +
                                    (size_t)(((((sq >> 3) & 7) * 16)) ^ ((dd & 7) << 4)) + (sq & 7) * 2;
                        *(ushort*)((char*)C3H + by) = hh;
                        *(ushort*)((char*)C3L + by) = ll;
                    }
                } else {
                    if (EPI == 1) o = gelu_f(o);
                    else if (EPI == 2) o += resid[(size_t)m * N + n];
                    C[(size_t)m * N + n] = o;
                }
            }
        }
    }
}

// ---- MFMA flash attention: grid (8 qt, NH, NB), 256 thr = 4 waves ----
__global__ __launch_bounds__(256) void k_attn2(
    const ushort* __restrict__ QH, const ushort* __restrict__ QL,
    const ushort* __restrict__ KH, const ushort* __restrict__ KL,
    const ushort* __restrict__ VTH, const ushort* __restrict__ VTL,
    float* __restrict__ ao) {
    __shared__ __align__(16) char SM[81920];
    int qt = blockIdx.x, h = blockIdx.y, b = blockIdx.z;
    int tid = threadIdx.x, lane = tid & 63, wvi = tid >> 6;
    size_t R = ((size_t)(b * NH + h)) * NS;
    const char* KHg = (const char*)KH + R * 128;
    const char* KLg = (const char*)KL + R * 128;
    const char* VHg = (const char*)VTH + ((size_t)(b * NH + h) * 64) * 1024;
    const char* VLg = (const char*)VTL + ((size_t)(b * NH + h) * 64) * 1024;

    stage_lin((const char*)QH + (R + qt * 64) * 128, SM + 65536, wvi, lane);
    stage_lin((const char*)QL + (R + qt * 64) * 128, SM + 73728, wvi, lane);
    stage_lin(KHg, SM + 0, wvi, lane);
    stage_lin(KLg, SM + 8192, wvi, lane);
    stage_vt(VHg, 0, SM + 32768, wvi, lane);
    stage_vt(VLg, 0, SM + 40960, wvi, lane);
    __syncthreads();

    s16x8 fqh[2], fql[2];
#pragma unroll
    for (int ks = 0; ks < 2; ++ks) {
        int row = wvi * 16 + (lane & 15);
        int by = row * 128 + ((((ks * 32 + (lane >> 4) * 8) * 2)) ^ ((row & 7) << 4));
        fqh[ks] = *(const s16x8*)(SM + 65536 + by);
        fql[ks] = *(const s16x8*)(SM + 73728 + by);
    }

    float mr_[4] = {-FLT_MAX, -FLT_MAX, -FLT_MAX, -FLT_MAX};
    float lr_[4] = {0.f, 0.f, 0.f, 0.f};
    f32x4 acc_o[4] = {};

    for (int c = 0; c < 8; ++c) {
        const char* khc = SM + ((c & 1) ? 16384 : 0);
        const char* klc = khc + 8192;
        const char* vhc = SM + 32768 + ((c & 1) ? 16384 : 0);
        const char* vlc = vhc + 8192;
        if (c + 1 < 8) {
            char* khn = SM + ((c & 1) ? 0 : 16384);
            char* vhn = SM + 32768 + ((c & 1) ? 0 : 16384);
            stage_lin(KHg + (size_t)(c + 1) * 8192, khn, wvi, lane);
            stage_lin(KLg + (size_t)(c + 1) * 8192, khn + 8192, wvi, lane);
            stage_vt(VHg, (c + 1) * 128, vhn, wvi, lane);
            stage_vt(VLg, (c + 1) * 128, vhn + 8192, wvi, lane);
        }
        f32x4 sa[4] = {};
#pragma unroll
        for (int ks = 0; ks < 2; ++ks) {
            int kbyte = (ks * 32 + (lane >> 4) * 8) * 2;
#pragma unroll
            for (int fk = 0; fk < 4; ++fk) {
                int krow = fk * 16 + (lane & 15);
                int by = krow * 128 + (kbyte ^ ((krow & 7) << 4));
                s16x8 kh8 = *(const s16x8*)(khc + by);
                s16x8 kl8 = *(const s16x8*)(klc + by);
                sa[fk] = __builtin_amdgcn_mfma_f32_16x16x32_bf16(fqh[ks], kh8, sa[fk], 0, 0, 0);
                sa[fk] = __builtin_amdgcn_mfma_f32_16x16x32_bf16(fqh[ks], kl8, sa[fk], 0, 0, 0);
                sa[fk] = __builtin_amdgcn_mfma_f32_16x16x32_bf16(fql[ks], kh8, sa[fk], 0, 0, 0);
            }
        }
#pragma unroll
        for (int r = 0; r < 4; ++r) {
            float smax = fmaxf(fmaxf(sa[0][r], sa[1][r]), fmaxf(sa[2][r], sa[3][r]));
            smax = fmaxf(smax, __shfl_xor(smax, 1));
            smax = fmaxf(smax, __shfl_xor(smax, 2));
            smax = fmaxf(smax, __shfl_xor(smax, 4));
            smax = fmaxf(smax, __shfl_xor(smax, 8));
            float mn = fmaxf(mr_[r], smax);
            float alpha = __expf(mr_[r] - mn);
            mr_[r] = mn;
            float p0 = __expf(sa[0][r] - mn);
            float p1 = __expf(sa[1][r] - mn);
            float p2 = __expf(sa[2][r] - mn);
            float p3 = __expf(sa[3][r] - mn);
            float ls = p0 + p1 + p2 + p3;
            ls += __shfl_xor(ls, 1);
            ls += __shfl_xor(ls, 2);
            ls += __shfl_xor(ls, 4);
            ls += __shfl_xor(ls, 8);
            lr_[r] = lr_[r] * alpha + ls;
#pragma unroll
            for (int fd = 0; fd < 4; ++fd) acc_o[fd][r] *= alpha;
            int prow = wvi * 16 + (lane >> 4) * 4 + r;
            int sw = (prow & 7) << 4;
            int l15 = lane & 15;
            int wb = (l15 & 7) * 2;
            float pv_[4] = {p0, p1, p2, p3};
#pragma unroll
            for (int fk = 0; fk < 4; ++fk) {
                ushort hh, ll;
                split1(pv_[fk], hh, ll);
                int gran = fk * 2 + (l15 >> 3);
                int by = prow * 128 + ((gran * 16) ^ sw) + wb;
                *(ushort*)(SM + 65536 + by) = hh;
                *(ushort*)(SM + 73728 + by) = ll;
            }
        }
        s16x8 fph[2], fpl[2];
#pragma unroll
        for (int ks = 0; ks < 2; ++ks) {
            int prow = wvi * 16 + (lane & 15);
            int by = prow * 128 + ((((ks * 32 + (lane >> 4) * 8) * 2)) ^ ((prow & 7) << 4));
            fph[ks] = *(const s16x8*)(SM + 65536 + by);
            fpl[ks] = *(const s16x8*)(SM + 73728 + by);
        }
#pragma unroll
        for (int ks = 0; ks < 2; ++ks) {
            int kbyte = (ks * 32 + (lane >> 4) * 8) * 2;
#pragma unroll
            for (int fd = 0; fd < 4; ++fd) {
                int vrow = fd * 16 + (lane & 15);
                int by = vrow * 128 + (kbyte ^ ((vrow & 7) << 4));
                s16x8 vh8 = *(const s16x8*)(vhc + by);
                s16x8 vl8 = *(const s16x8*)(vlc + by);
                acc_o[fd] = __builtin_amdgcn_mfma_f32_16x16x32_bf16(fph[ks], vh8, acc_o[fd], 0, 0, 0);
                acc_o[fd] = __builtin_amdgcn_mfma_f32_16x16x32_bf16(fph[ks], vl8, acc_o[fd], 0, 0, 0);
                acc_o[fd] = __builtin_amdgcn_mfma_f32_16x16x32_bf16(fpl[ks], vh8, acc_o[fd], 0, 0, 0);
            }
        }
        __syncthreads();
    }
    float inv_[4];
#pragma unroll
    for (int r = 0; r < 4; ++r) inv_[r] = 1.0f / lr_[r];
#pragma unroll
    for (int fd = 0; fd < 4; ++fd)
#pragma unroll
        for (int r = 0; r < 4; ++r) {
            int srow = qt * 64 + wvi * 16 + (lane >> 4) * 4 + r;
            int col = h * 64 + fd * 16 + (lane & 15);
            ao[((size_t)(b * NS) + srow) * ND + col] = acc_o[fd][r] * inv_[r];
        }
}

// ---- OLD fp32 flash attention (mid/low fallback) ----
__global__ __launch_bounds__(256) void k_attn(const float* __restrict__ qkv,
                                              float* __restrict__ ao) {
    __shared__ float qs[32][65];
    __shared__ float ks[64][65];
    __shared__ float sc[32][68];
    __shared__ float pm[32][8];
    __shared__ float Mrow[32], Srow[32], Arow[32];
    int s0 = blockIdx.x * 32, h = blockIdx.y, b = blockIdx.z;
    int tid = threadIdx.x, tx = tid & 15, ty = tid >> 4;
    const float* base = qkv + (size_t)b * NS * 1536;
#pragma unroll
    for (int i = 0; i < 8; ++i) {
        int idx = tid + i * 256;
        int r = idx >> 6, d = idx & 63;
        qs[r][d] = base[(size_t)(s0 + r) * 1536 + h * 64 + d] * 0.125f;
    }
    if (tid < 32) { Mrow[tid] = -FLT_MAX; Srow[tid] = 0.f; }
    float accp[2][4] = {};
    int rg = tid >> 3, gg = tid & 7;
    for (int c = 0; c < 8; ++c) {
        __syncthreads();
#pragma unroll
        for (int i = 0; i < 16; ++i) {
            int idx = tid + i * 256;
            int r = idx >> 6, d = idx & 63;
            ks[r][d] = base[(size_t)(c * 64 + r) * 1536 + 512 + h * 64 + d];
        }
        __syncthreads();
        float a00 = 0, a01 = 0, a02 = 0, a03 = 0, a10 = 0, a11 = 0, a12 = 0, a13 = 0;
#pragma unroll 8
        for (int d = 0; d < 64; ++d) {
            float q0 = qs[ty][d], q1 = qs[ty + 16][d];
            float k0 = ks[tx][d], k1 = ks[tx + 16][d], k2 = ks[tx + 32][d], k3 = ks[tx + 48][d];
            a00 += q0 * k0; a01 += q0 * k1; a02 += q0 * k2; a03 += q0 * k3;
            a10 += q1 * k0; a11 += q1 * k1; a12 += q1 * k2; a13 += q1 * k3;
        }
        sc[ty][tx] = a00; sc[ty][tx + 16] = a01; sc[ty][tx + 32] = a02; sc[ty][tx + 48] = a03;
        sc[ty + 16][tx] = a10; sc[ty + 16][tx + 16] = a11; sc[ty + 16][tx + 32] = a12; sc[ty + 16][tx + 48] = a13;
        __syncthreads();
        float lm = -FLT_MAX;
#pragma unroll
        for (int j = 0; j < 8; ++j) lm = fmaxf(lm, sc[rg][gg * 8 + j]);
        pm[rg][gg] = lm;
        __syncthreads();
        if (gg == 0) {
            float nm = Mrow[rg];
#pragma unroll
            for (int j = 0; j < 8; ++j) nm = fmaxf(nm, pm[rg][j]);
            Arow[rg] = __expf(Mrow[rg] - nm);
            Mrow[rg] = nm;
        }
        __syncthreads();
        float mr = Mrow[rg];
        float ssp = 0.f;
#pragma unroll
        for (int j = 0; j < 8; ++j) {
            float e = __expf(sc[rg][gg * 8 + j] - mr);
            sc[rg][gg * 8 + j] = e;
            ssp += e;
        }
        pm[rg][gg] = ssp;
        __syncthreads();
        if (gg == 0) {
            float s2 = 0.f;
#pragma unroll
            for (int j = 0; j < 8; ++j) s2 += pm[rg][j];
            Srow[rg] = Srow[rg] * Arow[rg] + s2;
        }
        float al0 = Arow[ty], al1 = Arow[ty + 16];
#pragma unroll
        for (int j = 0; j < 4; ++j) { accp[0][j] *= al0; accp[1][j] *= al1; }
        __syncthreads();
#pragma unroll
        for (int i = 0; i < 16; ++i) {
            int idx = tid + i * 256;
            int r = idx >> 6, d = idx & 63;
            ks[r][d] = base[(size_t)(c * 64 + r) * 1536 + 1024 + h * 64 + d];
        }
        __syncthreads();
#pragma unroll 8
        for (int kk = 0; kk < 64; ++kk) {
            float p0 = sc[ty][kk], p1 = sc[ty + 16][kk];
            float v0 = ks[kk][tx], v1 = ks[kk][tx + 16], v2 = ks[kk][tx + 32], v3 = ks[kk][tx + 48];
            accp[0][0] += p0 * v0; accp[0][1] += p0 * v1; accp[0][2] += p0 * v2; accp[0][3] += p0 * v3;
            accp[1][0] += p1 * v0; accp[1][1] += p1 * v1; accp[1][2] += p1 * v2; accp[1][3] += p1 * v3;
        }
    }
    __syncthreads();
    float inv0 = 1.0f / Srow[ty], inv1 = 1.0f / Srow[ty + 16];
    size_t o0 = ((size_t)(b * NS) + s0 + ty) * ND + h * 64;
    size_t o1 = ((size_t)(b * NS) + s0 + ty + 16) * ND + h * 64;
    ao[o0 + tx] = accp[0][0] * inv0;
    ao[o0 + tx + 16] = accp[0][1] * inv0;
    ao[o0 + tx + 32] = accp[0][2] * inv0;
    ao[o0 + tx + 48] = accp[0][3] * inv0;
    ao[o1 + tx] = accp[1][0] * inv1;
    ao[o1 + tx + 16] = accp[1][1] * inv1;
    ao[o1 + tx + 32] = accp[1][2] * inv1;
    ao[o1 + tx + 48] = accp[1][3] * inv1;
}

// ==== KNN Phase B v4: 4 waves/query quarters + value-search shrink + merge ====
// Block = 1 query; blockIdx.x = query index within chunk; bb = bbase + (gq>>12).
__global__ __launch_bounds__(256) void k_ksel4(
    const float* __restrict__ sims, const float* __restrict__ mv,
    const float* __restrict__ gate, float* __restrict__ ao, int bbase) {
    __shared__ float bval[4][CAPS];
    __shared__ ushort bidx[4][CAPS];
    int tid = threadIdx.x, lane = tid & 63, wvi = tid >> 6;
    int gq = blockIdx.x;
    int bb = bbase + (gq >> 12), q = gq & 4095;
    const float* sr = sims + (size_t)gq * NM + wvi * 2048;
    float* bv = &bval[wvi][0];
    ushort* bi = &bidx[wvi][0];
    unsigned long long lm = (1ULL << lane) - 1;

    // block 0 of this quarter: direct fill
    {
        float4 v = *(const float4*)(sr + lane * 4);
        int m0 = lane * 4;
        int gI = wvi * 2048 + m0;
        bv[m0 + 0] = v.x; bi[m0 + 0] = (ushort)(gI + 0);
        bv[m0 + 1] = v.y; bi[m0 + 1] = (ushort)(gI + 1);
        bv[m0 + 2] = v.z; bi[m0 + 2] = (ushort)(gI + 2);
        bv[m0 + 3] = v.w; bi[m0 + 3] = (ushort)(gI + 3);
    }
    float thr = shrink6v(bv, bi, 256, lane);
    int cnt = 32;

    float4 vA = *(const float4*)(sr + 256 + lane * 4);
    float4 vB = *(const float4*)(sr + 512 + lane * 4);
    for (int i = 1; i < 8; ++i) {
        float4 vC = vB;
        if (i + 2 < 8) vC = *(const float4*)(sr + (size_t)(i + 2) * 256 + lane * 4);
        int m0 = wvi * 2048 + i * 256 + lane * 4;
        bool px = vA.x >= thr, py = vA.y >= thr, pz = vA.z >= thr, pw = vA.w >= thr;
        unsigned long long bx = __ballot(px), by = __ballot(py), bz = __ballot(pz), bw = __ballot(pw);
        int nx = (int)__popcll(bx), ny = (int)__popcll(by), nz = (int)__popcll(bz), nw = (int)__popcll(bw);
        int b0 = cnt, b1 = b0 + nx, b2 = b1 + ny, b3 = b2 + nz;
        if (px) { int p = b0 + (int)__popcll(bx & lm); bv[p] = vA.x; bi[p] = (ushort)(m0 + 0); }
        if (py) { int p = b1 + (int)__popcll(by & lm); bv[p] = vA.y; bi[p] = (ushort)(m0 + 1); }
        if (pz) { int p = b2 + (int)__popcll(bz & lm); bv[p] = vA.z; bi[p] = (ushort)(m0 + 2); }
        if (pw) { int p = b3 + (int)__popcll(bw & lm); bv[p] = vA.w; bi[p] = (ushort)(m0 + 3); }
        cnt = b3 + nw;
        if (cnt >= TRIGS) {  // cnt <= 95+256=351 < CAPS
            thr = shrink6v(bv, bi, cnt, lane);
            cnt = 32;
        }
        vA = vB;
        vB = vC;
    }
    thr = shrink6v(bv, bi, cnt, lane);  // quarter top-32 in slots 0..31
    __syncthreads();

    if (wvi == 0) {
        // merge 4x32 = 128 entries: 2 per lane, exact 45-bit descend
        float v0 = bval[lane >> 5][lane & 31];
        ushort i0 = bidx[lane >> 5][lane & 31];
        float v1 = bval[2 + (lane >> 5)][lane & 31];
        ushort i1 = bidx[2 + (lane >> 5)][lane & 31];
        unsigned long long k0 = packkey(v0, (int)i0);
        unsigned long long k1 = packkey(v1, (int)i1);
        unsigned long long K = 0;
#pragma unroll 1
        for (int bit = 44; bit >= 0; --bit) {
            unsigned long long cand = K | (1ULL << bit);
            int c = (int)__popcll(__ballot(k0 >= cand)) + (int)__popcll(__ballot(k1 >= cand));
            if (c >= 32) K = cand;
        }
        int base = 0;
        {
            unsigned long long m = __ballot(k0 >= K);
            if (k0 >= K) { int p = (int)__popcll(m & lm); bv[p] = v0; bi[p] = i0; }
            base = (int)__popcll(m);
        }
        {
            unsigned long long m = __ballot(k1 >= K);
            if (k1 >= K) { int p = base + (int)__popcll(m & lm); bv[p] = v1; bi[p] = i1; }
        }
        // softmax over slots 0..31
        float val = (lane < 32) ? bv[lane] : -FLT_MAX;
        float mx = val;
#pragma unroll
        for (int off = 32; off; off >>= 1) mx = fmaxf(mx, __shfl_xor(mx, off));
        float e = (lane < 32) ? __expf(val - mx) : 0.f;
        float ssum = e;
#pragma unroll
        for (int off = 32; off; off >>= 1) ssum += __shfl_xor(ssum, off);
        float w = e / ssum;
        if (lane < 32) bv[lane] = w;
        // gather + blend: lane owns d = lane
        float acc = 0.f;
        const float* vb = mv + (size_t)bb * NM * NHD;
#pragma unroll 4
        for (int j = 0; j < 32; ++j) {
            float ww = bv[j];
            int idx = (int)bi[j];
            acc += ww * vb[(size_t)idx * NHD + lane];
        }
        int h = q >> 9, s = q & 511;
        float g = 1.0f / (1.0f + __expf(-gate[h]));
        float* aop = ao + ((size_t)(bb * NS) + s) * ND + h * 64 + lane;
        *aop = *aop * (1.0f - g) + acc * g;
    }
}

// ==== KNN v5 (small-ws fallback) ====
__global__ __launch_bounds__(256, 2) void k_knn5(
    const float* __restrict__ qkv, const ushort* __restrict__ mkh,
    const ushort* __restrict__ mkl, const float* __restrict__ mv,
    const float* __restrict__ gate, float* __restrict__ ao) {
    __shared__ __align__(16) char SM[63760];
    ushort* kh0 = (ushort*)SM;
    ushort* kl0 = (ushort*)(SM + 8192);
    ushort* kh1 = (ushort*)(SM + 16384);
    ushort* kl1 = (ushort*)(SM + 24576);
    float* cval = (float*)(SM + 32768);
    ushort* cidx = (ushort*)(SM + 53248);
    float* thrV = (float*)(SM + 63488);
    int* cnt = (int*)(SM + 63616);
    int* sflag = (int*)(SM + 63744);
    ushort* qh = (ushort*)(SM + 32768);
    ushort* ql = (ushort*)(SM + 36864);
    int b = blockIdx.y, s0 = blockIdx.x * 4;
    int tid = threadIdx.x, lane = tid & 63, wvi = tid >> 6;
    const ushort* mhb = mkh + (size_t)b * NM * 64;
    const ushort* mlb = mkl + (size_t)b * NM * 64;
    {
        int q = tid >> 3, dbase = (tid & 7) * 8;
        const float* src = &qkv[((size_t)(b * NS) + s0 + (q & 3)) * 1536 + (q >> 2) * 64 + dbase];
        float v[8];
#pragma unroll
        for (int j = 0; j < 8; ++j) v[j] = src[j] * 0.125f;
        s16x8 hv, lv;
        split8(v, hv, lv);
        int by = q * 128 + ((dbase * 2) ^ ((q & 7) << 4));
        *(s16x8*)((char*)qh + by) = hv;
        *(s16x8*)((char*)ql + by) = lv;
    }
    stage_dma64(mhb, mlb, kh0, kl0, wvi, lane);
    __syncthreads();
    s16x8 fqh[2][2], fql[2][2];
#pragma unroll
    for (int fq = 0; fq < 2; ++fq)
#pragma unroll
        for (int ks = 0; ks < 2; ++ks) {
            int row = fq * 16 + (lane & 15);
            int kb2 = (ks * 32 + (lane >> 4) * 8) * 2;
            int by = row * 128 + (kb2 ^ ((row & 7) << 4));
            fqh[fq][ks] = *(const s16x8*)((const char*)qh + by);
            fql[fq][ks] = *(const s16x8*)((const char*)ql + by);
        }
    if (tid < 32) { cnt[tid] = 0; thrV[tid] = -FLT_MAX; }
    if (tid == 0) *sflag = 0;
    __syncthreads();
    int qbase4 = (lane >> 4) * 4;
    int mrow = (lane & 15);
    for (int c = 0; c < NCC; ++c) {
        ushort* khc = (c & 1) ? kh1 : kh0;
        ushort* klc = (c & 1) ? kl1 : kl0;
        if (c + 1 < NCC) {
            size_t ro = (size_t)(c + 1) * KCC * 64;
            stage_dma64(mhb + ro, mlb + ro, (c & 1) ? kh0 : kh1, (c & 1) ? kl0 : kl1, wvi, lane);
        }
        float thc[2][4];
#pragma unroll
        for (int fq = 0; fq < 2; ++fq)
#pragma unroll
            for (int r = 0; r < 4; ++r) thc[fq][r] = thrV[fq * 16 + qbase4 + r];
        f32x4 acc[2] = {};
#pragma unroll
        for (int ks = 0; ks < 2; ++ks) {
            int row = wvi * 16 + mrow;
            int kb2 = (ks * 32 + (lane >> 4) * 8) * 2;
            int by = row * 128 + (kb2 ^ ((row & 7) << 4));
            s16x8 kh8 = *(const s16x8*)((const char*)khc + by);
            s16x8 kl8 = *(const s16x8*)((const char*)klc + by);
#pragma unroll
            for (int fq = 0; fq < 2; ++fq) {
                acc[fq] = __builtin_amdgcn_mfma_f32_16x16x32_bf16(fqh[fq][ks], kh8, acc[fq], 0, 0, 0);
                acc[fq] = __builtin_amdgcn_mfma_f32_16x16x32_bf16(fqh[fq][ks], kl8, acc[fq], 0, 0, 0);
                acc[fq] = __builtin_amdgcn_mfma_f32_16x16x32_bf16(fql[fq][ks], kh8, acc[fq], 0, 0, 0);
            }
        }
#pragma unroll
        for (int fq = 0; fq < 2; ++fq)
#pragma unroll
            for (int r = 0; r < 4; ++r) {
                float v = acc[fq][r];
                if (v >= thc[fq][r]) {
                    int q = fq * 16 + qbase4 + r;
                    int pos = atomicAdd(&cnt[q], 1);
                    if (pos < CAPB) {
                        cval[q * CAPB + pos] = v;
                        cidx[q * CAPB + pos] = (ushort)(c * KCC + wvi * 16 + mrow);
                    }
                    if (pos == TRIG) *sflag = 1;
                }
            }
        __syncthreads();
        if (*sflag) {
#pragma unroll 1
            for (int qq = 0; qq < 8; ++qq) {
                int q = wvi * 8 + qq;
                shrink_cheap(cval, cidx, q, cnt[q], lane, &thrV[q]);
                if (lane == 0) cnt[q] = 32;
            }
            if (tid == 0) *sflag = 0;
            __syncthreads();
        }
    }
#pragma unroll 1
    for (int qq = 0; qq < 8; ++qq) {
        int q = wvi * 8 + qq;
        shrink_cheap(cval, cidx, q, cnt[q], lane, nullptr);
    }
    __syncthreads();
    if (tid < 32) {
        int q = tid;
        float mx = -FLT_MAX;
#pragma unroll
        for (int j = 0; j < 32; ++j) mx = fmaxf(mx, cval[q * CAPB + j]);
        float es[32];
        float ssum = 0.f;
#pragma unroll
        for (int j = 0; j < 32; ++j) { es[j] = __expf(cval[q * CAPB + j] - mx); ssum += es[j]; }
        float inv = 1.0f / ssum;
#pragma unroll
        for (int j = 0; j < 32; ++j) cval[q * CAPB + j] = es[j] * inv;
    }
    __syncthreads();
    {
        int q = tid >> 3, dseg = (tid & 7) * 8;
        int h = q >> 2, si = q & 3;
        float r0x = 0, r0y = 0, r0z = 0, r0w = 0, r1x = 0, r1y = 0, r1z = 0, r1w = 0;
        const float* vb = mv + (size_t)b * NM * NHD;
        for (int j = 0; j < 32; ++j) {
            float w = cval[q * CAPB + j];
            int idx = (int)cidx[q * CAPB + j];
            const float* row = vb + (size_t)idx * NHD + dseg;
            float4 v0 = *(const float4*)(row);
            float4 v1 = *(const float4*)(row + 4);
            r0x += w * v0.x; r0y += w * v0.y; r0z += w * v0.z; r0w += w * v0.w;
            r1x += w * v1.x; r1y += w * v1.y; r1z += w * v1.z; r1w += w * v1.w;
        }
        float g = 1.0f / (1.0f + __expf(-gate[h]));
        float omg = 1.0f - g;
        float* aop = ao + ((size_t)(b * NS) + s0 + si) * ND + h * 64 + dseg;
        float rr[8] = {r0x, r0y, r0z, r0w, r1x, r1y, r1z, r1w};
#pragma unroll
        for (int k = 0; k < 8; ++k) aop[k] = aop[k] * omg + rr[k] * g;
    }
}

// ---- LayerNorm (plain, fallback) ----
__global__ __launch_bounds__(256) void k_ln(const float* __restrict__ X,
                                            const float* __restrict__ gam,
                                            const float* __restrict__ bet,
                                            float* __restrict__ Y) {
    __shared__ float red[4];
    __shared__ float sm, sv;
    int r = blockIdx.x, tid = threadIdx.x;
    const float* xr = X + (size_t)r * ND;
    float x0 = xr[tid], x1 = xr[tid + 256];
    float s = x0 + x1;
    for (int off = 32; off; off >>= 1) s += __shfl_down(s, off);
    if ((tid & 63) == 0) red[tid >> 6] = s;
    __syncthreads();
    if (tid == 0) sm = (red[0] + red[1] + red[2] + red[3]) * (1.0f / 512.0f);
    __syncthreads();
    float m = sm;
    float d0 = x0 - m, d1 = x1 - m;
    float vs = d0 * d0 + d1 * d1;
    for (int off = 32; off; off >>= 1) vs += __shfl_down(vs, off);
    if ((tid & 63) == 0) red[tid >> 6] = vs;
    __syncthreads();
    if (tid == 0) sv = rsqrtf((red[0] + red[1] + red[2] + red[3]) * (1.0f / 512.0f) + 1e-5f);
    __syncthreads();
    float rstd = sv;
    Y[(size_t)r * ND + tid] = d0 * rstd * gam[tid] + bet[tid];
    Y[(size_t)r * ND + tid + 256] = d1 * rstd * gam[tid + 256] + bet[tid + 256];
}

// ---- LayerNorm fused with split-bf16 output ----
__global__ __launch_bounds__(256) void k_ln2(const float* __restrict__ X,
                                             const float* __restrict__ gam,
                                             const float* __restrict__ bet,
                                             float* __restrict__ Y,
                                             ushort* __restrict__ YH,
                                             ushort* __restrict__ YL) {
    __shared__ float red[4];
    __shared__ float sm, sv;
    int r = blockIdx.x, tid = threadIdx.x;
    const float* xr = X + (size_t)r * ND;
    float x0 = xr[tid], x1 = xr[tid + 256];
    float s = x0 + x1;
    for (int off = 32; off; off >>= 1) s += __shfl_down(s, off);
    if ((tid & 63) == 0) red[tid >> 6] = s;
    __syncthreads();
    if (tid == 0) sm = (red[0] + red[1] + red[2] + red[3]) * (1.0f / 512.0f);
    __syncthreads();
    float m = sm;
    float d0 = x0 - m, d1 = x1 - m;
    float vs = d0 * d0 + d1 * d1;
    for (int off = 32; off; off >>= 1) vs += __shfl_down(vs, off);
    if ((tid & 63) == 0) red[tid >> 6] = vs;
    __syncthreads();
    if (tid == 0) sv = rsqrtf((red[0] + red[1] + red[2] + red[3]) * (1.0f / 512.0f) + 1e-5f);
    __syncthreads();
    float rstd = sv;
    float y0 = d0 * rstd * gam[tid] + bet[tid];
    float y1 = d1 * rstd * gam[tid + 256] + bet[tid + 256];
    Y[(size_t)r * ND + tid] = y0;
    Y[(size_t)r * ND + tid + 256] = y1;
    int sw = (r & 7) << 4;
    char* oh = (char*)YH + (size_t)r * 1024;
    char* ol = (char*)YL + (size_t)r * 1024;
    ushort hh, ll;
    split1(y0, hh, ll);
    int k0 = tid;
    int by0 = (k0 >> 6) * 128 + ((((k0 >> 3) & 7) * 16) ^ sw) + (k0 & 7) * 2;
    *(ushort*)(oh + by0) = hh;
    *(ushort*)(ol + by0) = ll;
    split1(y1, hh, ll);
    int k1 = tid + 256;
    int by1 = (k1 >> 6) * 128 + ((((k1 >> 3) & 7) * 16) ^ sw) + (k1 & 7) * 2;
    *(ushort*)(oh + by1) = hh;
    *(ushort*)(ol + by1) = ll;
}

// ---- mean pool: stage 1 partials ----
__global__ void k_pool2(const float* __restrict__ tok, float* __restrict__ part) {
    int c = blockIdx.x, b = blockIdx.y;
    int tid = threadIdx.x;
    int sp0 = c * 64;
    float a0 = 0.f, a1 = 0.f;
    const float* base = tok + ((size_t)(b * NS) + sp0) * ND;
#pragma unroll 4
    for (int i = 0; i < 64; ++i) {
        a0 += base[(size_t)i * ND + tid];
        a1 += base[(size_t)i * ND + tid + 256];
    }
    float* dst = part + ((size_t)(c * NB + b)) * ND;
    dst[tid] = a0;
    dst[tid + 256] = a1;
}

// ---- mean pool: stage 2 tree sum ----
__global__ void k_pool3(const float* __restrict__ part, float* __restrict__ pooled) {
    int b = blockIdx.x, d = threadIdx.x;
    float s = 0.f;
#pragma unroll
    for (int c = 0; c < 8; ++c) s += part[((size_t)(c * NB + b)) * ND + d];
    pooled[b * ND + d] = s * (1.0f / 512.0f);
}

__global__ void k_fc1(const float* __restrict__ pooled, const float* __restrict__ w,
                      const float* __restrict__ bias, float* __restrict__ o1) {
    int id = blockIdx.x * 256 + threadIdx.x;
    int b = id >> 10, j = id & 1023;
    float acc = bias[j];
    for (int d = 0; d < ND; ++d) acc += pooled[b * ND + d] * w[(size_t)d * NMLP + j];
    o1[id] = gelu_f(acc);
}

// ---- fc2: one wave per (b,c) output ----
__global__ __launch_bounds__(256) void k_fc2b(const float* __restrict__ o1,
                                              const float* __restrict__ w,
                                              const float* __restrict__ bias,
                                              float* __restrict__ out) {
    int c = blockIdx.x;
    int b = threadIdx.x >> 6, lane = threadIdx.x & 63;
    const float* o1b = o1 + b * NMLP;
    float acc = 0.f;
#pragma unroll
    for (int i = 0; i < 16; ++i) {
        int k = i * 64 + lane;
        acc += o1b[k] * w[(size_t)k * NC + c];
    }
    acc += __shfl_xor(acc, 32);
    acc += __shfl_xor(acc, 16);
    acc += __shfl_xor(acc, 8);
    acc += __shfl_xor(acc, 4);
    acc += __shfl_xor(acc, 2);
    acc += __shfl_xor(acc, 1);
    if (lane == 0) out[b * NC + c] = acc + bias[c];
}

extern "C" void kernel_launch(void* const* d_in, const int* in_sizes, int n_in,
                              void* d_out, int out_size, void* d_ws, size_t ws_size,
                              hipStream_t stream) {
    const float* x    = (const float*)d_in[0];
    const float* mask = (const float*)d_in[1];
    const float* pe   = (const float*)d_in[2];
    const float* Wqkv = (const float*)d_in[3];
    const float* bqkv = (const float*)d_in[4];
    const float* Wo   = (const float*)d_in[5];
    const float* bo   = (const float*)d_in[6];
    const float* ln1g = (const float*)d_in[7];
    const float* ln1b = (const float*)d_in[8];
    const float* W1   = (const float*)d_in[9];
    const float* b1   = (const float*)d_in[10];
    const float* W2   = (const float*)d_in[11];
    const float* b2   = (const float*)d_in[12];
    const float* ln2g = (const float*)d_in[13];
    const float* ln2b = (const float*)d_in[14];
    const float* gate = (const float*)d_in[15];
    const float* memk = (const float*)d_in[16];
    const float* memv = (const float*)d_in[17];
    const float* fc1w = (const float*)d_in[18];
    const float* fc1b = (const float*)d_in[19];
    const float* fc2w = (const float*)d_in[20];
    const float* fc2b_ = (const float*)d_in[21];
    float* out = (float*)d_out;

    float* ws = (float*)d_ws;

    // ---- big-path layout ----
    float* m8     = ws;                         // 2048
    ushort* mkh   = (ushort*)(m8 + 2048);       // 2097152 ush
    ushort* mkl   = mkh + 2097152;              // 2097152 ush
    float* tok    = (float*)(mkl + 2097152);    // 1048576
    float* qkv    = tok + 1048576;              // 3145728 (carved into split bufs)
    float* ao     = qkv + 3145728;              // 1048576
    float* pooled = ao + 1048576;               // 2048
    float* o1     = pooled + 2048;              // 4096
    ushort* aH    = (ushort*)(o1 + 4096);       // 1048576 ush
    ushort* aL    = aH + 1048576;               // 1048576 ush
    ushort* WqTH  = aL + 1048576;               // 4718592 ush
    ushort* WqTL  = WqTH + 4718592;
    ushort* WoTH  = WqTL + 4718592;             // 1572864 ush
    ushort* WoTL  = WoTH + 1572864;
    ushort* W1TH  = WoTL + 1572864;             // 6291456 ush
    ushort* W1TL  = W1TH + 6291456;
    ushort* W2TH  = W1TL + 6291456;             // 6291456 ush
    ushort* W2TL  = W2TH + 6291456;
    float* simsb  = (float*)(W2TL + 6291456);   // >= 32M floats
    // overlays inside simsb (dead during knn):
    ushort* fH  = (ushort*)(simsb + 4194304);
    ushort* fL  = fH + 4194304;
    float* ybuf = simsb + 8388608;
    float* ppart = simsb;                       // pool partials (tail only)
    // carve qkv fp32 region into split buffers (6 x 2MB)
    ushort* QHb  = (ushort*)qkv;
    ushort* QLb  = QHb + 1048576;
    ushort* KHb  = QLb + 1048576;
    ushort* KLb  = KHb + 1048576;
    ushort* VTHb = KLb + 1048576;
    ushort* VTLb = VTHb + 1048576;

    size_t needNew = (size_t)((simsb + 33554432) - ws) * sizeof(float);
    size_t need2   = needNew + (size_t)33554432 * sizeof(float);
    size_t need4   = needNew + (size_t)3 * 33554432 * sizeof(float);

    if (ws_size >= needNew) {
        int cb = (ws_size >= need4) ? 4 : ((ws_size >= need2) ? 2 : 1);
        k_m8<<<NB, 512, 0, stream>>>(mask, m8);
        k_mksplit<<<1024, 256, 0, stream>>>(memk, mkh, mkl);
        k_tok<<<dim3(16, 16, NB), dim3(32, 8), 0, stream>>>(x, pe, m8, tok);
        k_wsplitT<<<dim3(48, 8, 6), dim3(32, 8), 0, stream>>>(Wqkv, WqTH, WqTL, 512, 1536);
        k_wsplitT<<<dim3(16, 8, 6), dim3(32, 8), 0, stream>>>(Wo, WoTH, WoTL, 512, 512);
        k_wsplitT<<<dim3(64, 8, 6), dim3(32, 8), 0, stream>>>(W1, W1TH, W1TL, 512, 2048);
        k_wsplitT<<<dim3(16, 32, 6), dim3(32, 8), 0, stream>>>(W2, W2TH, W2TL, 2048, 512);
        k_asplit<<<512, 256, 0, stream>>>(tok, aH, aL, 512);

        for (int l = 0; l < NL; ++l) {
            k_gmm2<128, 128, 5><<<dim3(12, 16), 256, 0, stream>>>(
                aH, aL, WqTH + (size_t)l * 786432, WqTL + (size_t)l * 786432,
                bqkv + l * 1536, nullptr, nullptr, QHb, QLb, KHb, KLb, VTHb, VTLb,
                2048, 1536, 512, 0, 0, 0);
            k_attn2<<<dim3(8, NH, NB), 256, 0, stream>>>(QHb, QLb, KHb, KLb, VTHb, VTLb, ao);
            if (l == 0) {
                for (int bb0 = 0; bb0 < NB; bb0 += cb) {
                    k_gmm2<128, 128, 3><<<dim3(64, 32, cb), 256, 0, stream>>>(
                        QHb + (size_t)bb0 * 262144, QLb + (size_t)bb0 * 262144,
                        mkh + (size_t)bb0 * 524288, mkl + (size_t)bb0 * 524288,
                        nullptr, nullptr, simsb, nullptr, nullptr, nullptr, nullptr,
                        nullptr, nullptr, 4096, 8192, 64,
                        262144, 524288, 33554432);
                    k_ksel4<<<4096 * cb, 256, 0, stream>>>(simsb, memv, gate, ao, bb0);
                }
            }
            k_asplit<<<512, 256, 0, stream>>>(ao, aH, aL, 512);
            k_gmm2<64, 64, 2><<<dim3(8, 32), 256, 0, stream>>>(
                aH, aL, WoTH + (size_t)l * 262144, WoTL + (size_t)l * 262144,
                bo + l * 512, tok, ybuf, nullptr, nullptr, nullptr, nullptr,
                nullptr, nullptr, 2048, 512, 512, 0, 0, 0);
            k_ln2<<<2048, 256, 0, stream>>>(ybuf, ln1g + l * 512, ln1b + l * 512, tok, aH, aL);
            k_gmm2<128, 128, 4><<<dim3(16, 16), 256, 0, stream>>>(
                aH, aL, W1TH + (size_t)l * 1048576, W1TL + (size_t)l * 1048576,
                b1 + l * 2048, nullptr, nullptr, fH, fL, nullptr, nullptr,
                nullptr, nullptr, 2048, 2048, 512, 0, 0, 0);
            k_gmm2<64, 64, 2><<<dim3(8, 32), 256, 0, stream>>>(
                fH, fL, W2TH + (size_t)l * 1048576, W2TL + (size_t)l * 1048576,
                b2 + l * 512, tok, ybuf, nullptr, nullptr, nullptr, nullptr,
                nullptr, nullptr, 2048, 512, 2048, 0, 0, 0);
            k_ln2<<<2048, 256, 0, stream>>>(ybuf, ln2g + l * 512, ln2b + l * 512, tok, aH, aL);
        }
        k_pool2<<<dim3(8, NB), 256, 0, stream>>>(tok, ppart);
        k_pool3<<<NB, 512, 0, stream>>>(ppart, pooled);
        k_fc1<<<16, 256, 0, stream>>>(pooled, fc1w, fc1b, o1);
        k_fc2b<<<NC, 256, 0, stream>>>(o1, fc2w, fc2b_, out);
        return;
    }

    // ---- MID/LOW fallback ----
    float* m8b     = ws;
    ushort* mkh2   = (ushort*)(m8b + 2048);
    ushort* mkl2   = mkh2 + 2097152;
    float* tok2    = (float*)(mkl2 + 2097152);
    float* qkv2    = tok2 + 1048576;
    float* ao2     = qkv2 + 3145728;
    float* ybuf2   = ao2 + 1048576;
    float* ff12    = ybuf2 + 1048576;
    float* pooled2 = ff12 + 4194304;
    float* o12     = pooled2 + 2048;
    float* qmat2   = o12 + 4096;
    float* memkT2  = qmat2 + 1048576;
    float* simsb2  = memkT2 + 2097152;

    size_t needMid = (size_t)((simsb2 + 33554432) - ws) * sizeof(float);
    bool big = ws_size >= needMid;

    k_m8<<<NB, 512, 0, stream>>>(mask, m8b);
    if (big)
        k_memkT<<<dim3(NM / 32, 2, NB), dim3(32, 8), 0, stream>>>(memk, memkT2);
    else
        k_mksplit<<<1024, 256, 0, stream>>>(memk, mkh2, mkl2);
    k_tok<<<dim3(16, 16, NB), dim3(32, 8), 0, stream>>>(x, pe, m8b, tok2);

    for (int l = 0; l < NL; ++l) {
        k_gmm<128, 128, 0><<<dim3(12, 16), 256, 0, stream>>>(
            tok2, Wqkv + (size_t)l * 512 * 1536, bqkv + l * 1536, nullptr, qkv2, 2048, 1536, 512);
        k_attn<<<dim3(16, NH, NB), 256, 0, stream>>>(qkv2, ao2);
        if (l == 0) {
            if (big) {
                k_qmat<<<1024, 256, 0, stream>>>(qkv2, qmat2);
                for (int bb = 0; bb < NB; ++bb) {
                    k_gmm<128, 128, 3><<<dim3(64, 32), 256, 0, stream>>>(
                        qmat2 + (size_t)bb * 262144, memkT2 + (size_t)bb * 524288,
                        nullptr, nullptr, simsb2, 4096, 8192, 64);
                    k_ksel4<<<4096, 256, 0, stream>>>(simsb2, memv, gate, ao2, bb);
                }
            } else {
                k_knn5<<<dim3(NS / 4, NB), 256, 0, stream>>>(qkv2, mkh2, mkl2, memv, gate, ao2);
            }
        }
        k_gmm<64, 64, 2><<<dim3(8, 32), 256, 0, stream>>>(
            ao2, Wo + (size_t)l * 512 * 512, bo + l * 512, tok2, ybuf2, 2048, 512, 512);
        k_ln<<<2048, 256, 0, stream>>>(ybuf2, ln1g + l * 512, ln1b + l * 512, tok2);
        k_gmm<128, 128, 1><<<dim3(16, 16), 256, 0, stream>>>(
            tok2, W1 + (size_t)l * 512 * 2048, b1 + l * 2048, nullptr, ff12, 2048, 2048, 512);
        k_gmm<64, 64, 2><<<dim3(8, 32), 256, 0, stream>>>(
            ff12, W2 + (size_t)l * 2048 * 512, b2 + l * 512, tok2, ybuf2, 2048, 512, 2048);
        k_ln<<<2048, 256, 0, stream>>>(ybuf2, ln2g + l * 512, ln2b + l * 512, tok2);
    }
    k_pool2<<<dim3(8, NB), 256, 0, stream>>>(tok2, simsb2);
    k_pool3<<<NB, 512, 0, stream>>>(simsb2, pooled2);
    k_fc1<<<16, 256, 0, stream>>>(pooled2, fc1w, fc1b, o12);
    k_fc2b<<<NC, 256, 0, stream>>>(o12, fc2w, fc2b_, out);
}

// Round 18
// 1324.819 us; speedup vs baseline: 1.0436x; 1.0436x over previous
//
#include <hip/hip_runtime.h>
#include <hip/hip_bf16.h>
#include <float.h>
#include <math.h>

// Problem constants
#define NB 4
#define ND 512
#define NS 512
#define NH 8
#define NHD 64
#define NM 8192
#define NL 6
#define NFF 2048
#define NMLP 1024
#define NC 117

// knn5 (fallback) params
#define KCC 64
#define NCC (NM / KCC)
#define CAPB 160
#define TRIG 96

// k_ksel params
#define CAPS 352
#define TRIGS 96

#define AS1 __attribute__((address_space(1)))
#define AS3 __attribute__((address_space(3)))

typedef __attribute__((ext_vector_type(8))) short s16x8;
typedef __attribute__((ext_vector_type(4))) float f32x4;

__device__ __forceinline__ float gelu_f(float x) {
    return 0.5f * x * (1.0f + erff(x * 0.70710678118654752440f));
}

__device__ __forceinline__ ushort f2bf_rne(float x) {
    uint u = __float_as_uint(x);
    uint r = u + 0x7FFFu + ((u >> 16) & 1u);
    return (ushort)(r >> 16);
}
__device__ __forceinline__ float bf2f(ushort h) { return __uint_as_float(((uint)h) << 16); }
__device__ __forceinline__ void split1(float x, ushort& h, ushort& l) {
    h = f2bf_rne(x);
    float r = x - bf2f(h);
    l = f2bf_rne(r);
}
__device__ __forceinline__ void split8(const float* v, s16x8& hv, s16x8& lv) {
#pragma unroll
    for (int j = 0; j < 8; ++j) {
        ushort h, l;
        split1(v[j], h, l);
        hv[j] = (short)h;
        lv[j] = (short)l;
    }
}

// sortable key: (value desc, index asc) -> larger key wins; valid keys nonzero
__device__ __forceinline__ unsigned long long packkey(float v, int idx) {
    uint u = __float_as_uint(v);
    u = u ^ (((int)u < 0) ? 0xFFFFFFFFu : 0x80000000u);
    return (((unsigned long long)u) << 13) | (unsigned long long)(8191 - idx);
}
__device__ __forceinline__ float keyval(unsigned long long K) {
    uint vb = (uint)(K >> 13);
    uint orig = (vb & 0x80000000u) ? (vb ^ 0x80000000u) : ~vb;
    return __uint_as_float(orig);
}
__device__ __forceinline__ uint sortable32(float v) {
    uint u = __float_as_uint(v);
    return u ^ (((int)u < 0) ? 0xFFFFFFFFu : 0x80000000u);
}
__device__ __forceinline__ float unsortable32(uint s) {
    uint u = (s & 0x80000000u) ? (s ^ 0x80000000u) : ~s;
    return __uint_as_float(u);
}

// wave-parallel exact top-32 retain (3 slots/lane) — knn5 fallback path
__device__ __forceinline__ void shrink_cheap(float* __restrict__ cval,
                                             ushort* __restrict__ cidx,
                                             int q, int n, int lane,
                                             float* __restrict__ thrOut) {
    if (n < 32) return;
    int j0 = lane, j1 = lane + 64, j2 = lane + 128;
    bool o0 = j0 < n, o1 = j1 < n, o2 = j2 < n;
    float v0 = o0 ? cval[q * CAPB + j0] : 0.f;
    float v1 = o1 ? cval[q * CAPB + j1] : 0.f;
    float v2 = o2 ? cval[q * CAPB + j2] : 0.f;
    ushort i0 = o0 ? cidx[q * CAPB + j0] : 0;
    ushort i1 = o1 ? cidx[q * CAPB + j1] : 0;
    ushort i2 = o2 ? cidx[q * CAPB + j2] : 0;
    unsigned long long k0 = o0 ? packkey(v0, (int)i0) : 0ULL;
    unsigned long long k1 = o1 ? packkey(v1, (int)i1) : 0ULL;
    unsigned long long k2 = o2 ? packkey(v2, (int)i2) : 0ULL;
    unsigned long long lo = 0, hi = (1ULL << 45) - 1;
    while (lo < hi) {
        unsigned long long mid = (lo + hi + 1) >> 1;
        int c = (int)__popcll(__ballot(k0 >= mid)) + (int)__popcll(__ballot(k1 >= mid)) +
                (int)__popcll(__ballot(k2 >= mid));
        if (c >= 32) lo = mid;
        else hi = mid - 1;
    }
    unsigned long long K = lo;
    unsigned long long lm = (1ULL << lane) - 1;
    int base = 0;
    {
        unsigned long long m = __ballot(k0 >= K);
        if (k0 >= K) { int p = base + (int)__popcll(m & lm); cval[q * CAPB + p] = v0; cidx[q * CAPB + p] = i0; }
        base += (int)__popcll(m);
    }
    {
        unsigned long long m = __ballot(k1 >= K);
        if (k1 >= K) { int p = base + (int)__popcll(m & lm); cval[q * CAPB + p] = v1; cidx[q * CAPB + p] = i1; }
        base += (int)__popcll(m);
    }
    {
        unsigned long long m = __ballot(k2 >= K);
        if (k2 >= K) { int p = base + (int)__popcll(m & lm); cval[q * CAPB + p] = v2; cidx[q * CAPB + p] = i2; }
        base += (int)__popcll(m);
    }
    if (thrOut && lane == 0) *thrOut = keyval(K);
}

// Exact top-32 retain over n<=CAPS (6 slots/lane): value-only 32-bit bitwise
// descend + exact tie fallback (45-bit key). Winners -> slots 0..31 (unsorted).
__device__ __forceinline__ float shrink6v(float* __restrict__ bv,
                                          ushort* __restrict__ bi,
                                          int n, int lane) {
    int j0 = lane, j1 = lane + 64, j2 = lane + 128, j3 = lane + 192, j4 = lane + 256, j5 = lane + 320;
    bool o0 = j0 < n, o1 = j1 < n, o2 = j2 < n, o3 = j3 < n, o4 = j4 < n, o5 = j5 < n;
    float v0 = o0 ? bv[j0] : 0.f, v1 = o1 ? bv[j1] : 0.f, v2 = o2 ? bv[j2] : 0.f;
    float v3 = o3 ? bv[j3] : 0.f, v4 = o4 ? bv[j4] : 0.f, v5 = o5 ? bv[j5] : 0.f;
    ushort i0 = o0 ? bi[j0] : 0, i1 = o1 ? bi[j1] : 0, i2 = o2 ? bi[j2] : 0;
    ushort i3 = o3 ? bi[j3] : 0, i4 = o4 ? bi[j4] : 0, i5 = o5 ? bi[j5] : 0;
    uint s0 = o0 ? sortable32(v0) : 0u, s1 = o1 ? sortable32(v1) : 0u;
    uint s2 = o2 ? sortable32(v2) : 0u, s3 = o3 ? sortable32(v3) : 0u;
    uint s4 = o4 ? sortable32(v4) : 0u, s5 = o5 ? sortable32(v5) : 0u;
    uint S = 0;
#pragma unroll 1
    for (int bit = 31; bit >= 0; --bit) {
        uint cand = S | (1u << bit);
        int c = (int)__popcll(__ballot(s0 >= cand)) + (int)__popcll(__ballot(s1 >= cand)) +
                (int)__popcll(__ballot(s2 >= cand)) + (int)__popcll(__ballot(s3 >= cand)) +
                (int)__popcll(__ballot(s4 >= cand)) + (int)__popcll(__ballot(s5 >= cand));
        if (c >= 32) S = cand;
    }
    unsigned long long g0 = __ballot(s0 > S), g1 = __ballot(s1 > S), g2 = __ballot(s2 > S);
    unsigned long long g3 = __ballot(s3 > S), g4 = __ballot(s4 > S), g5 = __ballot(s5 > S);
    unsigned long long e0 = __ballot(o0 && s0 == S), e1 = __ballot(o1 && s1 == S), e2 = __ballot(o2 && s2 == S);
    unsigned long long e3 = __ballot(o3 && s3 == S), e4 = __ballot(o4 && s4 == S), e5 = __ballot(o5 && s5 == S);
    int cgt = (int)__popcll(g0) + (int)__popcll(g1) + (int)__popcll(g2) +
              (int)__popcll(g3) + (int)__popcll(g4) + (int)__popcll(g5);
    int ceq = (int)__popcll(e0) + (int)__popcll(e1) + (int)__popcll(e2) +
              (int)__popcll(e3) + (int)__popcll(e4) + (int)__popcll(e5);
    unsigned long long lm = (1ULL << lane) - 1;
    if (cgt + ceq == 32) {
        int base = 0;
        if (s0 > S) { int p = base + (int)__popcll(g0 & lm); bv[p] = v0; bi[p] = i0; } base += (int)__popcll(g0);
        if (s1 > S) { int p = base + (int)__popcll(g1 & lm); bv[p] = v1; bi[p] = i1; } base += (int)__popcll(g1);
        if (s2 > S) { int p = base + (int)__popcll(g2 & lm); bv[p] = v2; bi[p] = i2; } base += (int)__popcll(g2);
        if (s3 > S) { int p = base + (int)__popcll(g3 & lm); bv[p] = v3; bi[p] = i3; } base += (int)__popcll(g3);
        if (s4 > S) { int p = base + (int)__popcll(g4 & lm); bv[p] = v4; bi[p] = i4; } base += (int)__popcll(g4);
        if (s5 > S) { int p = base + (int)__popcll(g5 & lm); bv[p] = v5; bi[p] = i5; } base += (int)__popcll(g5);
        if (o0 && s0 == S) { int p = base + (int)__popcll(e0 & lm); bv[p] = v0; bi[p] = i0; } base += (int)__popcll(e0);
        if (o1 && s1 == S) { int p = base + (int)__popcll(e1 & lm); bv[p] = v1; bi[p] = i1; } base += (int)__popcll(e1);
        if (o2 && s2 == S) { int p = base + (int)__popcll(e2 & lm); bv[p] = v2; bi[p] = i2; } base += (int)__popcll(e2);
        if (o3 && s3 == S) { int p = base + (int)__popcll(e3 & lm); bv[p] = v3; bi[p] = i3; } base += (int)__popcll(e3);
        if (o4 && s4 == S) { int p = base + (int)__popcll(e4 & lm); bv[p] = v4; bi[p] = i4; } base += (int)__popcll(e4);
        if (o5 && s5 == S) { int p = base + (int)__popcll(e5 & lm); bv[p] = v5; bi[p] = i5; }
        return unsortable32(S);
    }
    unsigned long long k0 = o0 ? packkey(v0, (int)i0) : 0ULL;
    unsigned long long k1 = o1 ? packkey(v1, (int)i1) : 0ULL;
    unsigned long long k2 = o2 ? packkey(v2, (int)i2) : 0ULL;
    unsigned long long k3 = o3 ? packkey(v3, (int)i3) : 0ULL;
    unsigned long long k4 = o4 ? packkey(v4, (int)i4) : 0ULL;
    unsigned long long k5 = o5 ? packkey(v5, (int)i5) : 0ULL;
    unsigned long long K = 0;
#pragma unroll 1
    for (int bit = 44; bit >= 0; --bit) {
        unsigned long long cand = K | (1ULL << bit);
        int c = (int)__popcll(__ballot(k0 >= cand)) + (int)__popcll(__ballot(k1 >= cand)) +
                (int)__popcll(__ballot(k2 >= cand)) + (int)__popcll(__ballot(k3 >= cand)) +
                (int)__popcll(__ballot(k4 >= cand)) + (int)__popcll(__ballot(k5 >= cand));
        if (c >= 32) K = cand;
    }
    int base = 0;
    {
        unsigned long long m = __ballot(k0 >= K);
        if (k0 >= K) { int p = base + (int)__popcll(m & lm); bv[p] = v0; bi[p] = i0; }
        base += (int)__popcll(m);
    }
    {
        unsigned long long m = __ballot(k1 >= K);
        if (k1 >= K) { int p = base + (int)__popcll(m & lm); bv[p] = v1; bi[p] = i1; }
        base += (int)__popcll(m);
    }
    {
        unsigned long long m = __ballot(k2 >= K);
        if (k2 >= K) { int p = base + (int)__popcll(m & lm); bv[p] = v2; bi[p] = i2; }
        base += (int)__popcll(m);
    }
    {
        unsigned long long m = __ballot(k3 >= K);
        if (k3 >= K) { int p = base + (int)__popcll(m & lm); bv[p] = v3; bi[p] = i3; }
        base += (int)__popcll(m);
    }
    {
        unsigned long long m = __ballot(k4 >= K);
        if (k4 >= K) { int p = base + (int)__popcll(m & lm); bv[p] = v4; bi[p] = i4; }
        base += (int)__popcll(m);
    }
    {
        unsigned long long m = __ballot(k5 >= K);
        if (k5 >= K) { int p = base + (int)__popcll(m & lm); bv[p] = v5; bi[p] = i5; }
        base += (int)__popcll(m);
    }
    return keyval(K);
}

// ---- DMA helpers (rule #21: pre-swizzled sources, linear LDS dest) ----
__device__ __forceinline__ void stage_dma64(const ushort* __restrict__ gh,
                                            const ushort* __restrict__ gl,
                                            ushort* kh, ushort* kl,
                                            int wvi, int lane) {
#pragma unroll
    for (int i = 0; i < 2; ++i) {
        int off = (wvi * 2 + i) * 1024;
        __builtin_amdgcn_global_load_lds(
            (const AS1 uint*)((const char*)gh + off + lane * 16),
            (AS3 uint*)((char*)kh + off), 16, 0, 0);
        __builtin_amdgcn_global_load_lds(
            (const AS1 uint*)((const char*)gl + off + lane * 16),
            (AS3 uint*)((char*)kl + off), 16, 0, 0);
    }
}

// 8KB linear chunk
__device__ __forceinline__ void stage_lin(const char* __restrict__ g, char* dst,
                                          int wvi, int lane) {
#pragma unroll
    for (int i = 0; i < 2; ++i) {
        int base = (wvi * 2 + i) * 1024;
        __builtin_amdgcn_global_load_lds((const AS1 uint*)(g + base + lane * 16),
                                         (AS3 uint*)(dst + base), 16, 0, 0);
    }
}

// 8KB chunk of V^T: 64 rows of 1024B, chunk slice 128B per row
__device__ __forceinline__ void stage_vt(const char* __restrict__ gb, int cByte,
                                         char* dst, int wvi, int lane) {
#pragma unroll
    for (int i = 0; i < 2; ++i) {
        int base = (wvi * 2 + i) * 1024;
        int off = base + lane * 16;
        int d = off >> 7, o7 = off & 127;
        __builtin_amdgcn_global_load_lds(
            (const AS1 uint*)(gb + (size_t)d * 1024 + cByte + o7),
            (AS3 uint*)(dst + base), 16, 0, 0);
    }
}

// ---- mask 64^3 -> 8^3 trilinear ----
__global__ void k_m8(const float* __restrict__ mask, float* __restrict__ m8) {
    int b = blockIdx.x, sp = threadIdx.x;
    int a = sp >> 6, bb = (sp >> 3) & 7, cc = sp & 7;
    const float* mb = mask + (size_t)b * 262144;
    int i0 = 8 * a + 3, j0 = 8 * bb + 3, k0 = 8 * cc + 3;
    float s = 0.f;
#pragma unroll
    for (int di = 0; di < 2; ++di)
#pragma unroll
        for (int dj = 0; dj < 2; ++dj)
#pragma unroll
            for (int dk = 0; dk < 2; ++dk)
                s += mb[(i0 + di) * 4096 + (j0 + dj) * 64 + (k0 + dk)];
    m8[b * NS + sp] = s * 0.125f;
}

// ---- tok[b][s][d] = x[b][d][s]*m8[b][s] + pe[d][s] ----
__global__ void k_tok(const float* __restrict__ x, const float* __restrict__ pe,
                      const float* __restrict__ m8, float* __restrict__ tok) {
    __shared__ float t[32][33];
    int b = blockIdx.z;
    int sp0 = blockIdx.x * 32, d0 = blockIdx.y * 32;
    int tx = threadIdx.x, ty = threadIdx.y;
#pragma unroll
    for (int i = 0; i < 4; ++i) {
        int d = d0 + ty + i * 8;
        int sp = sp0 + tx;
        float v = x[((size_t)(b * ND + d)) * NS + sp] * m8[b * NS + sp] + pe[(size_t)d * NS + sp];
        t[ty + i * 8][tx] = v;
    }
    __syncthreads();
#pragma unroll
    for (int i = 0; i < 4; ++i) {
        int sp = sp0 + ty + i * 8;
        int d = d0 + tx;
        tok[((size_t)(b * NS) + sp) * ND + d] = t[tx][ty + i * 8];
    }
}

// ---- mem_k fp32 -> bf16 hi/lo pre-swizzled rows [m][64] ----
__global__ void k_mksplit(const float* __restrict__ mk, ushort* __restrict__ mh,
                          ushort* __restrict__ ml) {
    int t = blockIdx.x * 256 + threadIdx.x;
    int g = t & 7;
    int m = (t >> 3) & 8191;
    int b = t >> 16;
    const float* src = mk + ((size_t)(b * NM + m) * 64 + g * 8);
    float v[8];
#pragma unroll
    for (int j = 0; j < 8; ++j) v[j] = src[j];
    s16x8 hv, lv;
    split8(v, hv, lv);
    size_t rowbyte = (size_t)(b * NM + m) * 128;
    size_t off = rowbyte + (size_t)((g * 16) ^ ((m & 7) << 4));
    *(s16x8*)((char*)mh + off) = hv;
    *(s16x8*)((char*)ml + off) = lv;
}

// ---- mem_k [B,M,64] -> memkT [B,64,M] (mid path) ----
__global__ void k_memkT(const float* __restrict__ mk, float* __restrict__ mt) {
    __shared__ float t[32][33];
    int b = blockIdx.z;
    int m0 = blockIdx.x * 32, d0 = blockIdx.y * 32;
    int tx = threadIdx.x, ty = threadIdx.y;
    const float* src = mk + (size_t)b * NM * NHD;
    float* dst = mt + (size_t)b * NHD * NM;
#pragma unroll
    for (int i = 0; i < 4; ++i)
        t[ty + i * 8][tx] = src[(size_t)(m0 + ty + i * 8) * NHD + d0 + tx];
    __syncthreads();
#pragma unroll
    for (int i = 0; i < 4; ++i)
        dst[(size_t)(d0 + ty + i * 8) * NM + m0 + tx] = t[tx][ty + i * 8];
}

// ---- qmat (mid path), h-major rows ----
__global__ void k_qmat(const float* __restrict__ qkv, float* __restrict__ qmat) {
    int id = blockIdx.x * 256 + threadIdx.x;
    int r = id >> 4, dj = (id & 15) * 4;
    int b = r >> 12, h = (r >> 9) & 7, s = r & 511;
    float4 v = *(const float4*)&qkv[((size_t)(b * NS + s)) * 1536 + h * 64 + dj];
    v.x *= 0.125f; v.y *= 0.125f; v.z *= 0.125f; v.w *= 0.125f;
    *(float4*)&qmat[(size_t)r * 64 + dj] = v;
}

// ---- W [K][N] fp32 -> transposed split bf16 [N][K] hi/lo, swizzled rows ----
__global__ void k_wsplitT(const float* __restrict__ W, ushort* __restrict__ WH,
                          ushort* __restrict__ WL, int K, int N) {
    __shared__ float t[32][65];
    int l = blockIdx.z;
    const float* Wl = W + (size_t)l * K * N;
    ushort* WHl = WH + (size_t)l * N * K;
    ushort* WLl = WL + (size_t)l * N * K;
    int n0 = blockIdx.x * 32, k0 = blockIdx.y * 64;
    int tx = threadIdx.x, ty = threadIdx.y;
#pragma unroll
    for (int i = 0; i < 8; ++i) {
        int k = ty * 8 + i;
        t[tx][k] = Wl[(size_t)(k0 + k) * N + n0 + tx];
    }
    __syncthreads();
    int tid = ty * 32 + tx;
    int r = tid >> 3, gg = tid & 7;
    float v[8];
#pragma unroll
    for (int j = 0; j < 8; ++j) v[j] = t[r][gg * 8 + j];
    s16x8 hv, lv;
    split8(v, hv, lv);
    size_t byte = (size_t)(n0 + r) * (2 * K) + (size_t)(k0 >> 6) * 128 +
                  (size_t)(((gg * 16)) ^ ((r & 7) << 4));
    *(s16x8*)((char*)WHl + byte) = hv;
    *(s16x8*)((char*)WLl + byte) = lv;
}

// ---- activation X [M][K] fp32 -> split bf16 hi/lo swizzled rows ----
__global__ void k_asplit(const float* __restrict__ X, ushort* __restrict__ XH,
                         ushort* __restrict__ XL, int K) {
    int id = blockIdx.x * 256 + threadIdx.x;
    int gtot = K >> 3;
    int m = id / gtot, g = id - m * gtot;
    const float* src = X + (size_t)m * K + g * 8;
    float v[8];
    *(float4*)&v[0] = *(const float4*)(src);
    *(float4*)&v[4] = *(const float4*)(src + 4);
    s16x8 hv, lv;
    split8(v, hv, lv);
    int kc = g >> 3, gg = g & 7;
    size_t byte = (size_t)m * (2 * K) + (size_t)kc * 128 +
                  (size_t)((gg * 16) ^ ((m & 7) << 4));
    *(s16x8*)((char*)XH + byte) = hv;
    *(s16x8*)((char*)XL + byte) = lv;
}

// ---- OLD split-bf16 MFMA GEMM (mid-path only) ----
template <int BM, int BN, int EPI>
__global__ __launch_bounds__(256) void k_gmm(
    const float* __restrict__ A, const float* __restrict__ W,
    const float* __restrict__ bias, const float* __restrict__ resid,
    float* __restrict__ C, int M, int N, int K) {
    constexpr int PAD = 40;
    constexpr int FM = BM / 32, FN = BN / 32;
    __shared__ __align__(16) ushort Ah[BM * PAD];
    __shared__ __align__(16) ushort Al[BM * PAD];
    __shared__ __align__(16) ushort Bh[BN * PAD];
    __shared__ __align__(16) ushort Bl[BN * PAD];
    int tid = threadIdx.x, lane = tid & 63, wvi = tid >> 6;
    int wr = wvi >> 1, wc = wvi & 1;
    int bn = blockIdx.x * BN, bm = blockIdx.y * BM;
    constexpr int FPTA = BM / 8;
    constexpr int TPRA = 32 / FPTA;
    int arow = tid / TPRA;
    int akoff = (tid % TPRA) * FPTA;
    const float* Ap = A + (size_t)(bm + arow) * K + akoff;
    constexpr int FPTB = BN / 8;
    int bkrow = tid >> 3;
    int bnoff = (tid & 7) * FPTB;
    const float* Wp = W + (size_t)bkrow * N + bn + bnoff;
    float abuf[FPTA], bbuf[FPTB];
#pragma unroll
    for (int j = 0; j < FPTA; j += 4) *(float4*)&abuf[j] = *(const float4*)(Ap + j);
#pragma unroll
    for (int j = 0; j < FPTB; j += 4) *(float4*)&bbuf[j] = *(const float4*)(Wp + j);
    f32x4 acc[FM][FN] = {};
    for (int k0 = 0; k0 < K; k0 += 32) {
#pragma unroll
        for (int g = 0; g < FPTA / 8; ++g) {
            s16x8 hv, lv;
            split8(&abuf[g * 8], hv, lv);
            *(s16x8*)&Ah[arow * PAD + akoff + g * 8] = hv;
            *(s16x8*)&Al[arow * PAD + akoff + g * 8] = lv;
        }
#pragma unroll
        for (int j = 0; j < FPTB; ++j) {
            ushort h, l;
            split1(bbuf[j], h, l);
            Bh[(bnoff + j) * PAD + bkrow] = h;
            Bl[(bnoff + j) * PAD + bkrow] = l;
        }
        __syncthreads();
        if (k0 + 32 < K) {
#pragma unroll
            for (int j = 0; j < FPTA; j += 4)
                *(float4*)&abuf[j] = *(const float4*)(Ap + k0 + 32 + j);
#pragma unroll
            for (int j = 0; j < FPTB; j += 4)
                *(float4*)&bbuf[j] = *(const float4*)(Wp + (size_t)(k0 + 32) * N + j);
        }
        s16x8 fah[FM], fal[FM], fbh[FN], fbl[FN];
        int kb = (lane >> 4) * 8;
#pragma unroll
        for (int fm = 0; fm < FM; ++fm) {
            int row = wr * (BM / 2) + fm * 16 + (lane & 15);
            fah[fm] = *(const s16x8*)&Ah[row * PAD + kb];
            fal[fm] = *(const s16x8*)&Al[row * PAD + kb];
        }
#pragma unroll
        for (int fn = 0; fn < FN; ++fn) {
            int row = wc * (BN / 2) + fn * 16 + (lane & 15);
            fbh[fn] = *(const s16x8*)&Bh[row * PAD + kb];
            fbl[fn] = *(const s16x8*)&Bl[row * PAD + kb];
        }
#pragma unroll
        for (int fm = 0; fm < FM; ++fm)
#pragma unroll
            for (int fn = 0; fn < FN; ++fn) {
                acc[fm][fn] = __builtin_amdgcn_mfma_f32_16x16x32_bf16(fah[fm], fbh[fn], acc[fm][fn], 0, 0, 0);
                acc[fm][fn] = __builtin_amdgcn_mfma_f32_16x16x32_bf16(fah[fm], fbl[fn], acc[fm][fn], 0, 0, 0);
                acc[fm][fn] = __builtin_amdgcn_mfma_f32_16x16x32_bf16(fal[fm], fbh[fn], acc[fm][fn], 0, 0, 0);
            }
        __syncthreads();
    }
#pragma unroll
    for (int fm = 0; fm < FM; ++fm) {
#pragma unroll
        for (int fn = 0; fn < FN; ++fn) {
            int n = bn + wc * (BN / 2) + fn * 16 + (lane & 15);
            float bb = 0.f;
            if (EPI != 3) bb = bias[n];
#pragma unroll
            for (int r = 0; r < 4; ++r) {
                int m = bm + wr * (BM / 2) + fm * 16 + (lane >> 4) * 4 + r;
                float o = acc[fm][fn][r] + bb;
                if (EPI == 1) o = gelu_f(o);
                else if (EPI == 2) o += resid[(size_t)m * N + n];
                C[(size_t)m * N + n] = o;
            }
        }
    }
}

// ---- pure-bf16 MFMA GEMM: pre-split swizzled operands, DMA staging ----
// EPI: 0 bias, 1 bias+gelu, 2 bias+resid, 3 plain, 4 bias+gelu->split CH/CL,
//      5 qkv fused split epilogue. bsA/bsB/bsC: per-blockIdx.z element strides.
template <int BM, int BN, int EPI>
__global__ __launch_bounds__(256) void k_gmm2(
    const ushort* __restrict__ AH, const ushort* __restrict__ AL,
    const ushort* __restrict__ BH, const ushort* __restrict__ BL,
    const float* __restrict__ bias, const float* __restrict__ resid,
    float* __restrict__ C, ushort* __restrict__ CH, ushort* __restrict__ CL,
    ushort* __restrict__ C2H, ushort* __restrict__ C2L,
    ushort* __restrict__ C3H, ushort* __restrict__ C3L,
    int M, int N, int K, size_t bsA, size_t bsB, size_t bsC) {
    constexpr int FM = BM / 32, FN = BN / 32;
    __shared__ __align__(16) ushort sAh[BM * 64];
    __shared__ __align__(16) ushort sAl[BM * 64];
    __shared__ __align__(16) ushort sBh[BN * 64];
    __shared__ __align__(16) ushort sBl[BN * 64];
    int bz = blockIdx.z;
    AH += (size_t)bz * bsA; AL += (size_t)bz * bsA;
    BH += (size_t)bz * bsB; BL += (size_t)bz * bsB;
    if (C) C += (size_t)bz * bsC;
    int tid = threadIdx.x, lane = tid & 63, wvi = tid >> 6;
    int wr = wvi >> 1, wc = wvi & 1;
    int bn = blockIdx.x * BN, bm = blockIdx.y * BM;
    int rloc = tid >> 3, bgr = (tid & 7) * 16;
    size_t rowstride = (size_t)(2 * K);
    f32x4 acc[FM][FN] = {};

    for (int k0 = 0; k0 < K; k0 += 64) {
        __syncthreads();
        size_t kcb = (size_t)k0 * 2;
#pragma unroll
        for (int i = 0; i < BM / 32; ++i) {
            int r = i * 32 + rloc;
            size_t g = (size_t)(bm + r) * rowstride + kcb + bgr;
            __builtin_amdgcn_global_load_lds((const AS1 uint*)((const char*)AH + g),
                                             (AS3 uint*)((char*)sAh + r * 128 + bgr), 16, 0, 0);
            __builtin_amdgcn_global_load_lds((const AS1 uint*)((const char*)AL + g),
                                             (AS3 uint*)((char*)sAl + r * 128 + bgr), 16, 0, 0);
        }
#pragma unroll
        for (int i = 0; i < BN / 32; ++i) {
            int r = i * 32 + rloc;
            size_t g = (size_t)(bn + r) * rowstride + kcb + bgr;
            __builtin_amdgcn_global_load_lds((const AS1 uint*)((const char*)BH + g),
                                             (AS3 uint*)((char*)sBh + r * 128 + bgr), 16, 0, 0);
            __builtin_amdgcn_global_load_lds((const AS1 uint*)((const char*)BL + g),
                                             (AS3 uint*)((char*)sBl + r * 128 + bgr), 16, 0, 0);
        }
        __syncthreads();
#pragma unroll
        for (int ks = 0; ks < 2; ++ks) {
            int kbyte = (ks * 32 + (lane >> 4) * 8) * 2;
            s16x8 fah[FM], fal[FM], fbh[FN], fbl[FN];
#pragma unroll
            for (int fm = 0; fm < FM; ++fm) {
                int row = wr * (BM / 2) + fm * 16 + (lane & 15);
                int by = row * 128 + (kbyte ^ ((row & 7) << 4));
                fah[fm] = *(const s16x8*)((const char*)sAh + by);
                fal[fm] = *(const s16x8*)((const char*)sAl + by);
            }
#pragma unroll
            for (int fn = 0; fn < FN; ++fn) {
                int row = wc * (BN / 2) + fn * 16 + (lane & 15);
                int by = row * 128 + (kbyte ^ ((row & 7) << 4));
                fbh[fn] = *(const s16x8*)((const char*)sBh + by);
                fbl[fn] = *(const s16x8*)((const char*)sBl + by);
            }
#pragma unroll
            for (int fm = 0; fm < FM; ++fm)
#pragma unroll
                for (int fn = 0; fn < FN; ++fn) {
                    acc[fm][fn] = __builtin_amdgcn_mfma_f32_16x16x32_bf16(fah[fm], fbh[fn], acc[fm][fn], 0, 0, 0);
                    acc[fm][fn] = __builtin_amdgcn_mfma_f32_16x16x32_bf16(fah[fm], fbl[fn], acc[fm][fn], 0, 0, 0);
                    acc[fm][fn] = __builtin_amdgcn_mfma_f32_16x16x32_bf16(fal[fm], fbh[fn], acc[fm][fn], 0, 0, 0);
                }
        }
    }
#pragma unroll
    for (int fm = 0; fm < FM; ++fm) {
#pragma unroll
        for (int fn = 0; fn < FN; ++fn) {
            int n = bn + wc * (BN / 2) + fn * 16 + (lane & 15);
            float bb = 0.f;
            if (EPI != 3) bb = bias[n];
#pragma unroll
            for (int r = 0; r < 4; ++r) {
                int m = bm + wr * (BM / 2) + fm * 16 + (lane >> 4) * 4 + r;
                float o = acc[fm][fn][r] + bb;
                if (EPI == 4) {
                    o = gelu_f(o);
                    ushort hh, ll;
                    split1(o, hh, ll);
                    size_t byb = (size_t)m * 2 * N + (size_t)(n >> 6) * 128 +
                                 (size_t)(((((n >> 3) & 7) * 16)) ^ ((m & 7) << 4)) + (n & 7) * 2;
                    *(ushort*)((char*)CH + byb) = hh;
                    *(ushort*)((char*)CL + byb) = ll;
                } else if (EPI == 5) {
                    int seg = n >> 9;  // block-uniform
                    int hh_ = (n >> 6) & 7, dd = n & 63;
                    int bq = m >> 9, sq = m & 511;
                    ushort hh, ll;
                    if (seg == 0) {
                        split1(o * 0.125f, hh, ll);
                        size_t rr = (size_t)bq * 4096 + hh_ * 512 + sq;
                        size_t by = rr * 128 + (size_t)((((dd >> 3) * 16)) ^ ((sq & 7) << 4)) + (dd & 7) * 2;
                        *(ushort*)((char*)CH + by) = hh;
                        *(ushort*)((char*)CL + by) = ll;
                    } else if (seg == 1) {
                        split1(o, hh, ll);
                        size_t rr = (size_t)bq * 4096 + hh_ * 512 + sq;
                        size_t by = rr * 128 + (size_t)((((dd >> 3) * 16)) ^ ((sq & 7) << 4)) + (dd & 7) * 2;
                        *(ushort*)((char*)C2H + by) = hh;
                        *(ushort*)((char*)C2L + by) = ll;
                    } else {
                        split1(o, hh, ll);
                        size_t rr = (size_t)(bq * 8 + hh_) * 64 + dd;
                        size_t by = rr * 1024 + (size_t)(sq >> 6) * 128 +
                                    (size_t)(((((sq >> 3) & 7) * 16)) ^ ((dd & 7) << 4)) + (sq & 7) * 2;
                        *(ushort*)((char*)C3H + by) = hh;
                        *(ushort*)((char*)C3L + by) = ll;
                    }
                } else {
                    if (EPI == 1) o = gelu_f(o);
                    else if (EPI == 2) o += resid[(size_t)m * N + n];
                    C[(size_t)m * N + n] = o;
                }
            }
        }
    }
}

// ---- MFMA flash attention: grid (8 qt, NH, NB), 256 thr = 4 waves ----
__global__ __launch_bounds__(256) void k_attn2(
    const ushort* __restrict__ QH, const ushort* __restrict__ QL,
    const ushort* __restrict__ KH, const ushort* __restrict__ KL,
    const ushort* __restrict__ VTH, const ushort* __restrict__ VTL,
    float* __restrict__ ao) {
    __shared__ __align__(16) char SM[81920];
    int qt = blockIdx.x, h = blockIdx.y, b = blockIdx.z;
    int tid = threadIdx.x, lane = tid & 63, wvi = tid >> 6;
    size_t R = ((size_t)(b * NH + h)) * NS;
    const char* KHg = (const char*)KH + R * 128;
    const char* KLg = (const char*)KL + R * 128;
    const char* VHg = (const char*)VTH + ((size_t)(b * NH + h) * 64) * 1024;
    const char* VLg = (const char*)VTL + ((size_t)(b * NH + h) * 64) * 1024;

    stage_lin((const char*)QH + (R + qt * 64) * 128, SM + 65536, wvi, lane);
    stage_lin((const char*)QL + (R + qt * 64) * 128, SM + 73728, wvi, lane);
    stage_lin(KHg, SM + 0, wvi, lane);
    stage_lin(KLg, SM + 8192, wvi, lane);
    stage_vt(VHg, 0, SM + 32768, wvi, lane);
    stage_vt(VLg, 0, SM + 40960, wvi, lane);
    __syncthreads();

    s16x8 fqh[2], fql[2];
#pragma unroll
    for (int ks = 0; ks < 2; ++ks) {
        int row = wvi * 16 + (lane & 15);
        int by = row * 128 + ((((ks * 32 + (lane >> 4) * 8) * 2)) ^ ((row & 7) << 4));
        fqh[ks] = *(const s16x8*)(SM + 65536 + by);
        fql[ks] = *(const s16x8*)(SM + 73728 + by);
    }

    float mr_[4] = {-FLT_MAX, -FLT_MAX, -FLT_MAX, -FLT_MAX};
    float lr_[4] = {0.f, 0.f, 0.f, 0.f};
    f32x4 acc_o[4] = {};

    for (int c = 0; c < 8; ++c) {
        const char* khc = SM + ((c & 1) ? 16384 : 0);
        const char* klc = khc + 8192;
        const char* vhc = SM + 32768 + ((c & 1) ? 16384 : 0);
        const char* vlc = vhc + 8192;
        if (c + 1 < 8) {
            char* khn = SM + ((c & 1) ? 0 : 16384);
            char* vhn = SM + 32768 + ((c & 1) ? 0 : 16384);
            stage_lin(KHg + (size_t)(c + 1) * 8192, khn, wvi, lane);
            stage_lin(KLg + (size_t)(c + 1) * 8192, khn + 8192, wvi, lane);
            stage_vt(VHg, (c + 1) * 128, vhn, wvi, lane);
            stage_vt(VLg, (c + 1) * 128, vhn + 8192, wvi, lane);
        }
        f32x4 sa[4] = {};
#pragma unroll
        for (int ks = 0; ks < 2; ++ks) {
            int kbyte = (ks * 32 + (lane >> 4) * 8) * 2;
#pragma unroll
            for (int fk = 0; fk < 4; ++fk) {
                int krow = fk * 16 + (lane & 15);
                int by = krow * 128 + (kbyte ^ ((krow & 7) << 4));
                s16x8 kh8 = *(const s16x8*)(khc + by);
                s16x8 kl8 = *(const s16x8*)(klc + by);
                sa[fk] = __builtin_amdgcn_mfma_f32_16x16x32_bf16(fqh[ks], kh8, sa[fk], 0, 0, 0);
                sa[fk] = __builtin_amdgcn_mfma_f32_16x16x32_bf16(fqh[ks], kl8, sa[fk], 0, 0, 0);
                sa[fk] = __builtin_amdgcn_mfma_f32_16x16x32_bf16(fql[ks], kh8, sa[fk], 0, 0, 0);
            }
        }
#pragma unroll
        for (int r = 0; r < 4; ++r) {
            float smax = fmaxf(fmaxf(sa[0][r], sa[1][r]), fmaxf(sa[2][r], sa[3][r]));
            smax = fmaxf(smax, __shfl_xor(smax, 1));
            smax = fmaxf(smax, __shfl_xor(smax, 2));
            smax = fmaxf(smax, __shfl_xor(smax, 4));
            smax = fmaxf(smax, __shfl_xor(smax, 8));
            float mn = fmaxf(mr_[r], smax);
            float alpha = __expf(mr_[r] - mn);
            mr_[r] = mn;
            float p0 = __expf(sa[0][r] - mn);
            float p1 = __expf(sa[1][r] - mn);
            float p2 = __expf(sa[2][r] - mn);
            float p3 = __expf(sa[3][r] - mn);
            float ls = p0 + p1 + p2 + p3;
            ls += __shfl_xor(ls, 1);
            ls += __shfl_xor(ls, 2);
            ls += __shfl_xor(ls, 4);
            ls += __shfl_xor(ls, 8);
            lr_[r] = lr_[r] * alpha + ls;
#pragma unroll
            for (int fd = 0; fd < 4; ++fd) acc_o[fd][r] *= alpha;
            int prow = wvi * 16 + (lane >> 4) * 4 + r;
            int sw = (prow & 7) << 4;
            int l15 = lane & 15;
            int wb = (l15 & 7) * 2;
            float pv_[4] = {p0, p1, p2, p3};
#pragma unroll
            for (int fk = 0; fk < 4; ++fk) {
                ushort hh, ll;
                split1(pv_[fk], hh, ll);
                int gran = fk * 2 + (l15 >> 3);
                int by = prow * 128 + ((gran * 16) ^ sw) + wb;
                *(ushort*)(SM + 65536 + by) = hh;
                *(ushort*)(SM + 73728 + by) = ll;
            }
        }
        s16x8 fph[2], fpl[2];
#pragma unroll
        for (int ks = 0; ks < 2; ++ks) {
            int prow = wvi * 16 + (lane & 15);
            int by = prow * 128 + ((((ks * 32 + (lane >> 4) * 8) * 2)) ^ ((prow & 7) << 4));
            fph[ks] = *(const s16x8*)(SM + 65536 + by);
            fpl[ks] = *(const s16x8*)(SM + 73728 + by);
        }
#pragma unroll
        for (int ks = 0; ks < 2; ++ks) {
            int kbyte = (ks * 32 + (lane >> 4) * 8) * 2;
#pragma unroll
            for (int fd = 0; fd < 4; ++fd) {
                int vrow = fd * 16 + (lane & 15);
                int by = vrow * 128 + (kbyte ^ ((vrow & 7) << 4));
                s16x8 vh8 = *(const s16x8*)(vhc + by);
                s16x8 vl8 = *(const s16x8*)(vlc + by);
                acc_o[fd] = __builtin_amdgcn_mfma_f32_16x16x32_bf16(fph[ks], vh8, acc_o[fd], 0, 0, 0);
                acc_o[fd] = __builtin_amdgcn_mfma_f32_16x16x32_bf16(fph[ks], vl8, acc_o[fd], 0, 0, 0);
                acc_o[fd] = __builtin_amdgcn_mfma_f32_16x16x32_bf16(fpl[ks], vh8, acc_o[fd], 0, 0, 0);
            }
        }
        __syncthreads();
    }
    float inv_[4];
#pragma unroll
    for (int r = 0; r < 4; ++r) inv_[r] = 1.0f / lr_[r];
#pragma unroll
    for (int fd = 0; fd < 4; ++fd)
#pragma unroll
        for (int r = 0; r < 4; ++r) {
            int srow = qt * 64 + wvi * 16 + (lane >> 4) * 4 + r;
            int col = h * 64 + fd * 16 + (lane & 15);
            ao[((size_t)(b * NS) + srow) * ND + col] = acc_o[fd][r] * inv_[r];
        }
}

// ---- OLD fp32 flash attention (mid/low fallback) ----
__global__ __launch_bounds__(256) void k_attn(const float* __restrict__ qkv,
                                              float* __restrict__ ao) {
    __shared__ float qs[32][65];
    __shared__ float ks[64][65];
    __shared__ float sc[32][68];
    __shared__ float pm[32][8];
    __shared__ float Mrow[32], Srow[32], Arow[32];
    int s0 = blockIdx.x * 32, h = blockIdx.y, b = blockIdx.z;
    int tid = threadIdx.x, tx = tid & 15, ty = tid >> 4;
    const float* base = qkv + (size_t)b * NS * 1536;
#pragma unroll
    for (int i = 0; i < 8; ++i) {
        int idx = tid + i * 256;
        int r = idx >> 6, d = idx & 63;
        qs[r][d] = base[(size_t)(s0 + r) * 1536 + h * 64 + d] * 0.125f;
    }
    if (tid < 32) { Mrow[tid] = -FLT_MAX; Srow[tid] = 0.f; }
    float accp[2][4] = {};
    int rg = tid >> 3, gg = tid & 7;
    for (int c = 0; c < 8; ++c) {
        __syncthreads();
#pragma unroll
        for (int i = 0; i < 16; ++i) {
            int idx = tid + i * 256;
            int r = idx >> 6, d = idx & 63;
            ks[r][d] = base[(size_t)(c * 64 + r) * 1536 + 512 + h * 64 + d];
        }
        __syncthreads();
        float a00 = 0, a01 = 0, a02 = 0, a03 = 0, a10 = 0, a11 = 0, a12 = 0, a13 = 0;
#pragma unroll 8
        for (int d = 0; d < 64; ++d) {
            float q0 = qs[ty][d], q1 = qs[ty + 16][d];
            float k0 = ks[tx][d], k1 = ks[tx + 16][d], k2 = ks[tx + 32][d], k3 = ks[tx + 48][d];
            a00 += q0 * k0; a01 += q0 * k1; a02 += q0 * k2; a03 += q0 * k3;
            a10 += q1 * k0; a11 += q1 * k1; a12 += q1 * k2; a13 += q1 * k3;
        }
        sc[ty][tx] = a00; sc[ty][tx + 16] = a01; sc[ty][tx + 32] = a02; sc[ty][tx + 48] = a03;
        sc[ty + 16][tx] = a10; sc[ty + 16][tx + 16] = a11; sc[ty + 16][tx + 32] = a12; sc[ty + 16][tx + 48] = a13;
        __syncthreads();
        float lm = -FLT_MAX;
#pragma unroll
        for (int j = 0; j < 8; ++j) lm = fmaxf(lm, sc[rg][gg * 8 + j]);
        pm[rg][gg] = lm;
        __syncthreads();
        if (gg == 0) {
            float nm = Mrow[rg];
#pragma unroll
            for (int j = 0; j < 8; ++j) nm = fmaxf(nm, pm[rg][j]);
            Arow[rg] = __expf(Mrow[rg] - nm);
            Mrow[rg] = nm;
        }
        __syncthreads();
        float mr = Mrow[rg];
        float ssp = 0.f;
#pragma unroll
        for (int j = 0; j < 8; ++j) {
            float e = __expf(sc[rg][gg * 8 + j] - mr);
            sc[rg][gg * 8 + j] = e;
            ssp += e;
        }
        pm[rg][gg] = ssp;
        __syncthreads();
        if (gg == 0) {
            float s2 = 0.f;
#pragma unroll
            for (int j = 0; j < 8; ++j) s2 += pm[rg][j];
            Srow[rg] = Srow[rg] * Arow[rg] + s2;
        }
        float al0 = Arow[ty], al1 = Arow[ty + 16];
#pragma unroll
        for (int j = 0; j < 4; ++j) { accp[0][j] *= al0; accp[1][j] *= al1; }
        __syncthreads();
#pragma unroll
        for (int i = 0; i < 16; ++i) {
            int idx = tid + i * 256;
            int r = idx >> 6, d = idx & 63;
            ks[r][d] = base[(size_t)(c * 64 + r) * 1536 + 1024 + h * 64 + d];
        }
        __syncthreads();
#pragma unroll 8
        for (int kk = 0; kk < 64; ++kk) {
            float p0 = sc[ty][kk], p1 = sc[ty + 16][kk];
            float v0 = ks[kk][tx], v1 = ks[kk][tx + 16], v2 = ks[kk][tx + 32], v3 = ks[kk][tx + 48];
            accp[0][0] += p0 * v0; accp[0][1] += p0 * v1; accp[0][2] += p0 * v2; accp[0][3] += p0 * v3;
            accp[1][0] += p1 * v0; accp[1][1] += p1 * v1; accp[1][2] += p1 * v2; accp[1][3] += p1 * v3;
        }
    }
    __syncthreads();
    float inv0 = 1.0f / Srow[ty], inv1 = 1.0f / Srow[ty + 16];
    size_t o0 = ((size_t)(b * NS) + s0 + ty) * ND + h * 64;
    size_t o1 = ((size_t)(b * NS) + s0 + ty + 16) * ND + h * 64;
    ao[o0 + tx] = accp[0][0] * inv0;
    ao[o0 + tx + 16] = accp[0][1] * inv0;
    ao[o0 + tx + 32] = accp[0][2] * inv0;
    ao[o0 + tx + 48] = accp[0][3] * inv0;
    ao[o1 + tx] = accp[1][0] * inv1;
    ao[o1 + tx + 16] = accp[1][1] * inv1;
    ao[o1 + tx + 32] = accp[1][2] * inv1;
    ao[o1 + tx + 48] = accp[1][3] * inv1;
}

// ==== KNN Phase B v3: 2 waves/query halves + value-search shrink + merge ====
// gq = global query row within the current sims buffer; bb = bbase + (gq>>12).
__global__ __launch_bounds__(256) void k_ksel(
    const float* __restrict__ sims, const float* __restrict__ mv,
    const float* __restrict__ gate, float* __restrict__ ao, int bbase) {
    __shared__ float bval[4][CAPS];
    __shared__ ushort bidx[4][CAPS];
    int tid = threadIdx.x, lane = tid & 63, wvi = tid >> 6;
    int gq = blockIdx.x * 2 + (wvi >> 1);
    int bb = bbase + (gq >> 12), q = gq & 4095;
    int hf = wvi & 1;
    const float* sr = sims + (size_t)gq * NM + hf * 4096;
    float* bv = &bval[wvi][0];
    ushort* bi = &bidx[wvi][0];
    unsigned long long lm = (1ULL << lane) - 1;
    {
        float4 v = *(const float4*)(sr + lane * 4);
        int m0 = lane * 4;
        int gI = hf * 4096 + m0;
        bv[m0 + 0] = v.x; bi[m0 + 0] = (ushort)(gI + 0);
        bv[m0 + 1] = v.y; bi[m0 + 1] = (ushort)(gI + 1);
        bv[m0 + 2] = v.z; bi[m0 + 2] = (ushort)(gI + 2);
        bv[m0 + 3] = v.w; bi[m0 + 3] = (ushort)(gI + 3);
    }
    float thr = shrink6v(bv, bi, 256, lane);
    int cnt = 32;
    float4 vA = *(const float4*)(sr + 256 + lane * 4);
    float4 vB = *(const float4*)(sr + 512 + lane * 4);
    for (int i = 1; i < 16; ++i) {
        float4 vC = vB;
        if (i + 2 < 16) vC = *(const float4*)(sr + (size_t)(i + 2) * 256 + lane * 4);
        int m0 = hf * 4096 + i * 256 + lane * 4;
        bool px = vA.x >= thr, py = vA.y >= thr, pz = vA.z >= thr, pw = vA.w >= thr;
        unsigned long long bx = __ballot(px), by = __ballot(py), bz = __ballot(pz), bw = __ballot(pw);
        int nx = (int)__popcll(bx), ny = (int)__popcll(by), nz = (int)__popcll(bz), nw = (int)__popcll(bw);
        int b0 = cnt, b1 = b0 + nx, b2 = b1 + ny, b3 = b2 + nz;
        if (px) { int p = b0 + (int)__popcll(bx & lm); bv[p] = vA.x; bi[p] = (ushort)(m0 + 0); }
        if (py) { int p = b1 + (int)__popcll(by & lm); bv[p] = vA.y; bi[p] = (ushort)(m0 + 1); }
        if (pz) { int p = b2 + (int)__popcll(bz & lm); bv[p] = vA.z; bi[p] = (ushort)(m0 + 2); }
        if (pw) { int p = b3 + (int)__popcll(bw & lm); bv[p] = vA.w; bi[p] = (ushort)(m0 + 3); }
        cnt = b3 + nw;
        if (cnt >= TRIGS) {
            thr = shrink6v(bv, bi, cnt, lane);
            cnt = 32;
        }
        vA = vB;
        vB = vC;
    }
    thr = shrink6v(bv, bi, cnt, lane);
    __syncthreads();

    if (hf == 0) {
        float mval;
        ushort midx;
        if (lane < 32) { mval = bval[wvi][lane]; midx = bidx[wvi][lane]; }
        else { mval = bval[wvi + 1][lane - 32]; midx = bidx[wvi + 1][lane - 32]; }
        unsigned long long k = packkey(mval, (int)midx);
        unsigned long long K = 0;
#pragma unroll 1
        for (int bit = 44; bit >= 0; --bit) {
            unsigned long long cand = K | (1ULL << bit);
            if ((int)__popcll(__ballot(k >= cand)) >= 32) K = cand;
        }
        unsigned long long m = __ballot(k >= K);
        if (k >= K) {
            int p = (int)__popcll(m & lm);
            bv[p] = mval;
            bi[p] = midx;
        }
        float val = (lane < 32) ? bv[lane] : -FLT_MAX;
        float mx = val;
#pragma unroll
        for (int off = 32; off; off >>= 1) mx = fmaxf(mx, __shfl_xor(mx, off));
        float e = (lane < 32) ? __expf(val - mx) : 0.f;
        float ssum = e;
#pragma unroll
        for (int off = 32; off; off >>= 1) ssum += __shfl_xor(ssum, off);
        float w = e / ssum;
        if (lane < 32) bv[lane] = w;
        float acc = 0.f;
        const float* vb = mv + (size_t)bb * NM * NHD;
#pragma unroll 4
        for (int j = 0; j < 32; ++j) {
            float ww = bv[j];
            int idx = (int)bi[j];
            acc += ww * vb[(size_t)idx * NHD + lane];
        }
        int h = q >> 9, s = q & 511;
        float g = 1.0f / (1.0f + __expf(-gate[h]));
        float* aop = ao + ((size_t)(bb * NS) + s) * ND + h * 64 + lane;
        *aop = *aop * (1.0f - g) + acc * g;
    }
}

// ==== KNN v5 (small-ws fallback) ====
__global__ __launch_bounds__(256, 2) void k_knn5(
    const float* __restrict__ qkv, const ushort* __restrict__ mkh,
    const ushort* __restrict__ mkl, const float* __restrict__ mv,
    const float* __restrict__ gate, float* __restrict__ ao) {
    __shared__ __align__(16) char SM[63760];
    ushort* kh0 = (ushort*)SM;
    ushort* kl0 = (ushort*)(SM + 8192);
    ushort* kh1 = (ushort*)(SM + 16384);
    ushort* kl1 = (ushort*)(SM + 24576);
    float* cval = (float*)(SM + 32768);
    ushort* cidx = (ushort*)(SM + 53248);
    float* thrV = (float*)(SM + 63488);
    int* cnt = (int*)(SM + 63616);
    int* sflag = (int*)(SM + 63744);
    ushort* qh = (ushort*)(SM + 32768);
    ushort* ql = (ushort*)(SM + 36864);
    int b = blockIdx.y, s0 = blockIdx.x * 4;
    int tid = threadIdx.x, lane = tid & 63, wvi = tid >> 6;
    const ushort* mhb = mkh + (size_t)b * NM * 64;
    const ushort* mlb = mkl + (size_t)b * NM * 64;
    {
        int q = tid >> 3, dbase = (tid & 7) * 8;
        const float* src = &qkv[((size_t)(b * NS) + s0 + (q & 3)) * 1536 + (q >> 2) * 64 + dbase];
        float v[8];
#pragma unroll
        for (int j = 0; j < 8; ++j) v[j] = src[j] * 0.125f;
        s16x8 hv, lv;
        split8(v, hv, lv);
        int by = q * 128 + ((dbase * 2) ^ ((q & 7) << 4));
        *(s16x8*)((char*)qh + by) = hv;
        *(s16x8*)((char*)ql + by) = lv;
    }
    stage_dma64(mhb, mlb, kh0, kl0, wvi, lane);
    __syncthreads();
    s16x8 fqh[2][2], fql[2][2];
#pragma unroll
    for (int fq = 0; fq < 2; ++fq)
#pragma unroll
        for (int ks = 0; ks < 2; ++ks) {
            int row = fq * 16 + (lane & 15);
            int kb2 = (ks * 32 + (lane >> 4) * 8) * 2;
            int by = row * 128 + (kb2 ^ ((row & 7) << 4));
            fqh[fq][ks] = *(const s16x8*)((const char*)qh + by);
            fql[fq][ks] = *(const s16x8*)((const char*)ql + by);
        }
    if (tid < 32) { cnt[tid] = 0; thrV[tid] = -FLT_MAX; }
    if (tid == 0) *sflag = 0;
    __syncthreads();
    int qbase4 = (lane >> 4) * 4;
    int mrow = (lane & 15);
    for (int c = 0; c < NCC; ++c) {
        ushort* khc = (c & 1) ? kh1 : kh0;
        ushort* klc = (c & 1) ? kl1 : kl0;
        if (c + 1 < NCC) {
            size_t ro = (size_t)(c + 1) * KCC * 64;
            stage_dma64(mhb + ro, mlb + ro, (c & 1) ? kh0 : kh1, (c & 1) ? kl0 : kl1, wvi, lane);
        }
        float thc[2][4];
#pragma unroll
        for (int fq = 0; fq < 2; ++fq)
#pragma unroll
            for (int r = 0; r < 4; ++r) thc[fq][r] = thrV[fq * 16 + qbase4 + r];
        f32x4 acc[2] = {};
#pragma unroll
        for (int ks = 0; ks < 2; ++ks) {
            int row = wvi * 16 + mrow;
            int kb2 = (ks * 32 + (lane >> 4) * 8) * 2;
            int by = row * 128 + (kb2 ^ ((row & 7) << 4));
            s16x8 kh8 = *(const s16x8*)((const char*)khc + by);
            s16x8 kl8 = *(const s16x8*)((const char*)klc + by);
#pragma unroll
            for (int fq = 0; fq < 2; ++fq) {
                acc[fq] = __builtin_amdgcn_mfma_f32_16x16x32_bf16(fqh[fq][ks], kh8, acc[fq], 0, 0, 0);
                acc[fq] = __builtin_amdgcn_mfma_f32_16x16x32_bf16(fqh[fq][ks], kl8, acc[fq], 0, 0, 0);
                acc[fq] = __builtin_amdgcn_mfma_f32_16x16x32_bf16(fql[fq][ks], kh8, acc[fq], 0, 0, 0);
            }
        }
#pragma unroll
        for (int fq = 0; fq < 2; ++fq)
#pragma unroll
            for (int r = 0; r < 4; ++r) {
                float v = acc[fq][r];
                if (v >= thc[fq][r]) {
                    int q = fq * 16 + qbase4 + r;
                    int pos = atomicAdd(&cnt[q], 1);
                    if (pos < CAPB) {
                        cval[q * CAPB + pos] = v;
                        cidx[q * CAPB + pos] = (ushort)(c * KCC + wvi * 16 + mrow);
                    }
                    if (pos == TRIG) *sflag = 1;
                }
            }
        __syncthreads();
        if (*sflag) {
#pragma unroll 1
            for (int qq = 0; qq < 8; ++qq) {
                int q = wvi * 8 + qq;
                shrink_cheap(cval, cidx, q, cnt[q], lane, &thrV[q]);
                if (lane == 0) cnt[q] = 32;
            }
            if (tid == 0) *sflag = 0;
            __syncthreads();
        }
    }
#pragma unroll 1
    for (int qq = 0; qq < 8; ++qq) {
        int q = wvi * 8 + qq;
        shrink_cheap(cval, cidx, q, cnt[q], lane, nullptr);
    }
    __syncthreads();
    if (tid < 32) {
        int q = tid;
        float mx = -FLT_MAX;
#pragma unroll
        for (int j = 0; j < 32; ++j) mx = fmaxf(mx, cval[q * CAPB + j]);
        float es[32];
        float ssum = 0.f;
#pragma unroll
        for (int j = 0; j < 32; ++j) { es[j] = __expf(cval[q * CAPB + j] - mx); ssum += es[j]; }
        float inv = 1.0f / ssum;
#pragma unroll
        for (int j = 0; j < 32; ++j) cval[q * CAPB + j] = es[j] * inv;
    }
    __syncthreads();
    {
        int q = tid >> 3, dseg = (tid & 7) * 8;
        int h = q >> 2, si = q & 3;
        float r0x = 0, r0y = 0, r0z = 0, r0w = 0, r1x = 0, r1y = 0, r1z = 0, r1w = 0;
        const float* vb = mv + (size_t)b * NM * NHD;
        for (int j = 0; j < 32; ++j) {
            float w = cval[q * CAPB + j];
            int idx = (int)cidx[q * CAPB + j];
            const float* row = vb + (size_t)idx * NHD + dseg;
            float4 v0 = *(const float4*)(row);
            float4 v1 = *(const float4*)(row + 4);
            r0x += w * v0.x; r0y += w * v0.y; r0z += w * v0.z; r0w += w * v0.w;
            r1x += w * v1.x; r1y += w * v1.y; r1z += w * v1.z; r1w += w * v1.w;
        }
        float g = 1.0f / (1.0f + __expf(-gate[h]));
        float omg = 1.0f - g;
        float* aop = ao + ((size_t)(b * NS) + s0 + si) * ND + h * 64 + dseg;
        float rr[8] = {r0x, r0y, r0z, r0w, r1x, r1y, r1z, r1w};
#pragma unroll
        for (int k = 0; k < 8; ++k) aop[k] = aop[k] * omg + rr[k] * g;
    }
}

// ---- LayerNorm (plain, fallback) ----
__global__ __launch_bounds__(256) void k_ln(const float* __restrict__ X,
                                            const float* __restrict__ gam,
                                            const float* __restrict__ bet,
                                            float* __restrict__ Y) {
    __shared__ float red[4];
    __shared__ float sm, sv;
    int r = blockIdx.x, tid = threadIdx.x;
    const float* xr = X + (size_t)r * ND;
    float x0 = xr[tid], x1 = xr[tid + 256];
    float s = x0 + x1;
    for (int off = 32; off; off >>= 1) s += __shfl_down(s, off);
    if ((tid & 63) == 0) red[tid >> 6] = s;
    __syncthreads();
    if (tid == 0) sm = (red[0] + red[1] + red[2] + red[3]) * (1.0f / 512.0f);
    __syncthreads();
    float m = sm;
    float d0 = x0 - m, d1 = x1 - m;
    float vs = d0 * d0 + d1 * d1;
    for (int off = 32; off; off >>= 1) vs += __shfl_down(vs, off);
    if ((tid & 63) == 0) red[tid >> 6] = vs;
    __syncthreads();
    if (tid == 0) sv = rsqrtf((red[0] + red[1] + red[2] + red[3]) * (1.0f / 512.0f) + 1e-5f);
    __syncthreads();
    float rstd = sv;
    Y[(size_t)r * ND + tid] = d0 * rstd * gam[tid] + bet[tid];
    Y[(size_t)r * ND + tid + 256] = d1 * rstd * gam[tid + 256] + bet[tid + 256];
}

// ---- LayerNorm fused with split-bf16 output ----
__global__ __launch_bounds__(256) void k_ln2(const float* __restrict__ X,
                                             const float* __restrict__ gam,
                                             const float* __restrict__ bet,
                                             float* __restrict__ Y,
                                             ushort* __restrict__ YH,
                                             ushort* __restrict__ YL) {
    __shared__ float red[4];
    __shared__ float sm, sv;
    int r = blockIdx.x, tid = threadIdx.x;
    const float* xr = X + (size_t)r * ND;
    float x0 = xr[tid], x1 = xr[tid + 256];
    float s = x0 + x1;
    for (int off = 32; off; off >>= 1) s += __shfl_down(s, off);
    if ((tid & 63) == 0) red[tid >> 6] = s;
    __syncthreads();
    if (tid == 0) sm = (red[0] + red[1] + red[2] + red[3]) * (1.0f / 512.0f);
    __syncthreads();
    float m = sm;
    float d0 = x0 - m, d1 = x1 - m;
    float vs = d0 * d0 + d1 * d1;
    for (int off = 32; off; off >>= 1) vs += __shfl_down(vs, off);
    if ((tid & 63) == 0) red[tid >> 6] = vs;
    __syncthreads();
    if (tid == 0) sv = rsqrtf((red[0] + red[1] + red[2] + red[3]) * (1.0f / 512.0f) + 1e-5f);
    __syncthreads();
    float rstd = sv;
    float y0 = d0 * rstd * gam[tid] + bet[tid];
    float y1 = d1 * rstd * gam[tid + 256] + bet[tid + 256];
    Y[(size_t)r * ND + tid] = y0;
    Y[(size_t)r * ND + tid + 256] = y1;
    int sw = (r & 7) << 4;
    char* oh = (char*)YH + (size_t)r * 1024;
    char* ol = (char*)YL + (size_t)r * 1024;
    ushort hh, ll;
    split1(y0, hh, ll);
    int k0 = tid;
    int by0 = (k0 >> 6) * 128 + ((((k0 >> 3) & 7) * 16) ^ sw) + (k0 & 7) * 2;
    *(ushort*)(oh + by0) = hh;
    *(ushort*)(ol + by0) = ll;
    split1(y1, hh, ll);
    int k1 = tid + 256;
    int by1 = (k1 >> 6) * 128 + ((((k1 >> 3) & 7) * 16) ^ sw) + (k1 & 7) * 2;
    *(ushort*)(oh + by1) = hh;
    *(ushort*)(ol + by1) = ll;
}

// ---- mean pool: stage 1 partials ----
__global__ void k_pool2(const float* __restrict__ tok, float* __restrict__ part) {
    int c = blockIdx.x, b = blockIdx.y;
    int tid = threadIdx.x;
    int sp0 = c * 64;
    float a0 = 0.f, a1 = 0.f;
    const float* base = tok + ((size_t)(b * NS) + sp0) * ND;
#pragma unroll 4
    for (int i = 0; i < 64; ++i) {
        a0 += base[(size_t)i * ND + tid];
        a1 += base[(size_t)i * ND + tid + 256];
    }
    float* dst = part + ((size_t)(c * NB + b)) * ND;
    dst[tid] = a0;
    dst[tid + 256] = a1;
}

// ---- mean pool: stage 2 tree sum ----
__global__ void k_pool3(const float* __restrict__ part, float* __restrict__ pooled) {
    int b = blockIdx.x, d = threadIdx.x;
    float s = 0.f;
#pragma unroll
    for (int c = 0; c < 8; ++c) s += part[((size_t)(c * NB + b)) * ND + d];
    pooled[b * ND + d] = s * (1.0f / 512.0f);
}

__global__ void k_fc1(const float* __restrict__ pooled, const float* __restrict__ w,
                      const float* __restrict__ bias, float* __restrict__ o1) {
    int id = blockIdx.x * 256 + threadIdx.x;
    int b = id >> 10, j = id & 1023;
    float acc = bias[j];
    for (int d = 0; d < ND; ++d) acc += pooled[b * ND + d] * w[(size_t)d * NMLP + j];
    o1[id] = gelu_f(acc);
}

// ---- fc2: one wave per (b,c) output ----
__global__ __launch_bounds__(256) void k_fc2b(const float* __restrict__ o1,
                                              const float* __restrict__ w,
                                              const float* __restrict__ bias,
                                              float* __restrict__ out) {
    int c = blockIdx.x;
    int b = threadIdx.x >> 6, lane = threadIdx.x & 63;
    const float* o1b = o1 + b * NMLP;
    float acc = 0.f;
#pragma unroll
    for (int i = 0; i < 16; ++i) {
        int k = i * 64 + lane;
        acc += o1b[k] * w[(size_t)k * NC + c];
    }
    acc += __shfl_xor(acc, 32);
    acc += __shfl_xor(acc, 16);
    acc += __shfl_xor(acc, 8);
    acc += __shfl_xor(acc, 4);
    acc += __shfl_xor(acc, 2);
    acc += __shfl_xor(acc, 1);
    if (lane == 0) out[b * NC + c] = acc + bias[c];
}

extern "C" void kernel_launch(void* const* d_in, const int* in_sizes, int n_in,
                              void* d_out, int out_size, void* d_ws, size_t ws_size,
                              hipStream_t stream) {
    const float* x    = (const float*)d_in[0];
    const float* mask = (const float*)d_in[1];
    const float* pe   = (const float*)d_in[2];
    const float* Wqkv = (const float*)d_in[3];
    const float* bqkv = (const float*)d_in[4];
    const float* Wo   = (const float*)d_in[5];
    const float* bo   = (const float*)d_in[6];
    const float* ln1g = (const float*)d_in[7];
    const float* ln1b = (const float*)d_in[8];
    const float* W1   = (const float*)d_in[9];
    const float* b1   = (const float*)d_in[10];
    const float* W2   = (const float*)d_in[11];
    const float* b2   = (const float*)d_in[12];
    const float* ln2g = (const float*)d_in[13];
    const float* ln2b = (const float*)d_in[14];
    const float* gate = (const float*)d_in[15];
    const float* memk = (const float*)d_in[16];
    const float* memv = (const float*)d_in[17];
    const float* fc1w = (const float*)d_in[18];
    const float* fc1b = (const float*)d_in[19];
    const float* fc2w = (const float*)d_in[20];
    const float* fc2b_ = (const float*)d_in[21];
    float* out = (float*)d_out;

    float* ws = (float*)d_ws;

    // ---- big-path layout ----
    float* m8     = ws;                         // 2048
    ushort* mkh   = (ushort*)(m8 + 2048);       // 2097152 ush
    ushort* mkl   = mkh + 2097152;              // 2097152 ush
    float* tok    = (float*)(mkl + 2097152);    // 1048576
    float* qkv    = tok + 1048576;              // 3145728 (carved into split bufs)
    float* ao     = qkv + 3145728;              // 1048576
    float* pooled = ao + 1048576;               // 2048
    float* o1     = pooled + 2048;              // 4096
    ushort* aH    = (ushort*)(o1 + 4096);       // 1048576 ush
    ushort* aL    = aH + 1048576;               // 1048576 ush
    ushort* WqTH  = aL + 1048576;               // 4718592 ush
    ushort* WqTL  = WqTH + 4718592;
    ushort* WoTH  = WqTL + 4718592;             // 1572864 ush
    ushort* WoTL  = WoTH + 1572864;
    ushort* W1TH  = WoTL + 1572864;             // 6291456 ush
    ushort* W1TL  = W1TH + 6291456;
    ushort* W2TH  = W1TL + 6291456;             // 6291456 ush
    ushort* W2TL  = W2TH + 6291456;
    float* simsb  = (float*)(W2TL + 6291456);   // >= 32M floats
    // overlays inside simsb (dead during knn):
    ushort* fH  = (ushort*)(simsb + 4194304);
    ushort* fL  = fH + 4194304;
    float* ybuf = simsb + 8388608;
    float* ppart = simsb;                       // pool partials (tail only)
    // carve qkv fp32 region into split buffers (6 x 2MB)
    ushort* QHb  = (ushort*)qkv;
    ushort* QLb  = QHb + 1048576;
    ushort* KHb  = QLb + 1048576;
    ushort* KLb  = KHb + 1048576;
    ushort* VTHb = KLb + 1048576;
    ushort* VTLb = VTHb + 1048576;

    size_t needNew = (size_t)((simsb + 33554432) - ws) * sizeof(float);
    size_t need2   = needNew + (size_t)33554432 * sizeof(float);
    size_t need4   = needNew + (size_t)3 * 33554432 * sizeof(float);

    if (ws_size >= needNew) {
        int cb = (ws_size >= need4) ? 4 : ((ws_size >= need2) ? 2 : 1);
        k_m8<<<NB, 512, 0, stream>>>(mask, m8);
        k_mksplit<<<1024, 256, 0, stream>>>(memk, mkh, mkl);
        k_tok<<<dim3(16, 16, NB), dim3(32, 8), 0, stream>>>(x, pe, m8, tok);
        k_wsplitT<<<dim3(48, 8, 6), dim3(32, 8), 0, stream>>>(Wqkv, WqTH, WqTL, 512, 1536);
        k_wsplitT<<<dim3(16, 8, 6), dim3(32, 8), 0, stream>>>(Wo, WoTH, WoTL, 512, 512);
        k_wsplitT<<<dim3(64, 8, 6), dim3(32, 8), 0, stream>>>(W1, W1TH, W1TL, 512, 2048);
        k_wsplitT<<<dim3(16, 32, 6), dim3(32, 8), 0, stream>>>(W2, W2TH, W2TL, 2048, 512);
        k_asplit<<<512, 256, 0, stream>>>(tok, aH, aL, 512);

        for (int l = 0; l < NL; ++l) {
            k_gmm2<128, 128, 5><<<dim3(12, 16), 256, 0, stream>>>(
                aH, aL, WqTH + (size_t)l * 786432, WqTL + (size_t)l * 786432,
                bqkv + l * 1536, nullptr, nullptr, QHb, QLb, KHb, KLb, VTHb, VTLb,
                2048, 1536, 512, 0, 0, 0);
            k_attn2<<<dim3(8, NH, NB), 256, 0, stream>>>(QHb, QLb, KHb, KLb, VTHb, VTLb, ao);
            if (l == 0) {
                for (int bb0 = 0; bb0 < NB; bb0 += cb) {
                    k_gmm2<128, 128, 3><<<dim3(64, 32, cb), 256, 0, stream>>>(
                        QHb + (size_t)bb0 * 262144, QLb + (size_t)bb0 * 262144,
                        mkh + (size_t)bb0 * 524288, mkl + (size_t)bb0 * 524288,
                        nullptr, nullptr, simsb, nullptr, nullptr, nullptr, nullptr,
                        nullptr, nullptr, 4096, 8192, 64,
                        262144, 524288, 33554432);
                    k_ksel<<<2048 * cb, 256, 0, stream>>>(simsb, memv, gate, ao, bb0);
                }
            }
            k_asplit<<<512, 256, 0, stream>>>(ao, aH, aL, 512);
            k_gmm2<64, 64, 2><<<dim3(8, 32), 256, 0, stream>>>(
                aH, aL, WoTH + (size_t)l * 262144, WoTL + (size_t)l * 262144,
                bo + l * 512, tok, ybuf, nullptr, nullptr, nullptr, nullptr,
                nullptr, nullptr, 2048, 512, 512, 0, 0, 0);
            k_ln2<<<2048, 256, 0, stream>>>(ybuf, ln1g + l * 512, ln1b + l * 512, tok, aH, aL);
            k_gmm2<128, 128, 4><<<dim3(16, 16), 256, 0, stream>>>(
                aH, aL, W1TH + (size_t)l * 1048576, W1TL + (size_t)l * 1048576,
                b1 + l * 2048, nullptr, nullptr, fH, fL, nullptr, nullptr,
                nullptr, nullptr, 2048, 2048, 512, 0, 0, 0);
            k_gmm2<64, 64, 2><<<dim3(8, 32), 256, 0, stream>>>(
                fH, fL, W2TH + (size_t)l * 1048576, W2TL + (size_t)l * 1048576,
                b2 + l * 512, tok, ybuf, nullptr, nullptr, nullptr, nullptr,
                nullptr, nullptr, 2048, 512, 2048, 0, 0, 0);
            k_ln2<<<2048, 256, 0, stream>>>(ybuf, ln2g + l * 512, ln2b + l * 512, tok, aH, aL);
        }
        k_pool2<<<dim3(8, NB), 256, 0, stream>>>(tok, ppart);
        k_pool3<<<NB, 512, 0, stream>>>(ppart, pooled);
        k_fc1<<<16, 256, 0, stream>>>(pooled, fc1w, fc1b, o1);
        k_fc2b<<<NC, 256, 0, stream>>>(o1, fc2w, fc2b_, out);
        return;
    }

    // ---- MID/LOW fallback ----
    float* m8b     = ws;
    ushort* mkh2   = (ushort*)(m8b + 2048);
    ushort* mkl2   = mkh2 + 2097152;
    float* tok2    = (float*)(mkl2 + 2097152);
    float* qkv2    = tok2 + 1048576;
    float* ao2     = qkv2 + 3145728;
    float* ybuf2   = ao2 + 1048576;
    float* ff12    = ybuf2 + 1048576;
    float* pooled2 = ff12 + 4194304;
    float* o12     = pooled2 + 2048;
    float* qmat2   = o12 + 4096;
    float* memkT2  = qmat2 + 1048576;
    float* simsb2  = memkT2 + 2097152;

    size_t needMid = (size_t)((simsb2 + 33554432) - ws) * sizeof(float);
    bool big = ws_size >= needMid;

    k_m8<<<NB, 512, 0, stream>>>(mask, m8b);
    if (big)
        k_memkT<<<dim3(NM / 32, 2, NB), dim3(32, 8), 0, stream>>>(memk, memkT2);
    else
        k_mksplit<<<1024, 256, 0, stream>>>(memk, mkh2, mkl2);
    k_tok<<<dim3(16, 16, NB), dim3(32, 8), 0, stream>>>(x, pe, m8b, tok2);

    for (int l = 0; l < NL; ++l) {
        k_gmm<128, 128, 0><<<dim3(12, 16), 256, 0, stream>>>(
            tok2, Wqkv + (size_t)l * 512 * 1536, bqkv + l * 1536, nullptr, qkv2, 2048, 1536, 512);
        k_attn<<<dim3(16, NH, NB), 256, 0, stream>>>(qkv2, ao2);
        if (l == 0) {
            if (big) {
                k_qmat<<<1024, 256, 0, stream>>>(qkv2, qmat2);
                for (int bb = 0; bb < NB; ++bb) {
                    k_gmm<128, 128, 3><<<dim3(64, 32), 256, 0, stream>>>(
                        qmat2 + (size_t)bb * 262144, memkT2 + (size_t)bb * 524288,
                        nullptr, nullptr, simsb2, 4096, 8192, 64);
                    k_ksel<<<2048, 256, 0, stream>>>(simsb2, memv, gate, ao2, bb);
                }
            } else {
                k_knn5<<<dim3(NS / 4, NB), 256, 0, stream>>>(qkv2, mkh2, mkl2, memv, gate, ao2);
            }
        }
        k_gmm<64, 64, 2><<<dim3(8, 32), 256, 0, stream>>>(
            ao2, Wo + (size_t)l * 512 * 512, bo + l * 512, tok2, ybuf2, 2048, 512, 512);
        k_ln<<<2048, 256, 0, stream>>>(ybuf2, ln1g + l * 512, ln1b + l * 512, tok2);
        k_gmm<128, 128, 1><<<dim3(16, 16), 256, 0, stream>>>(
            tok2, W1 + (size_t)l * 512 * 2048, b1 + l * 2048, nullptr, ff12, 2048, 2048, 512);
        k_gmm<64, 64, 2><<<dim3(8, 32), 256, 0, stream>>>(
            ff12, W2 + (size_t)l * 2048 * 512, b2 + l * 512, tok2, ybuf2, 2048, 512, 2048);
        k_ln<<<2048, 256, 0, stream>>>(ybuf2, ln2g + l * 512, ln2b + l * 512, tok2);
    }
    k_pool2<<<dim3(8, NB), 256, 0, stream>>>(tok2, simsb2);
    k_pool3<<<NB, 512, 0, stream>>>(simsb2, pooled2);
    k_fc1<<<16, 256, 0, stream>>>(pooled2, fc1w, fc1b, o12);
    k_fc2b<<<NC, 256, 0, stream>>>(o12, fc2w, fc2b_, out);
}

// Round 19
// 1316.142 us; speedup vs baseline: 1.0505x; 1.0066x over previous
//
#include <hip/hip_runtime.h>
#include <hip/hip_bf16.h>
#include <float.h>
#include <math.h>

// Problem constants
#define NB 4
#define ND 512
#define NS 512
#define NH 8
#define NHD 64
#define NM 8192
#define NL 6
#define NFF 2048
#define NMLP 1024
#define NC 117

// knn5 (fallback) params
#define KCC 64
#define NCC (NM / KCC)
#define CAPB 160
#define TRIG 96

// k_ksel params
#define CAPS 352
#define TRIGS 96

#define AS1 __attribute__((address_space(1)))
#define AS3 __attribute__((address_space(3)))

typedef __attribute__((ext_vector_type(8))) short s16x8;
typedef __attribute__((ext_vector_type(4))) float f32x4;

__device__ __forceinline__ float gelu_f(float x) {
    return 0.5f * x * (1.0f + erff(x * 0.70710678118654752440f));
}

__device__ __forceinline__ ushort f2bf_rne(float x) {
    uint u = __float_as_uint(x);
    uint r = u + 0x7FFFu + ((u >> 16) & 1u);
    return (ushort)(r >> 16);
}
__device__ __forceinline__ float bf2f(ushort h) { return __uint_as_float(((uint)h) << 16); }
__device__ __forceinline__ void split1(float x, ushort& h, ushort& l) {
    h = f2bf_rne(x);
    float r = x - bf2f(h);
    l = f2bf_rne(r);
}
__device__ __forceinline__ void split8(const float* v, s16x8& hv, s16x8& lv) {
#pragma unroll
    for (int j = 0; j < 8; ++j) {
        ushort h, l;
        split1(v[j], h, l);
        hv[j] = (short)h;
        lv[j] = (short)l;
    }
}

// sortable key: (value desc, index asc) -> larger key wins; valid keys nonzero
__device__ __forceinline__ unsigned long long packkey(float v, int idx) {
    uint u = __float_as_uint(v);
    u = u ^ (((int)u < 0) ? 0xFFFFFFFFu : 0x80000000u);
    return (((unsigned long long)u) << 13) | (unsigned long long)(8191 - idx);
}
__device__ __forceinline__ float keyval(unsigned long long K) {
    uint vb = (uint)(K >> 13);
    uint orig = (vb & 0x80000000u) ? (vb ^ 0x80000000u) : ~vb;
    return __uint_as_float(orig);
}
__device__ __forceinline__ uint sortable32(float v) {
    uint u = __float_as_uint(v);
    return u ^ (((int)u < 0) ? 0xFFFFFFFFu : 0x80000000u);
}
__device__ __forceinline__ float unsortable32(uint s) {
    uint u = (s & 0x80000000u) ? (s ^ 0x80000000u) : ~s;
    return __uint_as_float(u);
}

// wave-parallel exact top-32 retain (3 slots/lane) — knn5 fallback path
__device__ __forceinline__ void shrink_cheap(float* __restrict__ cval,
                                             ushort* __restrict__ cidx,
                                             int q, int n, int lane,
                                             float* __restrict__ thrOut) {
    if (n < 32) return;
    int j0 = lane, j1 = lane + 64, j2 = lane + 128;
    bool o0 = j0 < n, o1 = j1 < n, o2 = j2 < n;
    float v0 = o0 ? cval[q * CAPB + j0] : 0.f;
    float v1 = o1 ? cval[q * CAPB + j1] : 0.f;
    float v2 = o2 ? cval[q * CAPB + j2] : 0.f;
    ushort i0 = o0 ? cidx[q * CAPB + j0] : 0;
    ushort i1 = o1 ? cidx[q * CAPB + j1] : 0;
    ushort i2 = o2 ? cidx[q * CAPB + j2] : 0;
    unsigned long long k0 = o0 ? packkey(v0, (int)i0) : 0ULL;
    unsigned long long k1 = o1 ? packkey(v1, (int)i1) : 0ULL;
    unsigned long long k2 = o2 ? packkey(v2, (int)i2) : 0ULL;
    unsigned long long lo = 0, hi = (1ULL << 45) - 1;
    while (lo < hi) {
        unsigned long long mid = (lo + hi + 1) >> 1;
        int c = (int)__popcll(__ballot(k0 >= mid)) + (int)__popcll(__ballot(k1 >= mid)) +
                (int)__popcll(__ballot(k2 >= mid));
        if (c >= 32) lo = mid;
        else hi = mid - 1;
    }
    unsigned long long K = lo;
    unsigned long long lm = (1ULL << lane) - 1;
    int base = 0;
    {
        unsigned long long m = __ballot(k0 >= K);
        if (k0 >= K) { int p = base + (int)__popcll(m & lm); cval[q * CAPB + p] = v0; cidx[q * CAPB + p] = i0; }
        base += (int)__popcll(m);
    }
    {
        unsigned long long m = __ballot(k1 >= K);
        if (k1 >= K) { int p = base + (int)__popcll(m & lm); cval[q * CAPB + p] = v1; cidx[q * CAPB + p] = i1; }
        base += (int)__popcll(m);
    }
    {
        unsigned long long m = __ballot(k2 >= K);
        if (k2 >= K) { int p = base + (int)__popcll(m & lm); cval[q * CAPB + p] = v2; cidx[q * CAPB + p] = i2; }
        base += (int)__popcll(m);
    }
    if (thrOut && lane == 0) *thrOut = keyval(K);
}

// Exact top-32 retain, 1 slot/lane (n<=64): value descend + exact tie fallback.
__device__ __forceinline__ float shrink1v(float v0, ushort i0, bool o0,
                                          float* __restrict__ bv,
                                          ushort* __restrict__ bi, int lane) {
    uint s0 = o0 ? sortable32(v0) : 0u;
    uint S = 0;
#pragma unroll 1
    for (int bit = 31; bit >= 0; --bit) {
        uint cand = S | (1u << bit);
        if ((int)__popcll(__ballot(s0 >= cand)) >= 32) S = cand;
    }
    unsigned long long g = __ballot(s0 > S);
    unsigned long long e = __ballot(o0 && s0 == S);
    int cgt = (int)__popcll(g), ceq = (int)__popcll(e);
    unsigned long long lm = (1ULL << lane) - 1;
    if (cgt + ceq == 32) {
        if (s0 > S) { int p = (int)__popcll(g & lm); bv[p] = v0; bi[p] = i0; }
        if (o0 && s0 == S) { int p = cgt + (int)__popcll(e & lm); bv[p] = v0; bi[p] = i0; }
        return unsortable32(S);
    }
    unsigned long long k0 = o0 ? packkey(v0, (int)i0) : 0ULL;
    unsigned long long K = 0;
#pragma unroll 1
    for (int bit = 44; bit >= 0; --bit) {
        unsigned long long cand = K | (1ULL << bit);
        if ((int)__popcll(__ballot(k0 >= cand)) >= 32) K = cand;
    }
    unsigned long long m = __ballot(k0 >= K);
    if (k0 >= K) { int p = (int)__popcll(m & lm); bv[p] = v0; bi[p] = i0; }
    return keyval(K);
}

// Exact top-32 retain, 3 slots/lane (n<=192): value descend + tie fallback.
__device__ __forceinline__ float shrink3v(float* __restrict__ bv,
                                          ushort* __restrict__ bi,
                                          int n, int lane) {
    int j0 = lane, j1 = lane + 64, j2 = lane + 128;
    bool o0 = j0 < n, o1 = j1 < n, o2 = j2 < n;
    float v0 = o0 ? bv[j0] : 0.f, v1 = o1 ? bv[j1] : 0.f, v2 = o2 ? bv[j2] : 0.f;
    ushort i0 = o0 ? bi[j0] : 0, i1 = o1 ? bi[j1] : 0, i2 = o2 ? bi[j2] : 0;
    uint s0 = o0 ? sortable32(v0) : 0u, s1 = o1 ? sortable32(v1) : 0u;
    uint s2 = o2 ? sortable32(v2) : 0u;
    uint S = 0;
#pragma unroll 1
    for (int bit = 31; bit >= 0; --bit) {
        uint cand = S | (1u << bit);
        int c = (int)__popcll(__ballot(s0 >= cand)) + (int)__popcll(__ballot(s1 >= cand)) +
                (int)__popcll(__ballot(s2 >= cand));
        if (c >= 32) S = cand;
    }
    unsigned long long g0 = __ballot(s0 > S), g1 = __ballot(s1 > S), g2 = __ballot(s2 > S);
    unsigned long long e0 = __ballot(o0 && s0 == S), e1 = __ballot(o1 && s1 == S), e2 = __ballot(o2 && s2 == S);
    int cgt = (int)__popcll(g0) + (int)__popcll(g1) + (int)__popcll(g2);
    int ceq = (int)__popcll(e0) + (int)__popcll(e1) + (int)__popcll(e2);
    unsigned long long lm = (1ULL << lane) - 1;
    if (cgt + ceq == 32) {
        int base = 0;
        if (s0 > S) { int p = base + (int)__popcll(g0 & lm); bv[p] = v0; bi[p] = i0; } base += (int)__popcll(g0);
        if (s1 > S) { int p = base + (int)__popcll(g1 & lm); bv[p] = v1; bi[p] = i1; } base += (int)__popcll(g1);
        if (s2 > S) { int p = base + (int)__popcll(g2 & lm); bv[p] = v2; bi[p] = i2; } base += (int)__popcll(g2);
        if (o0 && s0 == S) { int p = base + (int)__popcll(e0 & lm); bv[p] = v0; bi[p] = i0; } base += (int)__popcll(e0);
        if (o1 && s1 == S) { int p = base + (int)__popcll(e1 & lm); bv[p] = v1; bi[p] = i1; } base += (int)__popcll(e1);
        if (o2 && s2 == S) { int p = base + (int)__popcll(e2 & lm); bv[p] = v2; bi[p] = i2; }
        return unsortable32(S);
    }
    unsigned long long k0 = o0 ? packkey(v0, (int)i0) : 0ULL;
    unsigned long long k1 = o1 ? packkey(v1, (int)i1) : 0ULL;
    unsigned long long k2 = o2 ? packkey(v2, (int)i2) : 0ULL;
    unsigned long long K = 0;
#pragma unroll 1
    for (int bit = 44; bit >= 0; --bit) {
        unsigned long long cand = K | (1ULL << bit);
        int c = (int)__popcll(__ballot(k0 >= cand)) + (int)__popcll(__ballot(k1 >= cand)) +
                (int)__popcll(__ballot(k2 >= cand));
        if (c >= 32) K = cand;
    }
    int base = 0;
    {
        unsigned long long m = __ballot(k0 >= K);
        if (k0 >= K) { int p = base + (int)__popcll(m & lm); bv[p] = v0; bi[p] = i0; }
        base += (int)__popcll(m);
    }
    {
        unsigned long long m = __ballot(k1 >= K);
        if (k1 >= K) { int p = base + (int)__popcll(m & lm); bv[p] = v1; bi[p] = i1; }
        base += (int)__popcll(m);
    }
    {
        unsigned long long m = __ballot(k2 >= K);
        if (k2 >= K) { int p = base + (int)__popcll(m & lm); bv[p] = v2; bi[p] = i2; }
        base += (int)__popcll(m);
    }
    return keyval(K);
}

// Exact top-32 retain over n<=CAPS (6 slots/lane): value-only 32-bit bitwise
// descend + exact tie fallback (45-bit key). Winners -> slots 0..31 (unsorted).
__device__ __forceinline__ float shrink6v(float* __restrict__ bv,
                                          ushort* __restrict__ bi,
                                          int n, int lane) {
    int j0 = lane, j1 = lane + 64, j2 = lane + 128, j3 = lane + 192, j4 = lane + 256, j5 = lane + 320;
    bool o0 = j0 < n, o1 = j1 < n, o2 = j2 < n, o3 = j3 < n, o4 = j4 < n, o5 = j5 < n;
    float v0 = o0 ? bv[j0] : 0.f, v1 = o1 ? bv[j1] : 0.f, v2 = o2 ? bv[j2] : 0.f;
    float v3 = o3 ? bv[j3] : 0.f, v4 = o4 ? bv[j4] : 0.f, v5 = o5 ? bv[j5] : 0.f;
    ushort i0 = o0 ? bi[j0] : 0, i1 = o1 ? bi[j1] : 0, i2 = o2 ? bi[j2] : 0;
    ushort i3 = o3 ? bi[j3] : 0, i4 = o4 ? bi[j4] : 0, i5 = o5 ? bi[j5] : 0;
    uint s0 = o0 ? sortable32(v0) : 0u, s1 = o1 ? sortable32(v1) : 0u;
    uint s2 = o2 ? sortable32(v2) : 0u, s3 = o3 ? sortable32(v3) : 0u;
    uint s4 = o4 ? sortable32(v4) : 0u, s5 = o5 ? sortable32(v5) : 0u;
    uint S = 0;
#pragma unroll 1
    for (int bit = 31; bit >= 0; --bit) {
        uint cand = S | (1u << bit);
        int c = (int)__popcll(__ballot(s0 >= cand)) + (int)__popcll(__ballot(s1 >= cand)) +
                (int)__popcll(__ballot(s2 >= cand)) + (int)__popcll(__ballot(s3 >= cand)) +
                (int)__popcll(__ballot(s4 >= cand)) + (int)__popcll(__ballot(s5 >= cand));
        if (c >= 32) S = cand;
    }
    unsigned long long g0 = __ballot(s0 > S), g1 = __ballot(s1 > S), g2 = __ballot(s2 > S);
    unsigned long long g3 = __ballot(s3 > S), g4 = __ballot(s4 > S), g5 = __ballot(s5 > S);
    unsigned long long e0 = __ballot(o0 && s0 == S), e1 = __ballot(o1 && s1 == S), e2 = __ballot(o2 && s2 == S);
    unsigned long long e3 = __ballot(o3 && s3 == S), e4 = __ballot(o4 && s4 == S), e5 = __ballot(o5 && s5 == S);
    int cgt = (int)__popcll(g0) + (int)__popcll(g1) + (int)__popcll(g2) +
              (int)__popcll(g3) + (int)__popcll(g4) + (int)__popcll(g5);
    int ceq = (int)__popcll(e0) + (int)__popcll(e1) + (int)__popcll(e2) +
              (int)__popcll(e3) + (int)__popcll(e4) + (int)__popcll(e5);
    unsigned long long lm = (1ULL << lane) - 1;
    if (cgt + ceq == 32) {
        int base = 0;
        if (s0 > S) { int p = base + (int)__popcll(g0 & lm); bv[p] = v0; bi[p] = i0; } base += (int)__popcll(g0);
        if (s1 > S) { int p = base + (int)__popcll(g1 & lm); bv[p] = v1; bi[p] = i1; } base += (int)__popcll(g1);
        if (s2 > S) { int p = base + (int)__popcll(g2 & lm); bv[p] = v2; bi[p] = i2; } base += (int)__popcll(g2);
        if (s3 > S) { int p = base + (int)__popcll(g3 & lm); bv[p] = v3; bi[p] = i3; } base += (int)__popcll(g3);
        if (s4 > S) { int p = base + (int)__popcll(g4 & lm); bv[p] = v4; bi[p] = i4; } base += (int)__popcll(g4);
        if (s5 > S) { int p = base + (int)__popcll(g5 & lm); bv[p] = v5; bi[p] = i5; } base += (int)__popcll(g5);
        if (o0 && s0 == S) { int p = base + (int)__popcll(e0 & lm); bv[p] = v0; bi[p] = i0; } base += (int)__popcll(e0);
        if (o1 && s1 == S) { int p = base + (int)__popcll(e1 & lm); bv[p] = v1; bi[p] = i1; } base += (int)__popcll(e1);
        if (o2 && s2 == S) { int p = base + (int)__popcll(e2 & lm); bv[p] = v2; bi[p] = i2; } base += (int)__popcll(e2);
        if (o3 && s3 == S) { int p = base + (int)__popcll(e3 & lm); bv[p] = v3; bi[p] = i3; } base += (int)__popcll(e3);
        if (o4 && s4 == S) { int p = base + (int)__popcll(e4 & lm); bv[p] = v4; bi[p] = i4; } base += (int)__popcll(e4);
        if (o5 && s5 == S) { int p = base + (int)__popcll(e5 & lm); bv[p] = v5; bi[p] = i5; }
        return unsortable32(S);
    }
    unsigned long long k0 = o0 ? packkey(v0, (int)i0) : 0ULL;
    unsigned long long k1 = o1 ? packkey(v1, (int)i1) : 0ULL;
    unsigned long long k2 = o2 ? packkey(v2, (int)i2) : 0ULL;
    unsigned long long k3 = o3 ? packkey(v3, (int)i3) : 0ULL;
    unsigned long long k4 = o4 ? packkey(v4, (int)i4) : 0ULL;
    unsigned long long k5 = o5 ? packkey(v5, (int)i5) : 0ULL;
    unsigned long long K = 0;
#pragma unroll 1
    for (int bit = 44; bit >= 0; --bit) {
        unsigned long long cand = K | (1ULL << bit);
        int c = (int)__popcll(__ballot(k0 >= cand)) + (int)__popcll(__ballot(k1 >= cand)) +
                (int)__popcll(__ballot(k2 >= cand)) + (int)__popcll(__ballot(k3 >= cand)) +
                (int)__popcll(__ballot(k4 >= cand)) + (int)__popcll(__ballot(k5 >= cand));
        if (c >= 32) K = cand;
    }
    int base = 0;
    {
        unsigned long long m = __ballot(k0 >= K);
        if (k0 >= K) { int p = base + (int)__popcll(m & lm); bv[p] = v0; bi[p] = i0; }
        base += (int)__popcll(m);
    }
    {
        unsigned long long m = __ballot(k1 >= K);
        if (k1 >= K) { int p = base + (int)__popcll(m & lm); bv[p] = v1; bi[p] = i1; }
        base += (int)__popcll(m);
    }
    {
        unsigned long long m = __ballot(k2 >= K);
        if (k2 >= K) { int p = base + (int)__popcll(m & lm); bv[p] = v2; bi[p] = i2; }
        base += (int)__popcll(m);
    }
    {
        unsigned long long m = __ballot(k3 >= K);
        if (k3 >= K) { int p = base + (int)__popcll(m & lm); bv[p] = v3; bi[p] = i3; }
        base += (int)__popcll(m);
    }
    {
        unsigned long long m = __ballot(k4 >= K);
        if (k4 >= K) { int p = base + (int)__popcll(m & lm); bv[p] = v4; bi[p] = i4; }
        base += (int)__popcll(m);
    }
    {
        unsigned long long m = __ballot(k5 >= K);
        if (k5 >= K) { int p = base + (int)__popcll(m & lm); bv[p] = v5; bi[p] = i5; }
        base += (int)__popcll(m);
    }
    return keyval(K);
}

// ---- DMA helpers (rule #21: pre-swizzled sources, linear LDS dest) ----
__device__ __forceinline__ void stage_dma64(const ushort* __restrict__ gh,
                                            const ushort* __restrict__ gl,
                                            ushort* kh, ushort* kl,
                                            int wvi, int lane) {
#pragma unroll
    for (int i = 0; i < 2; ++i) {
        int off = (wvi * 2 + i) * 1024;
        __builtin_amdgcn_global_load_lds(
            (const AS1 uint*)((const char*)gh + off + lane * 16),
            (AS3 uint*)((char*)kh + off), 16, 0, 0);
        __builtin_amdgcn_global_load_lds(
            (const AS1 uint*)((const char*)gl + off + lane * 16),
            (AS3 uint*)((char*)kl + off), 16, 0, 0);
    }
}

// 8KB linear chunk
__device__ __forceinline__ void stage_lin(const char* __restrict__ g, char* dst,
                                          int wvi, int lane) {
#pragma unroll
    for (int i = 0; i < 2; ++i) {
        int base = (wvi * 2 + i) * 1024;
        __builtin_amdgcn_global_load_lds((const AS1 uint*)(g + base + lane * 16),
                                         (AS3 uint*)(dst + base), 16, 0, 0);
    }
}

// 8KB chunk of V^T: 64 rows of 1024B, chunk slice 128B per row
__device__ __forceinline__ void stage_vt(const char* __restrict__ gb, int cByte,
                                         char* dst, int wvi, int lane) {
#pragma unroll
    for (int i = 0; i < 2; ++i) {
        int base = (wvi * 2 + i) * 1024;
        int off = base + lane * 16;
        int d = off >> 7, o7 = off & 127;
        __builtin_amdgcn_global_load_lds(
            (const AS1 uint*)(gb + (size_t)d * 1024 + cByte + o7),
            (AS3 uint*)(dst + base), 16, 0, 0);
    }
}

// ---- mask 64^3 -> 8^3 trilinear ----
__global__ void k_m8(const float* __restrict__ mask, float* __restrict__ m8) {
    int b = blockIdx.x, sp = threadIdx.x;
    int a = sp >> 6, bb = (sp >> 3) & 7, cc = sp & 7;
    const float* mb = mask + (size_t)b * 262144;
    int i0 = 8 * a + 3, j0 = 8 * bb + 3, k0 = 8 * cc + 3;
    float s = 0.f;
#pragma unroll
    for (int di = 0; di < 2; ++di)
#pragma unroll
        for (int dj = 0; dj < 2; ++dj)
#pragma unroll
            for (int dk = 0; dk < 2; ++dk)
                s += mb[(i0 + di) * 4096 + (j0 + dj) * 64 + (k0 + dk)];
    m8[b * NS + sp] = s * 0.125f;
}

// ---- tok[b][s][d] = x[b][d][s]*m8[b][s] + pe[d][s] ----
__global__ void k_tok(const float* __restrict__ x, const float* __restrict__ pe,
                      const float* __restrict__ m8, float* __restrict__ tok) {
    __shared__ float t[32][33];
    int b = blockIdx.z;
    int sp0 = blockIdx.x * 32, d0 = blockIdx.y * 32;
    int tx = threadIdx.x, ty = threadIdx.y;
#pragma unroll
    for (int i = 0; i < 4; ++i) {
        int d = d0 + ty + i * 8;
        int sp = sp0 + tx;
        float v = x[((size_t)(b * ND + d)) * NS + sp] * m8[b * NS + sp] + pe[(size_t)d * NS + sp];
        t[ty + i * 8][tx] = v;
    }
    __syncthreads();
#pragma unroll
    for (int i = 0; i < 4; ++i) {
        int sp = sp0 + ty + i * 8;
        int d = d0 + tx;
        tok[((size_t)(b * NS) + sp) * ND + d] = t[tx][ty + i * 8];
    }
}

// ---- mem_k fp32 -> bf16 hi/lo pre-swizzled rows [m][64] ----
__global__ void k_mksplit(const float* __restrict__ mk, ushort* __restrict__ mh,
                          ushort* __restrict__ ml) {
    int t = blockIdx.x * 256 + threadIdx.x;
    int g = t & 7;
    int m = (t >> 3) & 8191;
    int b = t >> 16;
    const float* src = mk + ((size_t)(b * NM + m) * 64 + g * 8);
    float v[8];
#pragma unroll
    for (int j = 0; j < 8; ++j) v[j] = src[j];
    s16x8 hv, lv;
    split8(v, hv, lv);
    size_t rowbyte = (size_t)(b * NM + m) * 128;
    size_t off = rowbyte + (size_t)((g * 16) ^ ((m & 7) << 4));
    *(s16x8*)((char*)mh + off) = hv;
    *(s16x8*)((char*)ml + off) = lv;
}

// ---- mem_k [B,M,64] -> memkT [B,64,M] (mid path) ----
__global__ void k_memkT(const float* __restrict__ mk, float* __restrict__ mt) {
    __shared__ float t[32][33];
    int b = blockIdx.z;
    int m0 = blockIdx.x * 32, d0 = blockIdx.y * 32;
    int tx = threadIdx.x, ty = threadIdx.y;
    const float* src = mk + (size_t)b * NM * NHD;
    float* dst = mt + (size_t)b * NHD * NM;
#pragma unroll
    for (int i = 0; i < 4; ++i)
        t[ty + i * 8][tx] = src[(size_t)(m0 + ty + i * 8) * NHD + d0 + tx];
    __syncthreads();
#pragma unroll
    for (int i = 0; i < 4; ++i)
        dst[(size_t)(d0 + ty + i * 8) * NM + m0 + tx] = t[tx][ty + i * 8];
}

// ---- qmat (mid path), h-major rows ----
__global__ void k_qmat(const float* __restrict__ qkv, float* __restrict__ qmat) {
    int id = blockIdx.x * 256 + threadIdx.x;
    int r = id >> 4, dj = (id & 15) * 4;
    int b = r >> 12, h = (r >> 9) & 7, s = r & 511;
    float4 v = *(const float4*)&qkv[((size_t)(b * NS + s)) * 1536 + h * 64 + dj];
    v.x *= 0.125f; v.y *= 0.125f; v.z *= 0.125f; v.w *= 0.125f;
    *(float4*)&qmat[(size_t)r * 64 + dj] = v;
}

// ---- W [K][N] fp32 -> transposed split bf16 [N][K] hi/lo, swizzled rows ----
__global__ void k_wsplitT(const float* __restrict__ W, ushort* __restrict__ WH,
                          ushort* __restrict__ WL, int K, int N) {
    __shared__ float t[32][65];
    int l = blockIdx.z;
    const float* Wl = W + (size_t)l * K * N;
    ushort* WHl = WH + (size_t)l * N * K;
    ushort* WLl = WL + (size_t)l * N * K;
    int n0 = blockIdx.x * 32, k0 = blockIdx.y * 64;
    int tx = threadIdx.x, ty = threadIdx.y;
#pragma unroll
    for (int i = 0; i < 8; ++i) {
        int k = ty * 8 + i;
        t[tx][k] = Wl[(size_t)(k0 + k) * N + n0 + tx];
    }
    __syncthreads();
    int tid = ty * 32 + tx;
    int r = tid >> 3, gg = tid & 7;
    float v[8];
#pragma unroll
    for (int j = 0; j < 8; ++j) v[j] = t[r][gg * 8 + j];
    s16x8 hv, lv;
    split8(v, hv, lv);
    size_t byte = (size_t)(n0 + r) * (2 * K) + (size_t)(k0 >> 6) * 128 +
                  (size_t)(((gg * 16)) ^ ((r & 7) << 4));
    *(s16x8*)((char*)WHl + byte) = hv;
    *(s16x8*)((char*)WLl + byte) = lv;
}

// ---- activation X [M][K] fp32 -> split bf16 hi/lo swizzled rows ----
__global__ void k_asplit(const float* __restrict__ X, ushort* __restrict__ XH,
                         ushort* __restrict__ XL, int K) {
    int id = blockIdx.x * 256 + threadIdx.x;
    int gtot = K >> 3;
    int m = id / gtot, g = id - m * gtot;
    const float* src = X + (size_t)m * K + g * 8;
    float v[8];
    *(float4*)&v[0] = *(const float4*)(src);
    *(float4*)&v[4] = *(const float4*)(src + 4);
    s16x8 hv, lv;
    split8(v, hv, lv);
    int kc = g >> 3, gg = g & 7;
    size_t byte = (size_t)m * (2 * K) + (size_t)kc * 128 +
                  (size_t)((gg * 16) ^ ((m & 7) << 4));
    *(s16x8*)((char*)XH + byte) = hv;
    *(s16x8*)((char*)XL + byte) = lv;
}

// ---- OLD split-bf16 MFMA GEMM (mid-path only) ----
template <int BM, int BN, int EPI>
__global__ __launch_bounds__(256) void k_gmm(
    const float* __restrict__ A, const float* __restrict__ W,
    const float* __restrict__ bias, const float* __restrict__ resid,
    float* __restrict__ C, int M, int N, int K) {
    constexpr int PAD = 40;
    constexpr int FM = BM / 32, FN = BN / 32;
    __shared__ __align__(16) ushort Ah[BM * PAD];
    __shared__ __align__(16) ushort Al[BM * PAD];
    __shared__ __align__(16) ushort Bh[BN * PAD];
    __shared__ __align__(16) ushort Bl[BN * PAD];
    int tid = threadIdx.x, lane = tid & 63, wvi = tid >> 6;
    int wr = wvi >> 1, wc = wvi & 1;
    int bn = blockIdx.x * BN, bm = blockIdx.y * BM;
    constexpr int FPTA = BM / 8;
    constexpr int TPRA = 32 / FPTA;
    int arow = tid / TPRA;
    int akoff = (tid % TPRA) * FPTA;
    const float* Ap = A + (size_t)(bm + arow) * K + akoff;
    constexpr int FPTB = BN / 8;
    int bkrow = tid >> 3;
    int bnoff = (tid & 7) * FPTB;
    const float* Wp = W + (size_t)bkrow * N + bn + bnoff;
    float abuf[FPTA], bbuf[FPTB];
#pragma unroll
    for (int j = 0; j < FPTA; j += 4) *(float4*)&abuf[j] = *(const float4*)(Ap + j);
#pragma unroll
    for (int j = 0; j < FPTB; j += 4) *(float4*)&bbuf[j] = *(const float4*)(Wp + j);
    f32x4 acc[FM][FN] = {};
    for (int k0 = 0; k0 < K; k0 += 32) {
#pragma unroll
        for (int g = 0; g < FPTA / 8; ++g) {
            s16x8 hv, lv;
            split8(&abuf[g * 8], hv, lv);
            *(s16x8*)&Ah[arow * PAD + akoff + g * 8] = hv;
            *(s16x8*)&Al[arow * PAD + akoff + g * 8] = lv;
        }
#pragma unroll
        for (int j = 0; j < FPTB; ++j) {
            ushort h, l;
            split1(bbuf[j], h, l);
            Bh[(bnoff + j) * PAD + bkrow] = h;
            Bl[(bnoff + j) * PAD + bkrow] = l;
        }
        __syncthreads();
        if (k0 + 32 < K) {
#pragma unroll
            for (int j = 0; j < FPTA; j += 4)
                *(float4*)&abuf[j] = *(const float4*)(Ap + k0 + 32 + j);
#pragma unroll
            for (int j = 0; j < FPTB; j += 4)
                *(float4*)&bbuf[j] = *(const float4*)(Wp + (size_t)(k0 + 32) * N + j);
        }
        s16x8 fah[FM], fal[FM], fbh[FN], fbl[FN];
        int kb = (lane >> 4) * 8;
#pragma unroll
        for (int fm = 0; fm < FM; ++fm) {
            int row = wr * (BM / 2) + fm * 16 + (lane & 15);
            fah[fm] = *(const s16x8*)&Ah[row * PAD + kb];
            fal[fm] = *(const s16x8*)&Al[row * PAD + kb];
        }
#pragma unroll
        for (int fn = 0; fn < FN; ++fn) {
            int row = wc * (BN / 2) + fn * 16 + (lane & 15);
            fbh[fn] = *(const s16x8*)&Bh[row * PAD + kb];
            fbl[fn] = *(const s16x8*)&Bl[row * PAD + kb];
        }
#pragma unroll
        for (int fm = 0; fm < FM; ++fm)
#pragma unroll
            for (int fn = 0; fn < FN; ++fn) {
                acc[fm][fn] = __builtin_amdgcn_mfma_f32_16x16x32_bf16(fah[fm], fbh[fn], acc[fm][fn], 0, 0, 0);
                acc[fm][fn] = __builtin_amdgcn_mfma_f32_16x16x32_bf16(fah[fm], fbl[fn], acc[fm][fn], 0, 0, 0);
                acc[fm][fn] = __builtin_amdgcn_mfma_f32_16x16x32_bf16(fal[fm], fbh[fn], acc[fm][fn], 0, 0, 0);
            }
        __syncthreads();
    }
#pragma unroll
    for (int fm = 0; fm < FM; ++fm) {
#pragma unroll
        for (int fn = 0; fn < FN; ++fn) {
            int n = bn + wc * (BN / 2) + fn * 16 + (lane & 15);
            float bb = 0.f;
            if (EPI != 3) bb = bias[n];
#pragma unroll
            for (int r = 0; r < 4; ++r) {
                int m = bm + wr * (BM / 2) + fm * 16 + (lane >> 4) * 4 + r;
                float o = acc[fm][fn][r] + bb;
                if (EPI == 1) o = gelu_f(o);
                else if (EPI == 2) o += resid[(size_t)m * N + n];
                C[(size_t)m * N + n] = o;
            }
        }
    }
}

// ---- pure-bf16 MFMA GEMM: pre-split swizzled operands, DMA staging ----
// EPI: 0 bias, 1 bias+gelu, 2 bias+resid, 3 plain, 4 bias+gelu->split CH/CL,
//      5 qkv fused split epilogue. bsA/bsB/bsC: per-blockIdx.z element strides.
template <int BM, int BN, int EPI>
__global__ __launch_bounds__(256) void k_gmm2(
    const ushort* __restrict__ AH, const ushort* __restrict__ AL,
    const ushort* __restrict__ BH, const ushort* __restrict__ BL,
    const float* __restrict__ bias, const float* __restrict__ resid,
    float* __restrict__ C, ushort* __restrict__ CH, ushort* __restrict__ CL,
    ushort* __restrict__ C2H, ushort* __restrict__ C2L,
    ushort* __restrict__ C3H, ushort* __restrict__ C3L,
    int M, int N, int K, size_t bsA, size_t bsB, size_t bsC) {
    constexpr int FM = BM / 32, FN = BN / 32;
    __shared__ __align__(16) ushort sAh[BM * 64];
    __shared__ __align__(16) ushort sAl[BM * 64];
    __shared__ __align__(16) ushort sBh[BN * 64];
    __shared__ __align__(16) ushort sBl[BN * 64];
    int bz = blockIdx.z;
    AH += (size_t)bz * bsA; AL += (size_t)bz * bsA;
    BH += (size_t)bz * bsB; BL += (size_t)bz * bsB;
    if (C) C += (size_t)bz * bsC;
    int tid = threadIdx.x, lane = tid & 63, wvi = tid >> 6;
    int wr = wvi >> 1, wc = wvi & 1;
    int bn = blockIdx.x * BN, bm = blockIdx.y * BM;
    int rloc = tid >> 3, bgr = (tid & 7) * 16;
    size_t rowstride = (size_t)(2 * K);
    f32x4 acc[FM][FN] = {};

    for (int k0 = 0; k0 < K; k0 += 64) {
        __syncthreads();
        size_t kcb = (size_t)k0 * 2;
#pragma unroll
        for (int i = 0; i < BM / 32; ++i) {
            int r = i * 32 + rloc;
            size_t g = (size_t)(bm + r) * rowstride + kcb + bgr;
            __builtin_amdgcn_global_load_lds((const AS1 uint*)((const char*)AH + g),
                                             (AS3 uint*)((char*)sAh + r * 128 + bgr), 16, 0, 0);
            __builtin_amdgcn_global_load_lds((const AS1 uint*)((const char*)AL + g),
                                             (AS3 uint*)((char*)sAl + r * 128 + bgr), 16, 0, 0);
        }
#pragma unroll
        for (int i = 0; i < BN / 32; ++i) {
            int r = i * 32 + rloc;
            size_t g = (size_t)(bn + r) * rowstride + kcb + bgr;
            __builtin_amdgcn_global_load_lds((const AS1 uint*)((const char*)BH + g),
                                             (AS3 uint*)((char*)sBh + r * 128 + bgr), 16, 0, 0);
            __builtin_amdgcn_global_load_lds((const AS1 uint*)((const char*)BL + g),
                                             (AS3 uint*)((char*)sBl + r * 128 + bgr), 16, 0, 0);
        }
        __syncthreads();
#pragma unroll
        for (int ks = 0; ks < 2; ++ks) {
            int kbyte = (ks * 32 + (lane >> 4) * 8) * 2;
            s16x8 fah[FM], fal[FM], fbh[FN], fbl[FN];
#pragma unroll
            for (int fm = 0; fm < FM; ++fm) {
                int row = wr * (BM / 2) + fm * 16 + (lane & 15);
                int by = row * 128 + (kbyte ^ ((row & 7) << 4));
                fah[fm] = *(const s16x8*)((const char*)sAh + by);
                fal[fm] = *(const s16x8*)((const char*)sAl + by);
            }
#pragma unroll
            for (int fn = 0; fn < FN; ++fn) {
                int row = wc * (BN / 2) + fn * 16 + (lane & 15);
                int by = row * 128 + (kbyte ^ ((row & 7) << 4));
                fbh[fn] = *(const s16x8*)((const char*)sBh + by);
                fbl[fn] = *(const s16x8*)((const char*)sBl + by);
            }
#pragma unroll
            for (int fm = 0; fm < FM; ++fm)
#pragma unroll
                for (int fn = 0; fn < FN; ++fn) {
                    acc[fm][fn] = __builtin_amdgcn_mfma_f32_16x16x32_bf16(fah[fm], fbh[fn], acc[fm][fn], 0, 0, 0);
                    acc[fm][fn] = __builtin_amdgcn_mfma_f32_16x16x32_bf16(fah[fm], fbl[fn], acc[fm][fn], 0, 0, 0);
                    acc[fm][fn] = __builtin_amdgcn_mfma_f32_16x16x32_bf16(fal[fm], fbh[fn], acc[fm][fn], 0, 0, 0);
                }
        }
    }
#pragma unroll
    for (int fm = 0; fm < FM; ++fm) {
#pragma unroll
        for (int fn = 0; fn < FN; ++fn) {
            int n = bn + wc * (BN / 2) + fn * 16 + (lane & 15);
            float bb = 0.f;
            if (EPI != 3) bb = bias[n];
#pragma unroll
            for (int r = 0; r < 4; ++r) {
                int m = bm + wr * (BM / 2) + fm * 16 + (lane >> 4) * 4 + r;
                float o = acc[fm][fn][r] + bb;
                if (EPI == 4) {
                    o = gelu_f(o);
                    ushort hh, ll;
                    split1(o, hh, ll);
                    size_t byb = (size_t)m * 2 * N + (size_t)(n >> 6) * 128 +
                                 (size_t)(((((n >> 3) & 7) * 16)) ^ ((m & 7) << 4)) + (n & 7) * 2;
                    *(ushort*)((char*)CH + byb) = hh;
                    *(ushort*)((char*)CL + byb) = ll;
                } else if (EPI == 5) {
                    int seg = n >> 9;  // block-uniform
                    int hh_ = (n >> 6) & 7, dd = n & 63;
                    int bq = m >> 9, sq = m & 511;
                    ushort hh, ll;
                    if (seg == 0) {
                        split1(o * 0.125f, hh, ll);
                        size_t rr = (size_t)bq * 4096 + hh_ * 512 + sq;
                        size_t by = rr * 128 + (size_t)((((dd >> 3) * 16)) ^ ((sq & 7) << 4)) + (dd & 7) * 2;
                        *(ushort*)((char*)CH + by) = hh;
                        *(ushort*)((char*)CL + by) = ll;
                    } else if (seg == 1) {
                        split1(o, hh, ll);
                        size_t rr = (size_t)bq * 4096 + hh_ * 512 + sq;
                        size_t by = rr * 128 + (size_t)((((dd >> 3) * 16)) ^ ((sq & 7) << 4)) + (dd & 7) * 2;
                        *(ushort*)((char*)C2H + by) = hh;
                        *(ushort*)((char*)C2L + by) = ll;
                    } else {
                        split1(o, hh, ll);
                        size_t rr = (size_t)(bq * 8 + hh_) * 64 + dd;
                        size_t by = rr * 1024 + (size_t)(sq >> 6) * 128 +
                                    (size_t)(((((sq >> 3) & 7) * 16)) ^ ((dd & 7) << 4)) + (sq & 7) * 2;
                        *(ushort*)((char*)C3H + by) = hh;
                        *(ushort*)((char*)C3L + by) = ll;
                    }
                } else {
                    if (EPI == 1) o = gelu_f(o);
                    else if (EPI == 2) o += resid[(size_t)m * N + n];
                    C[(size_t)m * N + n] = o;
                }
            }
        }
    }
}

// ---- MFMA flash attention: grid (8 qt, NH, NB), 256 thr = 4 waves ----
__global__ __launch_bounds__(256) void k_attn2(
    const ushort* __restrict__ QH, const ushort* __restrict__ QL,
    const ushort* __restrict__ KH, const ushort* __restrict__ KL,
    const ushort* __restrict__ VTH, const ushort* __restrict__ VTL,
    float* __restrict__ ao) {
    __shared__ __align__(16) char SM[81920];
    int qt = blockIdx.x, h = blockIdx.y, b = blockIdx.z;
    int tid = threadIdx.x, lane = tid & 63, wvi = tid >> 6;
    size_t R = ((size_t)(b * NH + h)) * NS;
    const char* KHg = (const char*)KH + R * 128;
    const char* KLg = (const char*)KL + R * 128;
    const char* VHg = (const char*)VTH + ((size_t)(b * NH + h) * 64) * 1024;
    const char* VLg = (const char*)VTL + ((size_t)(b * NH + h) * 64) * 1024;

    stage_lin((const char*)QH + (R + qt * 64) * 128, SM + 65536, wvi, lane);
    stage_lin((const char*)QL + (R + qt * 64) * 128, SM + 73728, wvi, lane);
    stage_lin(KHg, SM + 0, wvi, lane);
    stage_lin(KLg, SM + 8192, wvi, lane);
    stage_vt(VHg, 0, SM + 32768, wvi, lane);
    stage_vt(VLg, 0, SM + 40960, wvi, lane);
    __syncthreads();

    s16x8 fqh[2], fql[2];
#pragma unroll
    for (int ks = 0; ks < 2; ++ks) {
        int row = wvi * 16 + (lane & 15);
        int by = row * 128 + ((((ks * 32 + (lane >> 4) * 8) * 2)) ^ ((row & 7) << 4));
        fqh[ks] = *(const s16x8*)(SM + 65536 + by);
        fql[ks] = *(const s16x8*)(SM + 73728 + by);
    }

    float mr_[4] = {-FLT_MAX, -FLT_MAX, -FLT_MAX, -FLT_MAX};
    float lr_[4] = {0.f, 0.f, 0.f, 0.f};
    f32x4 acc_o[4] = {};

    for (int c = 0; c < 8; ++c) {
        const char* khc = SM + ((c & 1) ? 16384 : 0);
        const char* klc = khc + 8192;
        const char* vhc = SM + 32768 + ((c & 1) ? 16384 : 0);
        const char* vlc = vhc + 8192;
        if (c + 1 < 8) {
            char* khn = SM + ((c & 1) ? 0 : 16384);
            char* vhn = SM + 32768 + ((c & 1) ? 0 : 16384);
            stage_lin(KHg + (size_t)(c + 1) * 8192, khn, wvi, lane);
            stage_lin(KLg + (size_t)(c + 1) * 8192, khn + 8192, wvi, lane);
            stage_vt(VHg, (c + 1) * 128, vhn, wvi, lane);
            stage_vt(VLg, (c + 1) * 128, vhn + 8192, wvi, lane);
        }
        f32x4 sa[4] = {};
#pragma unroll
        for (int ks = 0; ks < 2; ++ks) {
            int kbyte = (ks * 32 + (lane >> 4) * 8) * 2;
#pragma unroll
            for (int fk = 0; fk < 4; ++fk) {
                int krow = fk * 16 + (lane & 15);
                int by = krow * 128 + (kbyte ^ ((krow & 7) << 4));
                s16x8 kh8 = *(const s16x8*)(khc + by);
                s16x8 kl8 = *(const s16x8*)(klc + by);
                sa[fk] = __builtin_amdgcn_mfma_f32_16x16x32_bf16(fqh[ks], kh8, sa[fk], 0, 0, 0);
                sa[fk] = __builtin_amdgcn_mfma_f32_16x16x32_bf16(fqh[ks], kl8, sa[fk], 0, 0, 0);
                sa[fk] = __builtin_amdgcn_mfma_f32_16x16x32_bf16(fql[ks], kh8, sa[fk], 0, 0, 0);
            }
        }
#pragma unroll
        for (int r = 0; r < 4; ++r) {
            float smax = fmaxf(fmaxf(sa[0][r], sa[1][r]), fmaxf(sa[2][r], sa[3][r]));
            smax = fmaxf(smax, __shfl_xor(smax, 1));
            smax = fmaxf(smax, __shfl_xor(smax, 2));
            smax = fmaxf(smax, __shfl_xor(smax, 4));
            smax = fmaxf(smax, __shfl_xor(smax, 8));
            float mn = fmaxf(mr_[r], smax);
            float alpha = __expf(mr_[r] - mn);
            mr_[r] = mn;
            float p0 = __expf(sa[0][r] - mn);
            float p1 = __expf(sa[1][r] - mn);
            float p2 = __expf(sa[2][r] - mn);
            float p3 = __expf(sa[3][r] - mn);
            float ls = p0 + p1 + p2 + p3;
            ls += __shfl_xor(ls, 1);
            ls += __shfl_xor(ls, 2);
            ls += __shfl_xor(ls, 4);
            ls += __shfl_xor(ls, 8);
            lr_[r] = lr_[r] * alpha + ls;
#pragma unroll
            for (int fd = 0; fd < 4; ++fd) acc_o[fd][r] *= alpha;
            int prow = wvi * 16 + (lane >> 4) * 4 + r;
            int sw = (prow & 7) << 4;
            int l15 = lane & 15;
            int wb = (l15 & 7) * 2;
            float pv_[4] = {p0, p1, p2, p3};
#pragma unroll
            for (int fk = 0; fk < 4; ++fk) {
                ushort hh, ll;
                split1(pv_[fk], hh, ll);
                int gran = fk * 2 + (l15 >> 3);
                int by = prow * 128 + ((gran * 16) ^ sw) + wb;
                *(ushort*)(SM + 65536 + by) = hh;
                *(ushort*)(SM + 73728 + by) = ll;
            }
        }
        s16x8 fph[2], fpl[2];
#pragma unroll
        for (int ks = 0; ks < 2; ++ks) {
            int prow = wvi * 16 + (lane & 15);
            int by = prow * 128 + ((((ks * 32 + (lane >> 4) * 8) * 2)) ^ ((prow & 7) << 4));
            fph[ks] = *(const s16x8*)(SM + 65536 + by);
            fpl[ks] = *(const s16x8*)(SM + 73728 + by);
        }
#pragma unroll
        for (int ks = 0; ks < 2; ++ks) {
            int kbyte = (ks * 32 + (lane >> 4) * 8) * 2;
#pragma unroll
            for (int fd = 0; fd < 4; ++fd) {
                int vrow = fd * 16 + (lane & 15);
                int by = vrow * 128 + (kbyte ^ ((vrow & 7) << 4));
                s16x8 vh8 = *(const s16x8*)(vhc + by);
                s16x8 vl8 = *(const s16x8*)(vlc + by);
                acc_o[fd] = __builtin_amdgcn_mfma_f32_16x16x32_bf16(fph[ks], vh8, acc_o[fd], 0, 0, 0);
                acc_o[fd] = __builtin_amdgcn_mfma_f32_16x16x32_bf16(fph[ks], vl8, acc_o[fd], 0, 0, 0);
                acc_o[fd] = __builtin_amdgcn_mfma_f32_16x16x32_bf16(fpl[ks], vh8, acc_o[fd], 0, 0, 0);
            }
        }
        __syncthreads();
    }
    float inv_[4];
#pragma unroll
    for (int r = 0; r < 4; ++r) inv_[r] = 1.0f / lr_[r];
#pragma unroll
    for (int fd = 0; fd < 4; ++fd)
#pragma unroll
        for (int r = 0; r < 4; ++r) {
            int srow = qt * 64 + wvi * 16 + (lane >> 4) * 4 + r;
            int col = h * 64 + fd * 16 + (lane & 15);
            ao[((size_t)(b * NS) + srow) * ND + col] = acc_o[fd][r] * inv_[r];
        }
}

// ---- OLD fp32 flash attention (mid/low fallback) ----
__global__ __launch_bounds__(256) void k_attn(const float* __restrict__ qkv,
                                              float* __restrict__ ao) {
    __shared__ float qs[32][65];
    __shared__ float ks[64][65];
    __shared__ float sc[32][68];
    __shared__ float pm[32][8];
    __shared__ float Mrow[32], Srow[32], Arow[32];
    int s0 = blockIdx.x * 32, h = blockIdx.y, b = blockIdx.z;
    int tid = threadIdx.x, tx = tid & 15, ty = tid >> 4;
    const float* base = qkv + (size_t)b * NS * 1536;
#pragma unroll
    for (int i = 0; i < 8; ++i) {
        int idx = tid + i * 256;
        int r = idx >> 6, d = idx & 63;
        qs[r][d] = base[(size_t)(s0 + r) * 1536 + h * 64 + d] * 0.125f;
    }
    if (tid < 32) { Mrow[tid] = -FLT_MAX; Srow[tid] = 0.f; }
    float accp[2][4] = {};
    int rg = tid >> 3, gg = tid & 7;
    for (int c = 0; c < 8; ++c) {
        __syncthreads();
#pragma unroll
        for (int i = 0; i < 16; ++i) {
            int idx = tid + i * 256;
            int r = idx >> 6, d = idx & 63;
            ks[r][d] = base[(size_t)(c * 64 + r) * 1536 + 512 + h * 64 + d];
        }
        __syncthreads();
        float a00 = 0, a01 = 0, a02 = 0, a03 = 0, a10 = 0, a11 = 0, a12 = 0, a13 = 0;
#pragma unroll 8
        for (int d = 0; d < 64; ++d) {
            float q0 = qs[ty][d], q1 = qs[ty + 16][d];
            float k0 = ks[tx][d], k1 = ks[tx + 16][d], k2 = ks[tx + 32][d], k3 = ks[tx + 48][d];
            a00 += q0 * k0; a01 += q0 * k1; a02 += q0 * k2; a03 += q0 * k3;
            a10 += q1 * k0; a11 += q1 * k1; a12 += q1 * k2; a13 += q1 * k3;
        }
        sc[ty][tx] = a00; sc[ty][tx + 16] = a01; sc[ty][tx + 32] = a02; sc[ty][tx + 48] = a03;
        sc[ty + 16][tx] = a10; sc[ty + 16][tx + 16] = a11; sc[ty + 16][tx + 32] = a12; sc[ty + 16][tx + 48] = a13;
        __syncthreads();
        float lm = -FLT_MAX;
#pragma unroll
        for (int j = 0; j < 8; ++j) lm = fmaxf(lm, sc[rg][gg * 8 + j]);
        pm[rg][gg] = lm;
        __syncthreads();
        if (gg == 0) {
            float nm = Mrow[rg];
#pragma unroll
            for (int j = 0; j < 8; ++j) nm = fmaxf(nm, pm[rg][j]);
            Arow[rg] = __expf(Mrow[rg] - nm);
            Mrow[rg] = nm;
        }
        __syncthreads();
        float mr = Mrow[rg];
        float ssp = 0.f;
#pragma unroll
        for (int j = 0; j < 8; ++j) {
            float e = __expf(sc[rg][gg * 8 + j] - mr);
            sc[rg][gg * 8 + j] = e;
            ssp += e;
        }
        pm[rg][gg] = ssp;
        __syncthreads();
        if (gg == 0) {
            float s2 = 0.f;
#pragma unroll
            for (int j = 0; j < 8; ++j) s2 += pm[rg][j];
            Srow[rg] = Srow[rg] * Arow[rg] + s2;
        }
        float al0 = Arow[ty], al1 = Arow[ty + 16];
#pragma unroll
        for (int j = 0; j < 4; ++j) { accp[0][j] *= al0; accp[1][j] *= al1; }
        __syncthreads();
#pragma unroll
        for (int i = 0; i < 16; ++i) {
            int idx = tid + i * 256;
            int r = idx >> 6, d = idx & 63;
            ks[r][d] = base[(size_t)(c * 64 + r) * 1536 + 1024 + h * 64 + d];
        }
        __syncthreads();
#pragma unroll 8
        for (int kk = 0; kk < 64; ++kk) {
            float p0 = sc[ty][kk], p1 = sc[ty + 16][kk];
            float v0 = ks[kk][tx], v1 = ks[kk][tx + 16], v2 = ks[kk][tx + 32], v3 = ks[kk][tx + 48];
            accp[0][0] += p0 * v0; accp[0][1] += p0 * v1; accp[0][2] += p0 * v2; accp[0][3] += p0 * v3;
            accp[1][0] += p1 * v0; accp[1][1] += p1 * v1; accp[1][2] += p1 * v2; accp[1][3] += p1 * v3;
        }
    }
    __syncthreads();
    float inv0 = 1.0f / Srow[ty], inv1 = 1.0f / Srow[ty + 16];
    size_t o0 = ((size_t)(b * NS) + s0 + ty) * ND + h * 64;
    size_t o1 = ((size_t)(b * NS) + s0 + ty + 16) * ND + h * 64;
    ao[o0 + tx] = accp[0][0] * inv0;
    ao[o0 + tx + 16] = accp[0][1] * inv0;
    ao[o0 + tx + 32] = accp[0][2] * inv0;
    ao[o0 + tx + 48] = accp[0][3] * inv0;
    ao[o1 + tx] = accp[1][0] * inv1;
    ao[o1 + tx + 16] = accp[1][1] * inv1;
    ao[o1 + tx + 32] = accp[1][2] * inv1;
    ao[o1 + tx + 48] = accp[1][3] * inv1;
}

// ==== KNN Phase B v5: 2 waves/query halves, cheap exact init + light shrinks ====
// gq = global query row within the current sims buffer; bb = bbase + (gq>>12).
__global__ __launch_bounds__(256) void k_ksel(
    const float* __restrict__ sims, const float* __restrict__ mv,
    const float* __restrict__ gate, float* __restrict__ ao, int bbase) {
    __shared__ float bval[4][CAPS];
    __shared__ ushort bidx[4][CAPS];
    int tid = threadIdx.x, lane = tid & 63, wvi = tid >> 6;
    int gq = blockIdx.x * 2 + (wvi >> 1);
    int bb = bbase + (gq >> 12), q = gq & 4095;
    int hf = wvi & 1;
    const float* sr = sims + (size_t)gq * NM + hf * 4096;
    float* bv = &bval[wvi][0];
    ushort* bi = &bidx[wvi][0];
    unsigned long long lm = (1ULL << lane) - 1;

    // issue loads for blocks 0..2 upfront
    float4 v0 = *(const float4*)(sr + lane * 4);
    float4 vA = *(const float4*)(sr + 256 + lane * 4);
    float4 vB = *(const float4*)(sr + 512 + lane * 4);

    // cheap valid lower bound: 32nd-largest of the 64 lane-maxima of block 0
    // (>=32 lanes have max >= it -> >=32 elements >= it -> it <= block0's 32nd)
    float mx4 = fmaxf(fmaxf(v0.x, v0.y), fmaxf(v0.z, v0.w));
    {
        uint sm = sortable32(mx4);
        uint S = 0;
#pragma unroll 1
        for (int bit = 31; bit >= 0; --bit) {
            uint cand = S | (1u << bit);
            if ((int)__popcll(__ballot(sm >= cand)) >= 32) S = cand;
        }
        mx4 = unsortable32(S);
    }
    float thr = mx4;
    int cnt = 0;
    {
        int m0 = hf * 4096 + lane * 4;
        bool px = v0.x >= thr, py = v0.y >= thr, pz = v0.z >= thr, pw = v0.w >= thr;
        unsigned long long bx = __ballot(px), by = __ballot(py), bz = __ballot(pz), bw = __ballot(pw);
        int nx = (int)__popcll(bx), ny = (int)__popcll(by), nz = (int)__popcll(bz), nw = (int)__popcll(bw);
        int b1 = nx, b2 = b1 + ny, b3 = b2 + nz;
        if (px) { int p = (int)__popcll(bx & lm); bv[p] = v0.x; bi[p] = (ushort)(m0 + 0); }
        if (py) { int p = b1 + (int)__popcll(by & lm); bv[p] = v0.y; bi[p] = (ushort)(m0 + 1); }
        if (pz) { int p = b2 + (int)__popcll(bz & lm); bv[p] = v0.z; bi[p] = (ushort)(m0 + 2); }
        if (pw) { int p = b3 + (int)__popcll(bw & lm); bv[p] = v0.w; bi[p] = (ushort)(m0 + 3); }
        cnt = b3 + nw;
    }
    // exact top-32 of block 0 (survivors contain it); >=32 survivors guaranteed
    if (cnt <= 64) {
        bool oo = lane < cnt;
        float vv = oo ? bv[lane] : 0.f;
        ushort ii = oo ? bi[lane] : 0;
        thr = shrink1v(vv, ii, oo, bv, bi, lane);
    } else {
        thr = shrink6v(bv, bi, cnt, lane);
    }
    cnt = 32;

    for (int i = 1; i < 16; ++i) {
        float4 vC = vB;
        if (i + 2 < 16) vC = *(const float4*)(sr + (size_t)(i + 2) * 256 + lane * 4);
        int m0 = hf * 4096 + i * 256 + lane * 4;
        bool px = vA.x >= thr, py = vA.y >= thr, pz = vA.z >= thr, pw = vA.w >= thr;
        unsigned long long bx = __ballot(px), by = __ballot(py), bz = __ballot(pz), bw = __ballot(pw);
        int nx = (int)__popcll(bx), ny = (int)__popcll(by), nz = (int)__popcll(bz), nw = (int)__popcll(bw);
        int b0 = cnt, b1 = b0 + nx, b2 = b1 + ny, b3 = b2 + nz;
        if (px) { int p = b0 + (int)__popcll(bx & lm); bv[p] = vA.x; bi[p] = (ushort)(m0 + 0); }
        if (py) { int p = b1 + (int)__popcll(by & lm); bv[p] = vA.y; bi[p] = (ushort)(m0 + 1); }
        if (pz) { int p = b2 + (int)__popcll(bz & lm); bv[p] = vA.z; bi[p] = (ushort)(m0 + 2); }
        if (pw) { int p = b3 + (int)__popcll(bw & lm); bv[p] = vA.w; bi[p] = (ushort)(m0 + 3); }
        cnt = b3 + nw;
        if (cnt >= TRIGS) {  // cnt <= 95+256=351 < CAPS
            thr = shrink6v(bv, bi, cnt, lane);
            cnt = 32;
        }
        vA = vB;
        vB = vC;
    }
    // final: half top-32 into slots 0..31 (n uniform; usually <=192)
    if (cnt <= 192) thr = shrink3v(bv, bi, cnt, lane);
    else thr = shrink6v(bv, bi, cnt, lane);
    __syncthreads();

    if (hf == 0) {
        // merge 64 entries (own 32 + partner 32) = 1-slot exact shrink
        float mval;
        ushort midx;
        if (lane < 32) { mval = bval[wvi][lane]; midx = bidx[wvi][lane]; }
        else { mval = bval[wvi + 1][lane - 32]; midx = bidx[wvi + 1][lane - 32]; }
        shrink1v(mval, midx, true, bv, bi, lane);
        // softmax over slots 0..31
        float val = (lane < 32) ? bv[lane] : -FLT_MAX;
        float mx = val;
#pragma unroll
        for (int off = 32; off; off >>= 1) mx = fmaxf(mx, __shfl_xor(mx, off));
        float e = (lane < 32) ? __expf(val - mx) : 0.f;
        float ssum = e;
#pragma unroll
        for (int off = 32; off; off >>= 1) ssum += __shfl_xor(ssum, off);
        float w = e / ssum;
        if (lane < 32) bv[lane] = w;
        // gather + blend: lane owns d = lane
        float acc = 0.f;
        const float* vb = mv + (size_t)bb * NM * NHD;
#pragma unroll 4
        for (int j = 0; j < 32; ++j) {
            float ww = bv[j];
            int idx = (int)bi[j];
            acc += ww * vb[(size_t)idx * NHD + lane];
        }
        int h = q >> 9, s = q & 511;
        float g = 1.0f / (1.0f + __expf(-gate[h]));
        float* aop = ao + ((size_t)(bb * NS) + s) * ND + h * 64 + lane;
        *aop = *aop * (1.0f - g) + acc * g;
    }
}

// ==== KNN v5 (small-ws fallback) ====
__global__ __launch_bounds__(256, 2) void k_knn5(
    const float* __restrict__ qkv, const ushort* __restrict__ mkh,
    const ushort* __restrict__ mkl, const float* __restrict__ mv,
    const float* __restrict__ gate, float* __restrict__ ao) {
    __shared__ __align__(16) char SM[63760];
    ushort* kh0 = (ushort*)SM;
    ushort* kl0 = (ushort*)(SM + 8192);
    ushort* kh1 = (ushort*)(SM + 16384);
    ushort* kl1 = (ushort*)(SM + 24576);
    float* cval = (float*)(SM + 32768);
    ushort* cidx = (ushort*)(SM + 53248);
    float* thrV = (float*)(SM + 63488);
    int* cnt = (int*)(SM + 63616);
    int* sflag = (int*)(SM + 63744);
    ushort* qh = (ushort*)(SM + 32768);
    ushort* ql = (ushort*)(SM + 36864);
    int b = blockIdx.y, s0 = blockIdx.x * 4;
    int tid = threadIdx.x, lane = tid & 63, wvi = tid >> 6;
    const ushort* mhb = mkh + (size_t)b * NM * 64;
    const ushort* mlb = mkl + (size_t)b * NM * 64;
    {
        int q = tid >> 3, dbase = (tid & 7) * 8;
        const float* src = &qkv[((size_t)(b * NS) + s0 + (q & 3)) * 1536 + (q >> 2) * 64 + dbase];
        float v[8];
#pragma unroll
        for (int j = 0; j < 8; ++j) v[j] = src[j] * 0.125f;
        s16x8 hv, lv;
        split8(v, hv, lv);
        int by = q * 128 + ((dbase * 2) ^ ((q & 7) << 4));
        *(s16x8*)((char*)qh + by) = hv;
        *(s16x8*)((char*)ql + by) = lv;
    }
    stage_dma64(mhb, mlb, kh0, kl0, wvi, lane);
    __syncthreads();
    s16x8 fqh[2][2], fql[2][2];
#pragma unroll
    for (int fq = 0; fq < 2; ++fq)
#pragma unroll
        for (int ks = 0; ks < 2; ++ks) {
            int row = fq * 16 + (lane & 15);
            int kb2 = (ks * 32 + (lane >> 4) * 8) * 2;
            int by = row * 128 + (kb2 ^ ((row & 7) << 4));
            fqh[fq][ks] = *(const s16x8*)((const char*)qh + by);
            fql[fq][ks] = *(const s16x8*)((const char*)ql + by);
        }
    if (tid < 32) { cnt[tid] = 0; thrV[tid] = -FLT_MAX; }
    if (tid == 0) *sflag = 0;
    __syncthreads();
    int qbase4 = (lane >> 4) * 4;
    int mrow = (lane & 15);
    for (int c = 0; c < NCC; ++c) {
        ushort* khc = (c & 1) ? kh1 : kh0;
        ushort* klc = (c & 1) ? kl1 : kl0;
        if (c + 1 < NCC) {
            size_t ro = (size_t)(c + 1) * KCC * 64;
            stage_dma64(mhb + ro, mlb + ro, (c & 1) ? kh0 : kh1, (c & 1) ? kl0 : kl1, wvi, lane);
        }
        float thc[2][4];
#pragma unroll
        for (int fq = 0; fq < 2; ++fq)
#pragma unroll
            for (int r = 0; r < 4; ++r) thc[fq][r] = thrV[fq * 16 + qbase4 + r];
        f32x4 acc[2] = {};
#pragma unroll
        for (int ks = 0; ks < 2; ++ks) {
            int row = wvi * 16 + mrow;
            int kb2 = (ks * 32 + (lane >> 4) * 8) * 2;
            int by = row * 128 + (kb2 ^ ((row & 7) << 4));
            s16x8 kh8 = *(const s16x8*)((const char*)khc + by);
            s16x8 kl8 = *(const s16x8*)((const char*)klc + by);
#pragma unroll
            for (int fq = 0; fq < 2; ++fq) {
                acc[fq] = __builtin_amdgcn_mfma_f32_16x16x32_bf16(fqh[fq][ks], kh8, acc[fq], 0, 0, 0);
                acc[fq] = __builtin_amdgcn_mfma_f32_16x16x32_bf16(fqh[fq][ks], kl8, acc[fq], 0, 0, 0);
                acc[fq] = __builtin_amdgcn_mfma_f32_16x16x32_bf16(fql[fq][ks], kh8, acc[fq], 0, 0, 0);
            }
        }
#pragma unroll
        for (int fq = 0; fq < 2; ++fq)
#pragma unroll
            for (int r = 0; r < 4; ++r) {
                float v = acc[fq][r];
                if (v >= thc[fq][r]) {
                    int q = fq * 16 + qbase4 + r;
                    int pos = atomicAdd(&cnt[q], 1);
                    if (pos < CAPB) {
                        cval[q * CAPB + pos] = v;
                        cidx[q * CAPB + pos] = (ushort)(c * KCC + wvi * 16 + mrow);
                    }
                    if (pos == TRIG) *sflag = 1;
                }
            }
        __syncthreads();
        if (*sflag) {
#pragma unroll 1
            for (int qq = 0; qq < 8; ++qq) {
                int q = wvi * 8 + qq;
                shrink_cheap(cval, cidx, q, cnt[q], lane, &thrV[q]);
                if (lane == 0) cnt[q] = 32;
            }
            if (tid == 0) *sflag = 0;
            __syncthreads();
        }
    }
#pragma unroll 1
    for (int qq = 0; qq < 8; ++qq) {
        int q = wvi * 8 + qq;
        shrink_cheap(cval, cidx, q, cnt[q], lane, nullptr);
    }
    __syncthreads();
    if (tid < 32) {
        int q = tid;
        float mx = -FLT_MAX;
#pragma unroll
        for (int j = 0; j < 32; ++j) mx = fmaxf(mx, cval[q * CAPB + j]);
        float es[32];
        float ssum = 0.f;
#pragma unroll
        for (int j = 0; j < 32; ++j) { es[j] = __expf(cval[q * CAPB + j] - mx); ssum += es[j]; }
        float inv = 1.0f / ssum;
#pragma unroll
        for (int j = 0; j < 32; ++j) cval[q * CAPB + j] = es[j] * inv;
    }
    __syncthreads();
    {
        int q = tid >> 3, dseg = (tid & 7) * 8;
        int h = q >> 2, si = q & 3;
        float r0x = 0, r0y = 0, r0z = 0, r0w = 0, r1x = 0, r1y = 0, r1z = 0, r1w = 0;
        const float* vb = mv + (size_t)b * NM * NHD;
        for (int j = 0; j < 32; ++j) {
            float w = cval[q * CAPB + j];
            int idx = (int)cidx[q * CAPB + j];
            const float* row = vb + (size_t)idx * NHD + dseg;
            float4 v0 = *(const float4*)(row);
            float4 v1 = *(const float4*)(row + 4);
            r0x += w * v0.x; r0y += w * v0.y; r0z += w * v0.z; r0w += w * v0.w;
            r1x += w * v1.x; r1y += w * v1.y; r1z += w * v1.z; r1w += w * v1.w;
        }
        float g = 1.0f / (1.0f + __expf(-gate[h]));
        float omg = 1.0f - g;
        float* aop = ao + ((size_t)(b * NS) + s0 + si) * ND + h * 64 + dseg;
        float rr[8] = {r0x, r0y, r0z, r0w, r1x, r1y, r1z, r1w};
#pragma unroll
        for (int k = 0; k < 8; ++k) aop[k] = aop[k] * omg + rr[k] * g;
    }
}

// ---- LayerNorm (plain, fallback) ----
__global__ __launch_bounds__(256) void k_ln(const float* __restrict__ X,
                                            const float* __restrict__ gam,
                                            const float* __restrict__ bet,
                                            float* __restrict__ Y) {
    __shared__ float red[4];
    __shared__ float sm, sv;
    int r = blockIdx.x, tid = threadIdx.x;
    const float* xr = X + (size_t)r * ND;
    float x0 = xr[tid], x1 = xr[tid + 256];
    float s = x0 + x1;
    for (int off = 32; off; off >>= 1) s += __shfl_down(s, off);
    if ((tid & 63) == 0) red[tid >> 6] = s;
    __syncthreads();
    if (tid == 0) sm = (red[0] + red[1] + red[2] + red[3]) * (1.0f / 512.0f);
    __syncthreads();
    float m = sm;
    float d0 = x0 - m, d1 = x1 - m;
    float vs = d0 * d0 + d1 * d1;
    for (int off = 32; off; off >>= 1) vs += __shfl_down(vs, off);
    if ((tid & 63) == 0) red[tid >> 6] = vs;
    __syncthreads();
    if (tid == 0) sv = rsqrtf((red[0] + red[1] + red[2] + red[3]) * (1.0f / 512.0f) + 1e-5f);
    __syncthreads();
    float rstd = sv;
    Y[(size_t)r * ND + tid] = d0 * rstd * gam[tid] + bet[tid];
    Y[(size_t)r * ND + tid + 256] = d1 * rstd * gam[tid + 256] + bet[tid + 256];
}

// ---- LayerNorm fused with split-bf16 output ----
__global__ __launch_bounds__(256) void k_ln2(const float* __restrict__ X,
                                             const float* __restrict__ gam,
                                             const float* __restrict__ bet,
                                             float* __restrict__ Y,
                                             ushort* __restrict__ YH,
                                             ushort* __restrict__ YL) {
    __shared__ float red[4];
    __shared__ float sm, sv;
    int r = blockIdx.x, tid = threadIdx.x;
    const float* xr = X + (size_t)r * ND;
    float x0 = xr[tid], x1 = xr[tid + 256];
    float s = x0 + x1;
    for (int off = 32; off; off >>= 1) s += __shfl_down(s, off);
    if ((tid & 63) == 0) red[tid >> 6] = s;
    __syncthreads();
    if (tid == 0) sm = (red[0] + red[1] + red[2] + red[3]) * (1.0f / 512.0f);
    __syncthreads();
    float m = sm;
    float d0 = x0 - m, d1 = x1 - m;
    float vs = d0 * d0 + d1 * d1;
    for (int off = 32; off; off >>= 1) vs += __shfl_down(vs, off);
    if ((tid & 63) == 0) red[tid >> 6] = vs;
    __syncthreads();
    if (tid == 0) sv = rsqrtf((red[0] + red[1] + red[2] + red[3]) * (1.0f / 512.0f) + 1e-5f);
    __syncthreads();
    float rstd = sv;
    float y0 = d0 * rstd * gam[tid] + bet[tid];
    float y1 = d1 * rstd * gam[tid + 256] + bet[tid + 256];
    Y[(size_t)r * ND + tid] = y0;
    Y[(size_t)r * ND + tid + 256] = y1;
    int sw = (r & 7) << 4;
    char* oh = (char*)YH + (size_t)r * 1024;
    char* ol = (char*)YL + (size_t)r * 1024;
    ushort hh, ll;
    split1(y0, hh, ll);
    int k0 = tid;
    int by0 = (k0 >> 6) * 128 + ((((k0 >> 3) & 7) * 16) ^ sw) + (k0 & 7) * 2;
    *(ushort*)(oh + by0) = hh;
    *(ushort*)(ol + by0) = ll;
    split1(y1, hh, ll);
    int k1 = tid + 256;
    int by1 = (k1 >> 6) * 128 + ((((k1 >> 3) & 7) * 16) ^ sw) + (k1 & 7) * 2;
    *(ushort*)(oh + by1) = hh;
    *(ushort*)(ol + by1) = ll;
}

// ---- mean pool: stage 1 partials ----
__global__ void k_pool2(const float* __restrict__ tok, float* __restrict__ part) {
    int c = blockIdx.x, b = blockIdx.y;
    int tid = threadIdx.x;
    int sp0 = c * 64;
    float a0 = 0.f, a1 = 0.f;
    const float* base = tok + ((size_t)(b * NS) + sp0) * ND;
#pragma unroll 4
    for (int i = 0; i < 64; ++i) {
        a0 += base[(size_t)i * ND + tid];
        a1 += base[(size_t)i * ND + tid + 256];
    }
    float* dst = part + ((size_t)(c * NB + b)) * ND;
    dst[tid] = a0;
    dst[tid + 256] = a1;
}

// ---- mean pool: stage 2 tree sum ----
__global__ void k_pool3(const float* __restrict__ part, float* __restrict__ pooled) {
    int b = blockIdx.x, d = threadIdx.x;
    float s = 0.f;
#pragma unroll
    for (int c = 0; c < 8; ++c) s += part[((size_t)(c * NB + b)) * ND + d];
    pooled[b * ND + d] = s * (1.0f / 512.0f);
}

__global__ void k_fc1(const float* __restrict__ pooled, const float* __restrict__ w,
                      const float* __restrict__ bias, float* __restrict__ o1) {
    int id = blockIdx.x * 256 + threadIdx.x;
    int b = id >> 10, j = id & 1023;
    float acc = bias[j];
    for (int d = 0; d < ND; ++d) acc += pooled[b * ND + d] * w[(size_t)d * NMLP + j];
    o1[id] = gelu_f(acc);
}

// ---- fc2: one wave per (b,c) output ----
__global__ __launch_bounds__(256) void k_fc2b(const float* __restrict__ o1,
                                              const float* __restrict__ w,
                                              const float* __restrict__ bias,
                                              float* __restrict__ out) {
    int c = blockIdx.x;
    int b = threadIdx.x >> 6, lane = threadIdx.x & 63;
    const float* o1b = o1 + b * NMLP;
    float acc = 0.f;
#pragma unroll
    for (int i = 0; i < 16; ++i) {
        int k = i * 64 + lane;
        acc += o1b[k] * w[(size_t)k * NC + c];
    }
    acc += __shfl_xor(acc, 32);
    acc += __shfl_xor(acc, 16);
    acc += __shfl_xor(acc, 8);
    acc += __shfl_xor(acc, 4);
    acc += __shfl_xor(acc, 2);
    acc += __shfl_xor(acc, 1);
    if (lane == 0) out[b * NC + c] = acc + bias[c];
}

extern "C" void kernel_launch(void* const* d_in, const int* in_sizes, int n_in,
                              void* d_out, int out_size, void* d_ws, size_t ws_size,
                              hipStream_t stream) {
    const float* x    = (const float*)d_in[0];
    const float* mask = (const float*)d_in[1];
    const float* pe   = (const float*)d_in[2];
    const float* Wqkv = (const float*)d_in[3];
    const float* bqkv = (const float*)d_in[4];
    const float* Wo   = (const float*)d_in[5];
    const float* bo   = (const float*)d_in[6];
    const float* ln1g = (const float*)d_in[7];
    const float* ln1b = (const float*)d_in[8];
    const float* W1   = (const float*)d_in[9];
    const float* b1   = (const float*)d_in[10];
    const float* W2   = (const float*)d_in[11];
    const float* b2   = (const float*)d_in[12];
    const float* ln2g = (const float*)d_in[13];
    const float* ln2b = (const float*)d_in[14];
    const float* gate = (const float*)d_in[15];
    const float* memk = (const float*)d_in[16];
    const float* memv = (const float*)d_in[17];
    const float* fc1w = (const float*)d_in[18];
    const float* fc1b = (const float*)d_in[19];
    const float* fc2w = (const float*)d_in[20];
    const float* fc2b_ = (const float*)d_in[21];
    float* out = (float*)d_out;

    float* ws = (float*)d_ws;

    // ---- big-path layout ----
    float* m8     = ws;                         // 2048
    ushort* mkh   = (ushort*)(m8 + 2048);       // 2097152 ush
    ushort* mkl   = mkh + 2097152;              // 2097152 ush
    float* tok    = (float*)(mkl + 2097152);    // 1048576
    float* qkv    = tok + 1048576;              // 3145728 (carved into split bufs)
    float* ao     = qkv + 3145728;              // 1048576
    float* pooled = ao + 1048576;               // 2048
    float* o1     = pooled + 2048;              // 4096
    ushort* aH    = (ushort*)(o1 + 4096);       // 1048576 ush
    ushort* aL    = aH + 1048576;               // 1048576 ush
    ushort* WqTH  = aL + 1048576;               // 4718592 ush
    ushort* WqTL  = WqTH + 4718592;
    ushort* WoTH  = WqTL + 4718592;             // 1572864 ush
    ushort* WoTL  = WoTH + 1572864;
    ushort* W1TH  = WoTL + 1572864;             // 6291456 ush
    ushort* W1TL  = W1TH + 6291456;
    ushort* W2TH  = W1TL + 6291456;             // 6291456 ush
    ushort* W2TL  = W2TH + 6291456;
    float* simsb  = (float*)(W2TL + 6291456);   // >= 32M floats
    // overlays inside simsb (dead during knn):
    ushort* fH  = (ushort*)(simsb + 4194304);
    ushort* fL  = fH + 4194304;
    float* ybuf = simsb + 8388608;
    float* ppart = simsb;                       // pool partials (tail only)
    // carve qkv fp32 region into split buffers (6 x 2MB)
    ushort* QHb  = (ushort*)qkv;
    ushort* QLb  = QHb + 1048576;
    ushort* KHb  = QLb + 1048576;
    ushort* KLb  = KHb + 1048576;
    ushort* VTHb = KLb + 1048576;
    ushort* VTLb = VTHb + 1048576;

    size_t needNew = (size_t)((simsb + 33554432) - ws) * sizeof(float);
    size_t need2   = needNew + (size_t)33554432 * sizeof(float);
    size_t need4   = needNew + (size_t)3 * 33554432 * sizeof(float);

    if (ws_size >= needNew) {
        int cb = (ws_size >= need4) ? 4 : ((ws_size >= need2) ? 2 : 1);
        k_m8<<<NB, 512, 0, stream>>>(mask, m8);
        k_mksplit<<<1024, 256, 0, stream>>>(memk, mkh, mkl);
        k_tok<<<dim3(16, 16, NB), dim3(32, 8), 0, stream>>>(x, pe, m8, tok);
        k_wsplitT<<<dim3(48, 8, 6), dim3(32, 8), 0, stream>>>(Wqkv, WqTH, WqTL, 512, 1536);
        k_wsplitT<<<dim3(16, 8, 6), dim3(32, 8), 0, stream>>>(Wo, WoTH, WoTL, 512, 512);
        k_wsplitT<<<dim3(64, 8, 6), dim3(32, 8), 0, stream>>>(W1, W1TH, W1TL, 512, 2048);
        k_wsplitT<<<dim3(16, 32, 6), dim3(32, 8), 0, stream>>>(W2, W2TH, W2TL, 2048, 512);
        k_asplit<<<512, 256, 0, stream>>>(tok, aH, aL, 512);

        for (int l = 0; l < NL; ++l) {
            k_gmm2<128, 128, 5><<<dim3(12, 16), 256, 0, stream>>>(
                aH, aL, WqTH + (size_t)l * 786432, WqTL + (size_t)l * 786432,
                bqkv + l * 1536, nullptr, nullptr, QHb, QLb, KHb, KLb, VTHb, VTLb,
                2048, 1536, 512, 0, 0, 0);
            k_attn2<<<dim3(8, NH, NB), 256, 0, stream>>>(QHb, QLb, KHb, KLb, VTHb, VTLb, ao);
            if (l == 0) {
                for (int bb0 = 0; bb0 < NB; bb0 += cb) {
                    k_gmm2<128, 128, 3><<<dim3(64, 32, cb), 256, 0, stream>>>(
                        QHb + (size_t)bb0 * 262144, QLb + (size_t)bb0 * 262144,
                        mkh + (size_t)bb0 * 524288, mkl + (size_t)bb0 * 524288,
                        nullptr, nullptr, simsb, nullptr, nullptr, nullptr, nullptr,
                        nullptr, nullptr, 4096, 8192, 64,
                        262144, 524288, 33554432);
                    k_ksel<<<2048 * cb, 256, 0, stream>>>(simsb, memv, gate, ao, bb0);
                }
            }
            k_asplit<<<512, 256, 0, stream>>>(ao, aH, aL, 512);
            k_gmm2<64, 64, 2><<<dim3(8, 32), 256, 0, stream>>>(
                aH, aL, WoTH + (size_t)l * 262144, WoTL + (size_t)l * 262144,
                bo + l * 512, tok, ybuf, nullptr, nullptr, nullptr, nullptr,
                nullptr, nullptr, 2048, 512, 512, 0, 0, 0);
            k_ln2<<<2048, 256, 0, stream>>>(ybuf, ln1g + l * 512, ln1b + l * 512, tok, aH, aL);
            k_gmm2<128, 128, 4><<<dim3(16, 16), 256, 0, stream>>>(
                aH, aL, W1TH + (size_t)l * 1048576, W1TL + (size_t)l * 1048576,
                b1 + l * 2048, nullptr, nullptr, fH, fL, nullptr, nullptr,
                nullptr, nullptr, 2048, 2048, 512, 0, 0, 0);
            k_gmm2<64, 64, 2><<<dim3(8, 32), 256, 0, stream>>>(
                fH, fL, W2TH + (size_t)l * 1048576, W2TL + (size_t)l * 1048576,
                b2 + l * 512, tok, ybuf, nullptr, nullptr, nullptr, nullptr,
                nullptr, nullptr, 2048, 512, 2048, 0, 0, 0);
            k_ln2<<<2048, 256, 0, stream>>>(ybuf, ln2g + l * 512, ln2b + l * 512, tok, aH, aL);
        }
        k_pool2<<<dim3(8, NB), 256, 0, stream>>>(tok, ppart);
        k_pool3<<<NB, 512, 0, stream>>>(ppart, pooled);
        k_fc1<<<16, 256, 0, stream>>>(pooled, fc1w, fc1b, o1);
        k_fc2b<<<NC, 256, 0, stream>>>(o1, fc2w, fc2b_, out);
        return;
    }

    // ---- MID/LOW fallback ----
    float* m8b     = ws;
    ushort* mkh2   = (ushort*)(m8b + 2048);
    ushort* mkl2   = mkh2 + 2097152;
    float* tok2    = (float*)(mkl2 + 2097152);
    float* qkv2    = tok2 + 1048576;
    float* ao2     = qkv2 + 3145728;
    float* ybuf2   = ao2 + 1048576;
    float* ff12    = ybuf2 + 1048576;
    float* pooled2 = ff12 + 4194304;
    float* o12     = pooled2 + 2048;
    float* qmat2   = o12 + 4096;
    float* memkT2  = qmat2 + 1048576;
    float* simsb2  = memkT2 + 2097152;

    size_t needMid = (size_t)((simsb2 + 33554432) - ws) * sizeof(float);
    bool big = ws_size >= needMid;

    k_m8<<<NB, 512, 0, stream>>>(mask, m8b);
    if (big)
        k_memkT<<<dim3(NM / 32, 2, NB), dim3(32, 8), 0, stream>>>(memk, memkT2);
    else
        k_mksplit<<<1024, 256, 0, stream>>>(memk, mkh2, mkl2);
    k_tok<<<dim3(16, 16, NB), dim3(32, 8), 0, stream>>>(x, pe, m8b, tok2);

    for (int l = 0; l < NL; ++l) {
        k_gmm<128, 128, 0><<<dim3(12, 16), 256, 0, stream>>>(
            tok2, Wqkv + (size_t)l * 512 * 1536, bqkv + l * 1536, nullptr, qkv2, 2048, 1536, 512);
        k_attn<<<dim3(16, NH, NB), 256, 0, stream>>>(qkv2, ao2);
        if (l == 0) {
            if (big) {
                k_qmat<<<1024, 256, 0, stream>>>(qkv2, qmat2);
                for (int bb = 0; bb < NB; ++bb) {
                    k_gmm<128, 128, 3><<<dim3(64, 32), 256, 0, stream>>>(
                        qmat2 + (size_t)bb * 262144, memkT2 + (size_t)bb * 524288,
                        nullptr, nullptr, simsb2, 4096, 8192, 64);
                    k_ksel<<<2048, 256, 0, stream>>>(simsb2, memv, gate, ao2, bb);
                }
            } else {
                k_knn5<<<dim3(NS / 4, NB), 256, 0, stream>>>(qkv2, mkh2, mkl2, memv, gate, ao2);
            }
        }
        k_gmm<64, 64, 2><<<dim3(8, 32), 256, 0, stream>>>(
            ao2, Wo + (size_t)l * 512 * 512, bo + l * 512, tok2, ybuf2, 2048, 512, 512);
        k_ln<<<2048, 256, 0, stream>>>(ybuf2, ln1g + l * 512, ln1b + l * 512, tok2);
        k_gmm<128, 128, 1><<<dim3(16, 16), 256, 0, stream>>>(
            tok2, W1 + (size_t)l * 512 * 2048, b1 + l * 2048, nullptr, ff12, 2048, 2048, 512);
        k_gmm<64, 64, 2><<<dim3(8, 32), 256, 0, stream>>>(
            ff12, W2 + (size_t)l * 2048 * 512, b2 + l * 512, tok2, ybuf2, 2048, 512, 2048);
        k_ln<<<2048, 256, 0, stream>>>(ybuf2, ln2g + l * 512, ln2b + l * 512, tok2);
    }
    k_pool2<<<dim3(8, NB), 256, 0, stream>>>(tok2, simsb2);
    k_pool3<<<NB, 512, 0, stream>>>(simsb2, pooled2);
    k_fc1<<<16, 256, 0, stream>>>(pooled2, fc1w, fc1b, o12);
    k_fc2b<<<NC, 256, 0, stream>>>(o12, fc2w, fc2b_, out);
}